// Round 4
// baseline (1115.631 us; speedup 1.0000x reference)
//
#include <hip/hip_runtime.h>
#include <hip/hip_bf16.h>
#include <math.h>

#define N_ENT 40000
#define N_REL 500
#define E_DIR 200000
#define E_2HOP 50000
#define E_TOT 250000
#define D_IN 128
#define D_EMB 256
#define LRELU 0.2f
#define BN_EPS 1e-5f

typedef __hip_bfloat16 bf16;

__device__ __forceinline__ float b2f(bf16 v){ return __bfloat162float(v); }
__device__ __forceinline__ float ldf(const float* p){ return *p; }
__device__ __forceinline__ float ldf(const bf16* p){ return b2f(*p); }
__device__ __forceinline__ void stf(float* p, float v){ *p = v; }
__device__ __forceinline__ void stf(bf16* p, float v){ *p = __float2bfloat16(v); }

// W_heads (4,384,64) fp32 -> Wa/Wb/Wc each (128,256) with col = h*64+j
__global__ void repack_W_heads(const float* __restrict__ Wh, float* __restrict__ Wa,
                               float* __restrict__ Wb, float* __restrict__ Wc){
  int idx = blockIdx.x*blockDim.x + threadIdx.x;
  if (idx >= D_IN*D_EMB) return;
  int k = idx >> 8;
  int colv = idx & 255;
  int h = colv >> 6, j = colv & 63;
  const int HS = 384*64;
  Wa[idx] = Wh[h*HS + k*64 + j];
  Wb[idx] = Wh[h*HS + (k+128)*64 + j];
  Wc[idx] = Wh[h*HS + (k+256)*64 + j];
}

// ---------------- generic tiled GEMM, N fixed = 256 ----------------
template<typename AT, typename CT, bool ACCUM>
__global__ void gemm64(const AT* __restrict__ A, const float* __restrict__ B,
                       CT* __restrict__ C, int M, int K){
  const int N = 256;
  __shared__ float As[16][65];
  __shared__ float Bs[16][65];
  int bm = blockIdx.x * 64, bn = blockIdx.y * 64;
  int tid = threadIdx.x;
  int tx = tid & 15, ty = tid >> 4;
  float acc[4][4] = {};
  for (int k0 = 0; k0 < K; k0 += 16){
    #pragma unroll
    for (int j = 0; j < 4; j++){
      int idx = tid + j*256;
      int m = idx >> 4, kk = idx & 15;
      int gm = bm + m;
      float v = 0.f;
      if (gm < M) v = ldf(&A[(size_t)gm*K + k0 + kk]);
      As[kk][m] = v;
    }
    #pragma unroll
    for (int j = 0; j < 4; j++){
      int idx = tid + j*256;
      int kk = idx >> 6, n = idx & 63;
      Bs[kk][n] = B[(size_t)(k0+kk)*N + bn + n];
    }
    __syncthreads();
    #pragma unroll
    for (int kk = 0; kk < 16; kk++){
      float a[4], b[4];
      #pragma unroll
      for (int i = 0; i < 4; i++) a[i] = As[kk][ty*4+i];
      #pragma unroll
      for (int j = 0; j < 4; j++) b[j] = Bs[kk][tx*4+j];
      #pragma unroll
      for (int i = 0; i < 4; i++)
        #pragma unroll
        for (int j = 0; j < 4; j++) acc[i][j] += a[i]*b[j];
    }
    __syncthreads();
  }
  #pragma unroll
  for (int i = 0; i < 4; i++){
    int gm = bm + ty*4 + i;
    if (gm >= M) continue;
    #pragma unroll
    for (int j = 0; j < 4; j++){
      size_t o = (size_t)gm*N + bn + tx*4 + j;
      if (ACCUM) stf(&C[o], ldf(&C[o]) + acc[i][j]);
      else       stf(&C[o], acc[i][j]);
    }
  }
}

// ---------------- per-head / full dots ----------------
template<typename PT>
__global__ void head_dots4(const PT* __restrict__ P, const float* __restrict__ a,
                           float* __restrict__ s, int M){
  int wid = threadIdx.x >> 6, lane = threadIdx.x & 63;
  int i = blockIdx.x*4 + wid;
  if (i >= M) return;
  int f0 = lane*4;
  float p = 0.f;
  #pragma unroll
  for (int d = 0; d < 4; d++) p += ldf(&P[(size_t)i*256 + f0 + d]) * a[f0+d];
  #pragma unroll
  for (int o = 8; o >= 1; o >>= 1) p += __shfl_xor(p, o, 64);
  if ((lane & 15) == 0) s[i*4 + (lane>>4)] = p;
}

template<typename PT>
__global__ void full_dot(const PT* __restrict__ P, const float* __restrict__ a,
                         float* __restrict__ s, int M){
  int wid = threadIdx.x >> 6, lane = threadIdx.x & 63;
  int i = blockIdx.x*4 + wid;
  if (i >= M) return;
  int f0 = lane*4;
  float p = 0.f;
  #pragma unroll
  for (int d = 0; d < 4; d++) p += ldf(&P[(size_t)i*256 + f0 + d]) * a[f0+d];
  #pragma unroll
  for (int o = 32; o >= 1; o >>= 1) p += __shfl_xor(p, o, 64);
  if (lane == 0) s[i] = p;
}

// ---------------- edge helpers / CSR ----------------
__device__ __forceinline__ int e_row(int e, const int* ei, const int* i2){
  return (e < E_DIR) ? ei[E_DIR + e] : i2[(e - E_DIR)*4 + 3];
}
__device__ __forceinline__ int e_col(int e, const int* ei, const int* i2){
  return (e < E_DIR) ? ei[e] : i2[(e - E_DIR)*4 + 0];
}

__global__ void hist_kernel(const int* __restrict__ ei, const int* __restrict__ i2, int* __restrict__ cnt){
  int e = blockIdx.x*blockDim.x + threadIdx.x;
  if (e < E_TOT) atomicAdd(&cnt[e_row(e, ei, i2)], 1);
}

__global__ void scan40000(const int* __restrict__ cnt, int* __restrict__ off){
  __shared__ int part[1024];
  int tid = threadIdx.x;
  const int CH = 40;
  int base = tid * CH;
  int s = 0;
  for (int i = 0; i < CH; i++){ int idx = base + i; if (idx < N_ENT) s += cnt[idx]; }
  part[tid] = s;
  __syncthreads();
  for (int o = 1; o < 1024; o <<= 1){
    int v = (tid >= o) ? part[tid-o] : 0;
    __syncthreads();
    part[tid] += v;
    __syncthreads();
  }
  int run = (tid > 0) ? part[tid-1] : 0;
  for (int i = 0; i < CH; i++){
    int idx = base + i;
    if (idx < N_ENT){ off[idx] = run; run += cnt[idx]; }
  }
  if (tid == 0) off[N_ENT] = part[1023];
}

__global__ void scatter_kernel(const int* __restrict__ ei, const int* __restrict__ i2,
                               const int* __restrict__ off, int* __restrict__ cur, int* __restrict__ perm){
  int e = blockIdx.x*blockDim.x + threadIdx.x;
  if (e >= E_TOT) return;
  int r = e_row(e, ei, i2);
  int p = atomicAdd(&cur[r], 1);
  perm[off[r] + p] = e;
}

// ---------------- layer-1 aggregation (4 heads x 64) ----------------
__global__ void agg1(const int* __restrict__ off, const int* __restrict__ perm,
                     const int* __restrict__ ei, const int* __restrict__ et, const int* __restrict__ i2,
                     const float* __restrict__ s1, const float* __restrict__ s2, const float* __restrict__ sR,
                     const bf16* __restrict__ P1, const bf16* __restrict__ P2, const float* __restrict__ PRm,
                     float* __restrict__ X1){
  int wid = threadIdx.x >> 6, lane = threadIdx.x & 63;
  int i = blockIdx.x*4 + wid;
  if (i >= N_ENT) return;
  int st = off[i], en = off[i+1];
  int f0 = lane*4;
  size_t ob = (size_t)i*256 + f0;
  if (st == en){
    #pragma unroll
    for (int d = 0; d < 4; d++) X1[ob+d] = 0.f;
    return;
  }
  float s1i[4];
  #pragma unroll
  for (int h = 0; h < 4; h++) s1i[h] = s1[i*4+h];
  float mx[4] = {-1e30f,-1e30f,-1e30f,-1e30f};
  for (int t = st + lane; t < en; t += 64){
    int e = perm[t];
    int c = e_col(e, ei, i2);
    float l[4];
    if (e < E_DIR){
      int ty_ = et[e];
      #pragma unroll
      for (int h = 0; h < 4; h++) l[h] = s2[c*4+h] + sR[ty_*4+h];
    } else {
      int q = (e - E_DIR)*4;
      int t0 = i2[q+1], t1 = i2[q+2];
      #pragma unroll
      for (int h = 0; h < 4; h++) l[h] = s2[c*4+h] + sR[t0*4+h] + sR[t1*4+h];
    }
    #pragma unroll
    for (int h = 0; h < 4; h++){
      float v = s1i[h] + l[h];
      v = (v >= 0.f) ? v : LRELU*v;
      mx[h] = fmaxf(mx[h], v);
    }
  }
  #pragma unroll
  for (int o = 32; o >= 1; o >>= 1)
    #pragma unroll
    for (int h = 0; h < 4; h++) mx[h] = fmaxf(mx[h], __shfl_xor(mx[h], o, 64));
  float sm[4] = {0,0,0,0};
  for (int t = st + lane; t < en; t += 64){
    int e = perm[t];
    int c = e_col(e, ei, i2);
    float l[4];
    if (e < E_DIR){
      int ty_ = et[e];
      #pragma unroll
      for (int h = 0; h < 4; h++) l[h] = s2[c*4+h] + sR[ty_*4+h];
    } else {
      int q = (e - E_DIR)*4;
      int t0 = i2[q+1], t1 = i2[q+2];
      #pragma unroll
      for (int h = 0; h < 4; h++) l[h] = s2[c*4+h] + sR[t0*4+h] + sR[t1*4+h];
    }
    #pragma unroll
    for (int h = 0; h < 4; h++){
      float v = s1i[h] + l[h];
      v = (v >= 0.f) ? v : LRELU*v;
      sm[h] += __expf(v - mx[h]);
    }
  }
  #pragma unroll
  for (int o = 32; o >= 1; o >>= 1)
    #pragma unroll
    for (int h = 0; h < 4; h++) sm[h] += __shfl_xor(sm[h], o, 64);
  int hf = f0 >> 6;
  float inv = 1.f/(sm[hf] + 1e-16f);
  float mxh = mx[hf], s1h = s1i[hf];
  float a0=0,a1=0,a2=0,a3=0;
  for (int t = st; t < en; t++){
    int e = perm[t];
    int c = e_col(e, ei, i2);
    float l; const float* r0; const float* r1 = nullptr;
    if (e < E_DIR){
      int ty_ = et[e];
      l = s2[c*4+hf] + sR[ty_*4+hf];
      r0 = PRm + (size_t)ty_*256;
    } else {
      int q = (e - E_DIR)*4;
      int t0 = i2[q+1], t1 = i2[q+2];
      l = s2[c*4+hf] + sR[t0*4+hf] + sR[t1*4+hf];
      r0 = PRm + (size_t)t0*256; r1 = PRm + (size_t)t1*256;
    }
    float v = s1h + l; v = (v >= 0.f) ? v : LRELU*v;
    float w = __expf(v - mxh) * inv;
    const bf16* p2 = P2 + (size_t)c*256 + f0;
    float e0 = b2f(p2[0]) + r0[f0+0];
    float e1 = b2f(p2[1]) + r0[f0+1];
    float e2 = b2f(p2[2]) + r0[f0+2];
    float e3 = b2f(p2[3]) + r0[f0+3];
    if (r1){ e0 += r1[f0+0]; e1 += r1[f0+1]; e2 += r1[f0+2]; e3 += r1[f0+3]; }
    a0 += w*e0; a1 += w*e1; a2 += w*e2; a3 += w*e3;
  }
  float as = sm[hf]*inv;
  const bf16* p1 = P1 + ob;
  a0 += as*b2f(p1[0]); a1 += as*b2f(p1[1]); a2 += as*b2f(p1[2]); a3 += as*b2f(p1[3]);
  X1[ob+0] = (a0 > 0.f) ? a0 : __expf(a0)-1.f;
  X1[ob+1] = (a1 > 0.f) ? a1 : __expf(a1)-1.f;
  X1[ob+2] = (a2 > 0.f) ? a2 : __expf(a2)-1.f;
  X1[ob+3] = (a3 > 0.f) ? a3 : __expf(a3)-1.f;
}

// ---------------- layer-2 aggregation (single head, 256) ----------------
__global__ void agg2(const int* __restrict__ off, const int* __restrict__ perm,
                     const int* __restrict__ ei, const int* __restrict__ et, const int* __restrict__ i2,
                     const float* __restrict__ s1, const float* __restrict__ s2, const float* __restrict__ sR,
                     const bf16* __restrict__ Q1, const bf16* __restrict__ Q2, const float* __restrict__ QRm,
                     float* __restrict__ X2){
  int wid = threadIdx.x >> 6, lane = threadIdx.x & 63;
  int i = blockIdx.x*4 + wid;
  if (i >= N_ENT) return;
  int st = off[i], en = off[i+1];
  int f0 = lane*4;
  size_t ob = (size_t)i*256 + f0;
  if (st == en){
    #pragma unroll
    for (int d = 0; d < 4; d++) X2[ob+d] = 0.f;
    return;
  }
  float s1i = s1[i];
  float mx = -1e30f;
  for (int t = st + lane; t < en; t += 64){
    int e = perm[t];
    int c = e_col(e, ei, i2);
    float l;
    if (e < E_DIR) l = s2[c] + sR[et[e]];
    else { int q = (e - E_DIR)*4; l = s2[c] + sR[i2[q+1]] + sR[i2[q+2]]; }
    float v = s1i + l; v = (v >= 0.f) ? v : LRELU*v;
    mx = fmaxf(mx, v);
  }
  #pragma unroll
  for (int o = 32; o >= 1; o >>= 1) mx = fmaxf(mx, __shfl_xor(mx, o, 64));
  float sm = 0.f;
  for (int t = st + lane; t < en; t += 64){
    int e = perm[t];
    int c = e_col(e, ei, i2);
    float l;
    if (e < E_DIR) l = s2[c] + sR[et[e]];
    else { int q = (e - E_DIR)*4; l = s2[c] + sR[i2[q+1]] + sR[i2[q+2]]; }
    float v = s1i + l; v = (v >= 0.f) ? v : LRELU*v;
    sm += __expf(v - mx);
  }
  #pragma unroll
  for (int o = 32; o >= 1; o >>= 1) sm += __shfl_xor(sm, o, 64);
  float inv = 1.f/(sm + 1e-16f);
  float a0=0,a1=0,a2=0,a3=0;
  for (int t = st; t < en; t++){
    int e = perm[t];
    int c = e_col(e, ei, i2);
    float l; const float* r0; const float* r1 = nullptr;
    if (e < E_DIR){
      int ty_ = et[e];
      l = s2[c] + sR[ty_];
      r0 = QRm + (size_t)ty_*256;
    } else {
      int q = (e - E_DIR)*4;
      int t0 = i2[q+1], t1 = i2[q+2];
      l = s2[c] + sR[t0] + sR[t1];
      r0 = QRm + (size_t)t0*256; r1 = QRm + (size_t)t1*256;
    }
    float v = s1i + l; v = (v >= 0.f) ? v : LRELU*v;
    float w = __expf(v - mx) * inv;
    const bf16* q2 = Q2 + (size_t)c*256 + f0;
    float e0 = b2f(q2[0]) + r0[f0+0];
    float e1 = b2f(q2[1]) + r0[f0+1];
    float e2 = b2f(q2[2]) + r0[f0+2];
    float e3 = b2f(q2[3]) + r0[f0+3];
    if (r1){ e0 += r1[f0+0]; e1 += r1[f0+1]; e2 += r1[f0+2]; e3 += r1[f0+3]; }
    a0 += w*e0; a1 += w*e1; a2 += w*e2; a3 += w*e3;
  }
  float as = sm*inv;
  const bf16* q1 = Q1 + ob;
  a0 += as*b2f(q1[0]); a1 += as*b2f(q1[1]); a2 += as*b2f(q1[2]); a3 += as*b2f(q1[3]);
  X2[ob+0] = (a0 > 0.f) ? a0 : __expf(a0)-1.f;
  X2[ob+1] = (a1 > 0.f) ? a1 : __expf(a1)-1.f;
  X2[ob+2] = (a2 > 0.f) ? a2 : __expf(a2)-1.f;
  X2[ob+3] = (a3 > 0.f) ? a3 : __expf(a3)-1.f;
}

// ---------------- batch norm (in-place over fp32 X in d_out) ----------------
__global__ void bn_reduce(const float* __restrict__ X, float* __restrict__ sums, float* __restrict__ sq){
  int ch = threadIdx.x;
  float s = 0.f, q = 0.f;
  for (int r = blockIdx.x; r < N_ENT; r += gridDim.x){
    float v = X[(size_t)r*256 + ch];
    s += v; q += v*v;
  }
  atomicAdd(&sums[ch], s);
  atomicAdd(&sq[ch], q);
}

__global__ void bn_final(float* __restrict__ X, const float* __restrict__ sums, const float* __restrict__ sq,
                         const float* __restrict__ gamma, const float* __restrict__ beta){
  int idx = blockIdx.x*blockDim.x + threadIdx.x;
  if (idx >= N_ENT*256) return;
  int ch = idx & 255;
  const float invn = 1.f/(float)N_ENT;
  float mean = sums[ch] * invn;
  float var  = fmaxf(sq[ch] * invn - mean*mean, 0.f);
  X[idx] = (X[idx] - mean) * rsqrtf(var + BN_EPS) * gamma[ch] + beta[ch];
}

__global__ void copy_r(const float* __restrict__ RF, float* __restrict__ out){
  int idx = blockIdx.x*blockDim.x + threadIdx.x;
  if (idx < N_REL*256) out[idx] = RF[idx];
}

// ---------------- launch ----------------
extern "C" void kernel_launch(void* const* d_in, const int* in_sizes, int n_in,
                              void* d_out, int out_size, void* d_ws, size_t ws_size,
                              hipStream_t stream){
  const int*   ei  = (const int*)d_in[0];
  const int*   et  = (const int*)d_in[1];
  const int*   i2  = (const int*)d_in[2];
  const float* emb = (const float*)d_in[3];
  const float* rel = (const float*)d_in[4];
  const float* Wh  = (const float*)d_in[5];
  const float* ah  = (const float*)d_in[6];
  const float* gw  = (const float*)d_in[7];
  const float* ow  = (const float*)d_in[8];
  const float* oa  = (const float*)d_in[9];
  const float* we  = (const float*)d_in[10];
  const float* gma = (const float*)d_in[11];
  const float* bta = (const float*)d_in[12];
  float* out = (float*)d_out;

  char* ws = (char*)d_ws;
  size_t o = 0;
  auto alloc = [&](size_t bytes)->char*{
    char* p = ws + o; o = (o + bytes + 255) & ~(size_t)255; return p;
  };
  bf16*  P1  = (bf16*)alloc(20480000);    // P1 -> Q1 (40000x256 bf16)
  bf16*  P2  = (bf16*)alloc(20480000);    // P2 -> Q2
  float* PR  = (float*)alloc(512000);
  float* QR  = (float*)alloc(512000);
  float* RF  = (float*)alloc(512000);     // r in fp32
  float* WA  = (float*)alloc(131072);
  float* WB  = (float*)alloc(131072);
  float* WC  = (float*)alloc(131072);
  float* S1  = (float*)alloc(640000);
  float* S2  = (float*)alloc(640000);
  float* SRm = (float*)alloc(8192);
  float* S1B = (float*)alloc(160000);
  float* S2B = (float*)alloc(160000);
  float* SRB = (float*)alloc(2048);
  int*   CNT = (int*)alloc(160000);
  int*   CUR = (int*)alloc(160000);
  int*   OFF = (int*)alloc(160016);
  int*   PERM= (int*)alloc(1000000);
  float* BNS = (float*)alloc(1024);
  float* BNQ = (float*)alloc(1024);
  // X1 / X2 live in d_out's x-region (fp32, 40000*256), finalized in place by BN.
  float* X1 = out;
  float* X2 = out;
  (void)ws_size; (void)in_sizes; (void)n_in; (void)out_size;

  hipMemsetAsync(CNT, 0, 160000, stream);
  hipMemsetAsync(CUR, 0, 160000, stream);
  hipMemsetAsync(BNS, 0, 1024, stream);
  hipMemsetAsync(BNQ, 0, 1024, stream);

  // weight prep
  repack_W_heads<<<(D_IN*D_EMB+255)/256, 256, 0, stream>>>(Wh, WA, WB, WC);

  // CSR build
  hist_kernel<<<(E_TOT+255)/256, 256, 0, stream>>>(ei, i2, CNT);
  scan40000<<<1, 1024, 0, stream>>>(CNT, OFF);
  scatter_kernel<<<(E_TOT+255)/256, 256, 0, stream>>>(ei, i2, OFF, CUR, PERM);

  // layer-1 projections
  dim3 g1((N_ENT+63)/64, 4);
  dim3 g2((N_REL+63)/64, 4);
  gemm64<float,bf16,false><<<g1, 256, 0, stream>>>(emb, WA, P1, N_ENT, 128);
  gemm64<float,bf16,false><<<g1, 256, 0, stream>>>(emb, WB, P2, N_ENT, 128);
  gemm64<float,float,false><<<g2, 256, 0, stream>>>(rel, WC, PR, N_REL, 128);
  gemm64<float,float,false><<<g2, 256, 0, stream>>>(rel, gw, RF, N_REL, 128);

  head_dots4<bf16><<<(N_ENT+3)/4, 256, 0, stream>>>(P1, ah, S1, N_ENT);
  head_dots4<bf16><<<(N_ENT+3)/4, 256, 0, stream>>>(P2, ah, S2, N_ENT);
  head_dots4<float><<<(N_REL+3)/4, 256, 0, stream>>>(PR, ah, SRm, N_REL);

  agg1<<<N_ENT/4, 256, 0, stream>>>(OFF, PERM, ei, et, i2, S1, S2, SRm, P1, P2, PR, X1);

  // layer-2 projections (Q1/Q2 overwrite P1/P2; X1 read fp32 from d_out)
  gemm64<float,bf16,false><<<g1, 256, 0, stream>>>(X1, ow,          P1, N_ENT, 256);
  gemm64<float,bf16,false><<<g1, 256, 0, stream>>>(X1, ow + 65536,  P2, N_ENT, 256);
  gemm64<float,float,false><<<g2, 256, 0, stream>>>(RF, ow + 131072, QR, N_REL, 256);

  full_dot<bf16><<<(N_ENT+3)/4, 256, 0, stream>>>(P1, oa, S1B, N_ENT);
  full_dot<bf16><<<(N_ENT+3)/4, 256, 0, stream>>>(P2, oa, S2B, N_ENT);
  full_dot<float><<<(N_REL+3)/4, 256, 0, stream>>>(QR, oa, SRB, N_REL);

  // agg2 overwrites X1 (dead) with X2 in d_out
  agg2<<<N_ENT/4, 256, 0, stream>>>(OFF, PERM, ei, et, i2, S1B, S2B, SRB, P1, P2, QR, X2);

  // + init_embed @ W_entities (accumulate into X2 in d_out)
  gemm64<float,float,true><<<g1, 256, 0, stream>>>(emb, we, X2, N_ENT, 128);

  // batch norm in place + r output
  bn_reduce<<<256, 256, 0, stream>>>(X2, BNS, BNQ);
  bn_final<<<(N_ENT*256+255)/256, 256, 0, stream>>>(X2, BNS, BNQ, gma, bta);
  copy_r<<<(N_REL*256+255)/256, 256, 0, stream>>>(RF, out + (size_t)N_ENT*256);
}

// Round 5
// 919.023 us; speedup vs baseline: 1.2139x; 1.2139x over previous
//
#include <hip/hip_runtime.h>
#include <hip/hip_bf16.h>
#include <math.h>

#define N_ENT 40000
#define N_REL 500
#define E_DIR 200000
#define E_2HOP 50000
#define E_TOT 250000
#define D_IN 128
#define D_EMB 256
#define LRELU 0.2f
#define BN_EPS 1e-5f

typedef __hip_bfloat16 bf16;
typedef __attribute__((ext_vector_type(8))) short short8;
typedef __attribute__((ext_vector_type(4))) float float4v;

__device__ __forceinline__ float b2f(bf16 v){ return __bfloat162float(v); }
__device__ __forceinline__ float ldf(const float* p){ return *p; }
__device__ __forceinline__ float ldf(const bf16* p){ return b2f(*p); }
__device__ __forceinline__ void stf(float* p, float v){ *p = v; }
__device__ __forceinline__ void stf(bf16* p, float v){ *p = __float2bfloat16(v); }

// W_heads (4,384,64) fp32 -> Wa/Wb/Wc each (128,256) with col = h*64+j
__global__ void repack_W_heads(const float* __restrict__ Wh, float* __restrict__ Wa,
                               float* __restrict__ Wb, float* __restrict__ Wc){
  int idx = blockIdx.x*blockDim.x + threadIdx.x;
  if (idx >= D_IN*D_EMB) return;
  int k = idx >> 8;
  int colv = idx & 255;
  int h = colv >> 6, j = colv & 63;
  const int HS = 384*64;
  Wa[idx] = Wh[h*HS + k*64 + j];
  Wb[idx] = Wh[h*HS + (k+128)*64 + j];
  Wc[idx] = Wh[h*HS + (k+256)*64 + j];
}

// fp32 -> bf16 convert
__global__ void cvt_f2b(const float* __restrict__ in, bf16* __restrict__ out, int n){
  int i = blockIdx.x*blockDim.x + threadIdx.x;
  if (i < n) out[i] = __float2bfloat16(in[i]);
}

// Pack fp32 B (K x 256, row-major) into MFMA b_frag-contiguous bf16 layout:
// Bp[((kc*16 + nt)*64 + lane)*8 + j] = B[kc*32 + (lane>>4)*8 + j][nt*16 + (lane&15)]
__global__ void pack_B(const float* __restrict__ B, bf16* __restrict__ Bp, int K){
  int idx = blockIdx.x*blockDim.x + threadIdx.x;
  int total = (K >> 5) * 16 * 64;
  if (idx >= total) return;
  int lane = idx & 63;
  int nt = (idx >> 6) & 15;
  int kc = idx >> 10;
  int quad = lane >> 4, l16 = lane & 15;
  int kbase = kc*32 + quad*8;
  int col = nt*16 + l16;
  bf16* dst = Bp + (size_t)idx*8;
  #pragma unroll
  for (int j = 0; j < 8; j++) dst[j] = __float2bfloat16(B[(size_t)(kbase+j)*256 + col]);
}

// ---------------- MFMA GEMM: A (M x K bf16 row-major), Bp packed, C (M x 256 bf16) ----------------
// block = 256 threads (4 waves); each block does 64 rows x 256 cols; M % 64 == 0.
__global__ __launch_bounds__(256) void gemm_mfma(const short* __restrict__ A,
                                                 const short* __restrict__ Bp,
                                                 bf16* __restrict__ C, int M, int K){
  int w = threadIdx.x >> 6, lane = threadIdx.x & 63;
  int quad = lane >> 4, l16 = lane & 15;
  int rm = blockIdx.x*64 + w*16;           // wave's 16-row band
  int arow = rm + l16;                     // this lane's A row
  float4v acc[16];
  #pragma unroll
  for (int nt = 0; nt < 16; nt++) acc[nt] = (float4v){0.f,0.f,0.f,0.f};
  int nkc = K >> 5;
  for (int kc = 0; kc < nkc; kc++){
    short8 a = *(const short8*)(A + (size_t)arow*K + kc*32 + quad*8);
    const short8* bp = (const short8*)(Bp + ((size_t)(kc*16)*64 + lane)*8);
    #pragma unroll
    for (int nt = 0; nt < 16; nt++){
      short8 b = bp[(size_t)nt*64];
      acc[nt] = __builtin_amdgcn_mfma_f32_16x16x32_bf16(a, b, acc[nt], 0, 0, 0);
    }
  }
  #pragma unroll
  for (int nt = 0; nt < 16; nt++){
    #pragma unroll
    for (int r = 0; r < 4; r++){
      int row = quad*4 + r;
      C[(size_t)(rm + row)*256 + nt*16 + l16] = __float2bfloat16(acc[nt][r]);
    }
  }
}

// ---------------- generic tiled fp32 GEMM, N fixed = 256 ----------------
template<typename AT, typename CT, bool ACCUM>
__global__ void gemm64(const AT* __restrict__ A, const float* __restrict__ B,
                       CT* __restrict__ C, int M, int K){
  const int N = 256;
  __shared__ float As[16][65];
  __shared__ float Bs[16][65];
  int bm = blockIdx.x * 64, bn = blockIdx.y * 64;
  int tid = threadIdx.x;
  int tx = tid & 15, ty = tid >> 4;
  float acc[4][4] = {};
  for (int k0 = 0; k0 < K; k0 += 16){
    #pragma unroll
    for (int j = 0; j < 4; j++){
      int idx = tid + j*256;
      int m = idx >> 4, kk = idx & 15;
      int gm = bm + m;
      float v = 0.f;
      if (gm < M) v = ldf(&A[(size_t)gm*K + k0 + kk]);
      As[kk][m] = v;
    }
    #pragma unroll
    for (int j = 0; j < 4; j++){
      int idx = tid + j*256;
      int kk = idx >> 6, n = idx & 63;
      Bs[kk][n] = B[(size_t)(k0+kk)*N + bn + n];
    }
    __syncthreads();
    #pragma unroll
    for (int kk = 0; kk < 16; kk++){
      float a[4], b[4];
      #pragma unroll
      for (int i = 0; i < 4; i++) a[i] = As[kk][ty*4+i];
      #pragma unroll
      for (int j = 0; j < 4; j++) b[j] = Bs[kk][tx*4+j];
      #pragma unroll
      for (int i = 0; i < 4; i++)
        #pragma unroll
        for (int j = 0; j < 4; j++) acc[i][j] += a[i]*b[j];
    }
    __syncthreads();
  }
  #pragma unroll
  for (int i = 0; i < 4; i++){
    int gm = bm + ty*4 + i;
    if (gm >= M) continue;
    #pragma unroll
    for (int j = 0; j < 4; j++){
      size_t o = (size_t)gm*N + bn + tx*4 + j;
      if (ACCUM) stf(&C[o], ldf(&C[o]) + acc[i][j]);
      else       stf(&C[o], acc[i][j]);
    }
  }
}

// ---------------- per-head / full dots ----------------
template<typename PT>
__global__ void head_dots4(const PT* __restrict__ P, const float* __restrict__ a,
                           float* __restrict__ s, int M){
  int wid = threadIdx.x >> 6, lane = threadIdx.x & 63;
  int i = blockIdx.x*4 + wid;
  if (i >= M) return;
  int f0 = lane*4;
  float p = 0.f;
  #pragma unroll
  for (int d = 0; d < 4; d++) p += ldf(&P[(size_t)i*256 + f0 + d]) * a[f0+d];
  #pragma unroll
  for (int o = 8; o >= 1; o >>= 1) p += __shfl_xor(p, o, 64);
  if ((lane & 15) == 0) s[i*4 + (lane>>4)] = p;
}

template<typename PT>
__global__ void full_dot(const PT* __restrict__ P, const float* __restrict__ a,
                         float* __restrict__ s, int M){
  int wid = threadIdx.x >> 6, lane = threadIdx.x & 63;
  int i = blockIdx.x*4 + wid;
  if (i >= M) return;
  int f0 = lane*4;
  float p = 0.f;
  #pragma unroll
  for (int d = 0; d < 4; d++) p += ldf(&P[(size_t)i*256 + f0 + d]) * a[f0+d];
  #pragma unroll
  for (int o = 32; o >= 1; o >>= 1) p += __shfl_xor(p, o, 64);
  if (lane == 0) s[i] = p;
}

// ---------------- edge helpers / CSR ----------------
__device__ __forceinline__ int e_row(int e, const int* ei, const int* i2){
  return (e < E_DIR) ? ei[E_DIR + e] : i2[(e - E_DIR)*4 + 3];
}
__device__ __forceinline__ int e_col(int e, const int* ei, const int* i2){
  return (e < E_DIR) ? ei[e] : i2[(e - E_DIR)*4 + 0];
}

__global__ void hist_kernel(const int* __restrict__ ei, const int* __restrict__ i2, int* __restrict__ cnt){
  int e = blockIdx.x*blockDim.x + threadIdx.x;
  if (e < E_TOT) atomicAdd(&cnt[e_row(e, ei, i2)], 1);
}

__global__ void scan40000(const int* __restrict__ cnt, int* __restrict__ off){
  __shared__ int part[1024];
  int tid = threadIdx.x;
  const int CH = 40;
  int base = tid * CH;
  int s = 0;
  for (int i = 0; i < CH; i++){ int idx = base + i; if (idx < N_ENT) s += cnt[idx]; }
  part[tid] = s;
  __syncthreads();
  for (int o = 1; o < 1024; o <<= 1){
    int v = (tid >= o) ? part[tid-o] : 0;
    __syncthreads();
    part[tid] += v;
    __syncthreads();
  }
  int run = (tid > 0) ? part[tid-1] : 0;
  for (int i = 0; i < CH; i++){
    int idx = base + i;
    if (idx < N_ENT){ off[idx] = run; run += cnt[idx]; }
  }
  if (tid == 0) off[N_ENT] = part[1023];
}

__global__ void scatter_kernel(const int* __restrict__ ei, const int* __restrict__ i2,
                               const int* __restrict__ off, int* __restrict__ cur, int* __restrict__ perm){
  int e = blockIdx.x*blockDim.x + threadIdx.x;
  if (e >= E_TOT) return;
  int r = e_row(e, ei, i2);
  int p = atomicAdd(&cur[r], 1);
  perm[off[r] + p] = e;
}

// ---------------- layer-1 aggregation (4 heads x 64) ----------------
template<typename XT>
__global__ void agg1(const int* __restrict__ off, const int* __restrict__ perm,
                     const int* __restrict__ ei, const int* __restrict__ et, const int* __restrict__ i2,
                     const float* __restrict__ s1, const float* __restrict__ s2, const float* __restrict__ sR,
                     const bf16* __restrict__ P1, const bf16* __restrict__ P2, const float* __restrict__ PRm,
                     XT* __restrict__ X1){
  int wid = threadIdx.x >> 6, lane = threadIdx.x & 63;
  int i = blockIdx.x*4 + wid;
  if (i >= N_ENT) return;
  int st = off[i], en = off[i+1];
  int f0 = lane*4;
  size_t ob = (size_t)i*256 + f0;
  if (st == en){
    #pragma unroll
    for (int d = 0; d < 4; d++) stf(&X1[ob+d], 0.f);
    return;
  }
  float s1i[4];
  #pragma unroll
  for (int h = 0; h < 4; h++) s1i[h] = s1[i*4+h];
  float mx[4] = {-1e30f,-1e30f,-1e30f,-1e30f};
  for (int t = st + lane; t < en; t += 64){
    int e = perm[t];
    int c = e_col(e, ei, i2);
    float l[4];
    if (e < E_DIR){
      int ty_ = et[e];
      #pragma unroll
      for (int h = 0; h < 4; h++) l[h] = s2[c*4+h] + sR[ty_*4+h];
    } else {
      int q = (e - E_DIR)*4;
      int t0 = i2[q+1], t1 = i2[q+2];
      #pragma unroll
      for (int h = 0; h < 4; h++) l[h] = s2[c*4+h] + sR[t0*4+h] + sR[t1*4+h];
    }
    #pragma unroll
    for (int h = 0; h < 4; h++){
      float v = s1i[h] + l[h];
      v = (v >= 0.f) ? v : LRELU*v;
      mx[h] = fmaxf(mx[h], v);
    }
  }
  #pragma unroll
  for (int o = 32; o >= 1; o >>= 1)
    #pragma unroll
    for (int h = 0; h < 4; h++) mx[h] = fmaxf(mx[h], __shfl_xor(mx[h], o, 64));
  float sm[4] = {0,0,0,0};
  for (int t = st + lane; t < en; t += 64){
    int e = perm[t];
    int c = e_col(e, ei, i2);
    float l[4];
    if (e < E_DIR){
      int ty_ = et[e];
      #pragma unroll
      for (int h = 0; h < 4; h++) l[h] = s2[c*4+h] + sR[ty_*4+h];
    } else {
      int q = (e - E_DIR)*4;
      int t0 = i2[q+1], t1 = i2[q+2];
      #pragma unroll
      for (int h = 0; h < 4; h++) l[h] = s2[c*4+h] + sR[t0*4+h] + sR[t1*4+h];
    }
    #pragma unroll
    for (int h = 0; h < 4; h++){
      float v = s1i[h] + l[h];
      v = (v >= 0.f) ? v : LRELU*v;
      sm[h] += __expf(v - mx[h]);
    }
  }
  #pragma unroll
  for (int o = 32; o >= 1; o >>= 1)
    #pragma unroll
    for (int h = 0; h < 4; h++) sm[h] += __shfl_xor(sm[h], o, 64);
  int hf = f0 >> 6;
  float inv = 1.f/(sm[hf] + 1e-16f);
  float mxh = mx[hf], s1h = s1i[hf];
  float a0=0,a1=0,a2=0,a3=0;
  for (int t = st; t < en; t++){
    int e = perm[t];
    int c = e_col(e, ei, i2);
    float l; const float* r0; const float* r1 = nullptr;
    if (e < E_DIR){
      int ty_ = et[e];
      l = s2[c*4+hf] + sR[ty_*4+hf];
      r0 = PRm + (size_t)ty_*256;
    } else {
      int q = (e - E_DIR)*4;
      int t0 = i2[q+1], t1 = i2[q+2];
      l = s2[c*4+hf] + sR[t0*4+hf] + sR[t1*4+hf];
      r0 = PRm + (size_t)t0*256; r1 = PRm + (size_t)t1*256;
    }
    float v = s1h + l; v = (v >= 0.f) ? v : LRELU*v;
    float w = __expf(v - mxh) * inv;
    const bf16* p2 = P2 + (size_t)c*256 + f0;
    float e0 = b2f(p2[0]) + r0[f0+0];
    float e1 = b2f(p2[1]) + r0[f0+1];
    float e2 = b2f(p2[2]) + r0[f0+2];
    float e3 = b2f(p2[3]) + r0[f0+3];
    if (r1){ e0 += r1[f0+0]; e1 += r1[f0+1]; e2 += r1[f0+2]; e3 += r1[f0+3]; }
    a0 += w*e0; a1 += w*e1; a2 += w*e2; a3 += w*e3;
  }
  float as = sm[hf]*inv;
  const bf16* p1 = P1 + ob;
  a0 += as*b2f(p1[0]); a1 += as*b2f(p1[1]); a2 += as*b2f(p1[2]); a3 += as*b2f(p1[3]);
  stf(&X1[ob+0], (a0 > 0.f) ? a0 : __expf(a0)-1.f);
  stf(&X1[ob+1], (a1 > 0.f) ? a1 : __expf(a1)-1.f);
  stf(&X1[ob+2], (a2 > 0.f) ? a2 : __expf(a2)-1.f);
  stf(&X1[ob+3], (a3 > 0.f) ? a3 : __expf(a3)-1.f);
}

// ---------------- layer-2 aggregation (single head, 256) ----------------
__global__ void agg2(const int* __restrict__ off, const int* __restrict__ perm,
                     const int* __restrict__ ei, const int* __restrict__ et, const int* __restrict__ i2,
                     const float* __restrict__ s1, const float* __restrict__ s2, const float* __restrict__ sR,
                     const bf16* __restrict__ Q1, const bf16* __restrict__ Q2, const float* __restrict__ QRm,
                     float* __restrict__ X2){
  int wid = threadIdx.x >> 6, lane = threadIdx.x & 63;
  int i = blockIdx.x*4 + wid;
  if (i >= N_ENT) return;
  int st = off[i], en = off[i+1];
  int f0 = lane*4;
  size_t ob = (size_t)i*256 + f0;
  if (st == en){
    #pragma unroll
    for (int d = 0; d < 4; d++) X2[ob+d] = 0.f;
    return;
  }
  float s1i = s1[i];
  float mx = -1e30f;
  for (int t = st + lane; t < en; t += 64){
    int e = perm[t];
    int c = e_col(e, ei, i2);
    float l;
    if (e < E_DIR) l = s2[c] + sR[et[e]];
    else { int q = (e - E_DIR)*4; l = s2[c] + sR[i2[q+1]] + sR[i2[q+2]]; }
    float v = s1i + l; v = (v >= 0.f) ? v : LRELU*v;
    mx = fmaxf(mx, v);
  }
  #pragma unroll
  for (int o = 32; o >= 1; o >>= 1) mx = fmaxf(mx, __shfl_xor(mx, o, 64));
  float sm = 0.f;
  for (int t = st + lane; t < en; t += 64){
    int e = perm[t];
    int c = e_col(e, ei, i2);
    float l;
    if (e < E_DIR) l = s2[c] + sR[et[e]];
    else { int q = (e - E_DIR)*4; l = s2[c] + sR[i2[q+1]] + sR[i2[q+2]]; }
    float v = s1i + l; v = (v >= 0.f) ? v : LRELU*v;
    sm += __expf(v - mx);
  }
  #pragma unroll
  for (int o = 32; o >= 1; o >>= 1) sm += __shfl_xor(sm, o, 64);
  float inv = 1.f/(sm + 1e-16f);
  float a0=0,a1=0,a2=0,a3=0;
  for (int t = st; t < en; t++){
    int e = perm[t];
    int c = e_col(e, ei, i2);
    float l; const float* r0; const float* r1 = nullptr;
    if (e < E_DIR){
      int ty_ = et[e];
      l = s2[c] + sR[ty_];
      r0 = QRm + (size_t)ty_*256;
    } else {
      int q = (e - E_DIR)*4;
      int t0 = i2[q+1], t1 = i2[q+2];
      l = s2[c] + sR[t0] + sR[t1];
      r0 = QRm + (size_t)t0*256; r1 = QRm + (size_t)t1*256;
    }
    float v = s1i + l; v = (v >= 0.f) ? v : LRELU*v;
    float w = __expf(v - mx) * inv;
    const bf16* q2 = Q2 + (size_t)c*256 + f0;
    float e0 = b2f(q2[0]) + r0[f0+0];
    float e1 = b2f(q2[1]) + r0[f0+1];
    float e2 = b2f(q2[2]) + r0[f0+2];
    float e3 = b2f(q2[3]) + r0[f0+3];
    if (r1){ e0 += r1[f0+0]; e1 += r1[f0+1]; e2 += r1[f0+2]; e3 += r1[f0+3]; }
    a0 += w*e0; a1 += w*e1; a2 += w*e2; a3 += w*e3;
  }
  float as = sm*inv;
  const bf16* q1 = Q1 + ob;
  a0 += as*b2f(q1[0]); a1 += as*b2f(q1[1]); a2 += as*b2f(q1[2]); a3 += as*b2f(q1[3]);
  X2[ob+0] = (a0 > 0.f) ? a0 : __expf(a0)-1.f;
  X2[ob+1] = (a1 > 0.f) ? a1 : __expf(a1)-1.f;
  X2[ob+2] = (a2 > 0.f) ? a2 : __expf(a2)-1.f;
  X2[ob+3] = (a3 > 0.f) ? a3 : __expf(a3)-1.f;
}

// ---------------- batch norm (in-place over fp32 X in d_out) ----------------
__global__ void bn_reduce(const float* __restrict__ X, float* __restrict__ sums, float* __restrict__ sq){
  int ch = threadIdx.x;
  float s = 0.f, q = 0.f;
  for (int r = blockIdx.x; r < N_ENT; r += gridDim.x){
    float v = X[(size_t)r*256 + ch];
    s += v; q += v*v;
  }
  atomicAdd(&sums[ch], s);
  atomicAdd(&sq[ch], q);
}

__global__ void bn_final(float* __restrict__ X, const float* __restrict__ sums, const float* __restrict__ sq,
                         const float* __restrict__ gamma, const float* __restrict__ beta){
  int idx = blockIdx.x*blockDim.x + threadIdx.x;
  if (idx >= N_ENT*256) return;
  int ch = idx & 255;
  const float invn = 1.f/(float)N_ENT;
  float mean = sums[ch] * invn;
  float var  = fmaxf(sq[ch] * invn - mean*mean, 0.f);
  X[idx] = (X[idx] - mean) * rsqrtf(var + BN_EPS) * gamma[ch] + beta[ch];
}

__global__ void copy_r(const float* __restrict__ RF, float* __restrict__ out){
  int idx = blockIdx.x*blockDim.x + threadIdx.x;
  if (idx < N_REL*256) out[idx] = RF[idx];
}

// ---------------- launch ----------------
extern "C" void kernel_launch(void* const* d_in, const int* in_sizes, int n_in,
                              void* d_out, int out_size, void* d_ws, size_t ws_size,
                              hipStream_t stream){
  const int*   ei  = (const int*)d_in[0];
  const int*   et  = (const int*)d_in[1];
  const int*   i2  = (const int*)d_in[2];
  const float* emb = (const float*)d_in[3];
  const float* rel = (const float*)d_in[4];
  const float* Wh  = (const float*)d_in[5];
  const float* ah  = (const float*)d_in[6];
  const float* gw  = (const float*)d_in[7];
  const float* ow  = (const float*)d_in[8];
  const float* oa  = (const float*)d_in[9];
  const float* we  = (const float*)d_in[10];
  const float* gma = (const float*)d_in[11];
  const float* bta = (const float*)d_in[12];
  float* out = (float*)d_out;

  char* ws = (char*)d_ws;
  size_t o = 0;
  auto alloc = [&](size_t bytes)->char*{
    char* p = ws + o; o = (o + bytes + 255) & ~(size_t)255; return p;
  };
  bf16*  P1  = (bf16*)alloc(20480000);    // P1 -> Q1 (40000x256 bf16)
  bf16*  P2  = (bf16*)alloc(20480000);    // P2 -> Q2
  float* PR  = (float*)alloc(512000);
  float* QR  = (float*)alloc(512000);
  float* RF  = (float*)alloc(512000);     // r in fp32
  float* WA  = (float*)alloc(131072);
  float* WB  = (float*)alloc(131072);
  float* WC  = (float*)alloc(131072);
  bf16*  WAp = (bf16*)alloc(65536);       // packed 128x256
  bf16*  WBp = (bf16*)alloc(65536);
  bf16*  OWp0= (bf16*)alloc(131072);      // packed 256x256 (ow rows 0..255)
  bf16*  OWp1= (bf16*)alloc(131072);      // packed 256x256 (ow rows 256..511)
  float* S1  = (float*)alloc(640000);
  float* S2  = (float*)alloc(640000);
  float* SRm = (float*)alloc(8192);
  float* S1B = (float*)alloc(160000);
  float* S2B = (float*)alloc(160000);
  float* SRB = (float*)alloc(2048);
  int*   CNT = (int*)alloc(160000);
  int*   CUR = (int*)alloc(160000);
  int*   OFF = (int*)alloc(160016);
  int*   PERM= (int*)alloc(1000000);
  float* BNS = (float*)alloc(1024);
  float* BNQ = (float*)alloc(1024);
  // d_out x-region (40.96 MB) staging: X1 bf16 in [0, 20.48MB), embb bf16 in
  // [20.48MB, 30.72MB). Both dead before agg2 writes X2 fp32 over the full region.
  bf16* X1b  = (bf16*)out;
  bf16* embb = (bf16*)((char*)out + 20480000);
  float* X2 = out;
  (void)ws_size; (void)in_sizes; (void)n_in; (void)out_size;

  hipMemsetAsync(CNT, 0, 160000, stream);
  hipMemsetAsync(CUR, 0, 160000, stream);
  hipMemsetAsync(BNS, 0, 1024, stream);
  hipMemsetAsync(BNQ, 0, 1024, stream);

  // weight prep
  repack_W_heads<<<(D_IN*D_EMB+255)/256, 256, 0, stream>>>(Wh, WA, WB, WC);
  pack_B<<<16, 256, 0, stream>>>(WA, WAp, 128);
  pack_B<<<16, 256, 0, stream>>>(WB, WBp, 128);
  pack_B<<<32, 256, 0, stream>>>(ow,          OWp0, 256);
  pack_B<<<32, 256, 0, stream>>>(ow + 65536,  OWp1, 256);
  cvt_f2b<<<(N_ENT*D_IN+255)/256, 256, 0, stream>>>(emb, embb, N_ENT*D_IN);

  // CSR build
  hist_kernel<<<(E_TOT+255)/256, 256, 0, stream>>>(ei, i2, CNT);
  scan40000<<<1, 1024, 0, stream>>>(CNT, OFF);
  scatter_kernel<<<(E_TOT+255)/256, 256, 0, stream>>>(ei, i2, OFF, CUR, PERM);

  // layer-1 projections: MFMA for entity side, fp32 vector for rel side
  dim3 g2((N_REL+63)/64, 4);
  gemm_mfma<<<N_ENT/64, 256, 0, stream>>>((const short*)embb, (const short*)WAp, P1, N_ENT, 128);
  gemm_mfma<<<N_ENT/64, 256, 0, stream>>>((const short*)embb, (const short*)WBp, P2, N_ENT, 128);
  gemm64<float,float,false><<<g2, 256, 0, stream>>>(rel, WC, PR, N_REL, 128);
  gemm64<float,float,false><<<g2, 256, 0, stream>>>(rel, gw, RF, N_REL, 128);

  head_dots4<bf16><<<(N_ENT+3)/4, 256, 0, stream>>>(P1, ah, S1, N_ENT);
  head_dots4<bf16><<<(N_ENT+3)/4, 256, 0, stream>>>(P2, ah, S2, N_ENT);
  head_dots4<float><<<(N_REL+3)/4, 256, 0, stream>>>(PR, ah, SRm, N_REL);

  agg1<bf16><<<N_ENT/4, 256, 0, stream>>>(OFF, PERM, ei, et, i2, S1, S2, SRm, P1, P2, PR, X1b);

  // layer-2 projections: MFMA (Q1/Q2 overwrite P1/P2; A = X1 bf16 in d_out)
  gemm_mfma<<<N_ENT/64, 256, 0, stream>>>((const short*)X1b, (const short*)OWp0, P1, N_ENT, 256);
  gemm_mfma<<<N_ENT/64, 256, 0, stream>>>((const short*)X1b, (const short*)OWp1, P2, N_ENT, 256);
  gemm64<float,float,false><<<g2, 256, 0, stream>>>(RF, ow + 131072, QR, N_REL, 256);

  full_dot<bf16><<<(N_ENT+3)/4, 256, 0, stream>>>(P1, oa, S1B, N_ENT);
  full_dot<bf16><<<(N_ENT+3)/4, 256, 0, stream>>>(P2, oa, S2B, N_ENT);
  full_dot<float><<<(N_REL+3)/4, 256, 0, stream>>>(QR, oa, SRB, N_REL);

  // agg2 writes X2 fp32 over the whole d_out x-region (X1b/embb dead)
  agg2<<<N_ENT/4, 256, 0, stream>>>(OFF, PERM, ei, et, i2, S1B, S2B, SRB, P1, P2, QR, X2);

  // + init_embed @ W_entities (fp32 vector, accumulate into X2 in d_out)
  dim3 g1((N_ENT+63)/64, 4);
  gemm64<float,float,true><<<g1, 256, 0, stream>>>(emb, we, X2, N_ENT, 128);

  // batch norm in place + r output
  bn_reduce<<<256, 256, 0, stream>>>(X2, BNS, BNQ);
  bn_final<<<(N_ENT*256+255)/256, 256, 0, stream>>>(X2, BNS, BNQ, gma, bta);
  copy_r<<<(N_REL*256+255)/256, 256, 0, stream>>>(RF, out + (size_t)N_ENT*256);
}

// Round 6
// 726.592 us; speedup vs baseline: 1.5354x; 1.2648x over previous
//
#include <hip/hip_runtime.h>
#include <hip/hip_bf16.h>
#include <math.h>

#define N_ENT 40000
#define N_REL 500
#define E_DIR 200000
#define E_2HOP 50000
#define E_TOT 250000
#define D_IN 128
#define D_EMB 256
#define LRELU 0.2f
#define BN_EPS 1e-5f

typedef __hip_bfloat16 bf16;
typedef __attribute__((ext_vector_type(8))) short short8;
typedef __attribute__((ext_vector_type(4))) float float4v;

__device__ __forceinline__ float b2f(bf16 v){ return __bfloat162float(v); }
__device__ __forceinline__ float ldf(const float* p){ return *p; }
__device__ __forceinline__ float ldf(const bf16* p){ return b2f(*p); }
__device__ __forceinline__ void stf(float* p, float v){ *p = v; }
__device__ __forceinline__ void stf(bf16* p, float v){ *p = __float2bfloat16(v); }
__device__ __forceinline__ float bitsf(unsigned int u){ return __builtin_bit_cast(float, u); }

// W_heads (4,384,64) fp32 -> Wa/Wb/Wc each (128,256) with col = h*64+j
__global__ void repack_W_heads(const float* __restrict__ Wh, float* __restrict__ Wa,
                               float* __restrict__ Wb, float* __restrict__ Wc){
  int idx = blockIdx.x*blockDim.x + threadIdx.x;
  if (idx >= D_IN*D_EMB) return;
  int k = idx >> 8;
  int colv = idx & 255;
  int h = colv >> 6, j = colv & 63;
  const int HS = 384*64;
  Wa[idx] = Wh[h*HS + k*64 + j];
  Wb[idx] = Wh[h*HS + (k+128)*64 + j];
  Wc[idx] = Wh[h*HS + (k+256)*64 + j];
}

__global__ void cvt_f2b(const float* __restrict__ in, bf16* __restrict__ out, int n){
  int i = blockIdx.x*blockDim.x + threadIdx.x;
  if (i < n) out[i] = __float2bfloat16(in[i]);
}

// Pack fp32 B (K x 256 row-major) into MFMA b_frag-contiguous bf16 layout.
__global__ void pack_B(const float* __restrict__ B, bf16* __restrict__ Bp, int K){
  int idx = blockIdx.x*blockDim.x + threadIdx.x;
  int total = (K >> 5) * 16 * 64;
  if (idx >= total) return;
  int lane = idx & 63;
  int nt = (idx >> 6) & 15;
  int kc = idx >> 10;
  int quad = lane >> 4, l16 = lane & 15;
  int kbase = kc*32 + quad*8;
  int col = nt*16 + l16;
  bf16* dst = Bp + (size_t)idx*8;
  #pragma unroll
  for (int j = 0; j < 8; j++) dst[j] = __float2bfloat16(B[(size_t)(kbase+j)*256 + col]);
}

// ---------------- MFMA GEMM: A (M x K bf16), Bp packed, C (M x 256 bf16) ----------------
__global__ __launch_bounds__(256) void gemm_mfma(const short* __restrict__ A,
                                                 const short* __restrict__ Bp,
                                                 bf16* __restrict__ C, int M, int K){
  int w = threadIdx.x >> 6, lane = threadIdx.x & 63;
  int quad = lane >> 4, l16 = lane & 15;
  int rm = blockIdx.x*64 + w*16;
  int arow = rm + l16;
  float4v acc[16];
  #pragma unroll
  for (int nt = 0; nt < 16; nt++) acc[nt] = (float4v){0.f,0.f,0.f,0.f};
  int nkc = K >> 5;
  for (int kc = 0; kc < nkc; kc++){
    short8 a = *(const short8*)(A + (size_t)arow*K + kc*32 + quad*8);
    const short8* bp = (const short8*)(Bp + ((size_t)(kc*16)*64 + lane)*8);
    #pragma unroll
    for (int nt = 0; nt < 16; nt++){
      short8 b = bp[(size_t)nt*64];
      acc[nt] = __builtin_amdgcn_mfma_f32_16x16x32_bf16(a, b, acc[nt], 0, 0, 0);
    }
  }
  #pragma unroll
  for (int nt = 0; nt < 16; nt++){
    #pragma unroll
    for (int r = 0; r < 4; r++){
      int row = quad*4 + r;
      C[(size_t)(rm + row)*256 + nt*16 + l16] = __float2bfloat16(acc[nt][r]);
    }
  }
}

// ---------------- generic tiled fp32 GEMM, N fixed = 256 ----------------
template<typename AT, typename CT, bool ACCUM>
__global__ void gemm64(const AT* __restrict__ A, const float* __restrict__ B,
                       CT* __restrict__ C, int M, int K){
  const int N = 256;
  __shared__ float As[16][65];
  __shared__ float Bs[16][65];
  int bm = blockIdx.x * 64, bn = blockIdx.y * 64;
  int tid = threadIdx.x;
  int tx = tid & 15, ty = tid >> 4;
  float acc[4][4] = {};
  for (int k0 = 0; k0 < K; k0 += 16){
    #pragma unroll
    for (int j = 0; j < 4; j++){
      int idx = tid + j*256;
      int m = idx >> 4, kk = idx & 15;
      int gm = bm + m;
      float v = 0.f;
      if (gm < M) v = ldf(&A[(size_t)gm*K + k0 + kk]);
      As[kk][m] = v;
    }
    #pragma unroll
    for (int j = 0; j < 4; j++){
      int idx = tid + j*256;
      int kk = idx >> 6, n = idx & 63;
      Bs[kk][n] = B[(size_t)(k0+kk)*N + bn + n];
    }
    __syncthreads();
    #pragma unroll
    for (int kk = 0; kk < 16; kk++){
      float a[4], b[4];
      #pragma unroll
      for (int i = 0; i < 4; i++) a[i] = As[kk][ty*4+i];
      #pragma unroll
      for (int j = 0; j < 4; j++) b[j] = Bs[kk][tx*4+j];
      #pragma unroll
      for (int i = 0; i < 4; i++)
        #pragma unroll
        for (int j = 0; j < 4; j++) acc[i][j] += a[i]*b[j];
    }
    __syncthreads();
  }
  #pragma unroll
  for (int i = 0; i < 4; i++){
    int gm = bm + ty*4 + i;
    if (gm >= M) continue;
    #pragma unroll
    for (int j = 0; j < 4; j++){
      size_t o = (size_t)gm*N + bn + tx*4 + j;
      if (ACCUM) stf(&C[o], ldf(&C[o]) + acc[i][j]);
      else       stf(&C[o], acc[i][j]);
    }
  }
}

// ---------------- per-head / full dots ----------------
template<typename PT>
__global__ void head_dots4(const PT* __restrict__ P, const float* __restrict__ a,
                           float* __restrict__ s, int M){
  int wid = threadIdx.x >> 6, lane = threadIdx.x & 63;
  int i = blockIdx.x*4 + wid;
  if (i >= M) return;
  int f0 = lane*4;
  float p = 0.f;
  #pragma unroll
  for (int d = 0; d < 4; d++) p += ldf(&P[(size_t)i*256 + f0 + d]) * a[f0+d];
  #pragma unroll
  for (int o = 8; o >= 1; o >>= 1) p += __shfl_xor(p, o, 64);
  if ((lane & 15) == 0) s[i*4 + (lane>>4)] = p;
}

template<typename PT>
__global__ void full_dot(const PT* __restrict__ P, const float* __restrict__ a,
                         float* __restrict__ s, int M){
  int wid = threadIdx.x >> 6, lane = threadIdx.x & 63;
  int i = blockIdx.x*4 + wid;
  if (i >= M) return;
  int f0 = lane*4;
  float p = 0.f;
  #pragma unroll
  for (int d = 0; d < 4; d++) p += ldf(&P[(size_t)i*256 + f0 + d]) * a[f0+d];
  #pragma unroll
  for (int o = 32; o >= 1; o >>= 1) p += __shfl_xor(p, o, 64);
  if (lane == 0) s[i] = p;
}

// ---------------- CSR build ----------------
__device__ __forceinline__ int e_row(int e, const int* ei, const int* i2){
  return (e < E_DIR) ? ei[E_DIR + e] : i2[(e - E_DIR)*4 + 3];
}

__global__ void hist_kernel(const int* __restrict__ ei, const int* __restrict__ i2, int* __restrict__ cnt){
  int e = blockIdx.x*blockDim.x + threadIdx.x;
  if (e < E_TOT) atomicAdd(&cnt[e_row(e, ei, i2)], 1);
}

__global__ void scan40000(const int* __restrict__ cnt, int* __restrict__ off){
  __shared__ int part[1024];
  int tid = threadIdx.x;
  const int CH = 40;
  int base = tid * CH;
  int s = 0;
  for (int i = 0; i < CH; i++){ int idx = base + i; if (idx < N_ENT) s += cnt[idx]; }
  part[tid] = s;
  __syncthreads();
  for (int o = 1; o < 1024; o <<= 1){
    int v = (tid >= o) ? part[tid-o] : 0;
    __syncthreads();
    part[tid] += v;
    __syncthreads();
  }
  int run = (tid > 0) ? part[tid-1] : 0;
  for (int i = 0; i < CH; i++){
    int idx = base + i;
    if (idx < N_ENT){ off[idx] = run; run += cnt[idx]; }
  }
  if (tid == 0) off[N_ENT] = part[1023];
}

__global__ void scatter_kernel(const int* __restrict__ ei, const int* __restrict__ i2,
                               const int* __restrict__ off, int* __restrict__ cur,
                               int* __restrict__ perm, int* __restrict__ rowp){
  int e = blockIdx.x*blockDim.x + threadIdx.x;
  if (e >= E_TOT) return;
  int r = e_row(e, ei, i2);
  int p = atomicAdd(&cur[r], 1);
  int d = off[r] + p;
  perm[d] = e; rowp[d] = r;
}

// per-slot col / rel indices in permuted order
__global__ void edge_prep(const int* __restrict__ perm, const int* __restrict__ ei,
                          const int* __restrict__ et, const int* __restrict__ i2,
                          int* __restrict__ cperm, int* __restrict__ r0i, int* __restrict__ r1i){
  int t = blockIdx.x*blockDim.x + threadIdx.x;
  if (t >= E_TOT) return;
  int e = perm[t];
  if (e < E_DIR){ cperm[t] = ei[e]; r0i[t] = et[e]; r1i[t] = -1; }
  else { int q = (e - E_DIR)*4; cperm[t] = i2[q]; r0i[t] = i2[q+1]; r1i[t] = i2[q+2]; }
}

// layer-1 logits (leaky applied), head-plane layout L1[h*E_TOT + t]
__global__ void elog1(const int* __restrict__ rowp, const int* __restrict__ cperm,
                      const int* __restrict__ r0i, const int* __restrict__ r1i,
                      const float* __restrict__ s1, const float* __restrict__ s2,
                      const float* __restrict__ sR, float* __restrict__ L1){
  int t = blockIdx.x*blockDim.x + threadIdx.x;
  if (t >= E_TOT) return;
  int r = rowp[t], c = cperm[t], i0 = r0i[t], i1 = r1i[t];
  #pragma unroll
  for (int h = 0; h < 4; h++){
    float v = s1[r*4+h] + s2[c*4+h] + sR[i0*4+h];
    if (i1 >= 0) v += sR[i1*4+h];
    v = (v >= 0.f) ? v : LRELU*v;
    L1[(size_t)h*E_TOT + t] = v;
  }
}

__global__ void elog2(const int* __restrict__ rowp, const int* __restrict__ cperm,
                      const int* __restrict__ r0i, const int* __restrict__ r1i,
                      const float* __restrict__ s1, const float* __restrict__ s2,
                      const float* __restrict__ sR, float* __restrict__ L2){
  int t = blockIdx.x*blockDim.x + threadIdx.x;
  if (t >= E_TOT) return;
  int r = rowp[t], c = cperm[t], i0 = r0i[t], i1 = r1i[t];
  float v = s1[r] + s2[c] + sR[i0];
  if (i1 >= 0) v += sR[i1];
  v = (v >= 0.f) ? v : LRELU*v;
  L2[t] = v;
}

// ---------------- layer-1 aggregation ----------------
__global__ __launch_bounds__(256) void agg1(const int* __restrict__ off,
    const int* __restrict__ cperm, const int* __restrict__ r0i, const int* __restrict__ r1i,
    const float* __restrict__ L1, const bf16* __restrict__ P1, const bf16* __restrict__ P2,
    const float* __restrict__ PRm, bf16* __restrict__ X1){
  int wid = threadIdx.x >> 6, lane = threadIdx.x & 63;
  int i = blockIdx.x*4 + wid;
  if (i >= N_ENT) return;
  int st = off[i], en = off[i+1];
  int hf = lane >> 4, l16 = lane & 15, f0 = lane*4;
  size_t ob = (size_t)i*256 + f0;
  if (st == en){
    #pragma unroll
    for (int d = 0; d < 4; d++) X1[ob+d] = __float2bfloat16(0.f);
    return;
  }
  const float* Lh = L1 + (size_t)hf*E_TOT;
  float mx = -1e30f;
  for (int t = st + l16; t < en; t += 16) mx = fmaxf(mx, Lh[t]);
  #pragma unroll
  for (int o = 8; o >= 1; o >>= 1) mx = fmaxf(mx, __shfl_xor(mx, o, 64));
  float sm = 0.f;
  for (int t = st + l16; t < en; t += 16) sm += __expf(Lh[t] - mx);
  #pragma unroll
  for (int o = 8; o >= 1; o >>= 1) sm += __shfl_xor(sm, o, 64);
  float inv = 1.f/(sm + 1e-16f);
  float a0=0,a1=0,a2=0,a3=0;
  #pragma unroll 2
  for (int t = st; t < en; t++){
    float w = __expf(Lh[t] - mx) * inv;
    int c = cperm[t], i0 = r0i[t], i1 = r1i[t];
    uint2 u = *(const uint2*)(P2 + (size_t)c*256 + f0);
    float4 rv = *(const float4*)(PRm + (size_t)i0*256 + f0);
    float e0 = bitsf(u.x << 16) + rv.x;
    float e1 = bitsf(u.x & 0xffff0000u) + rv.y;
    float e2 = bitsf(u.y << 16) + rv.z;
    float e3 = bitsf(u.y & 0xffff0000u) + rv.w;
    if (i1 >= 0){
      float4 r1v = *(const float4*)(PRm + (size_t)i1*256 + f0);
      e0 += r1v.x; e1 += r1v.y; e2 += r1v.z; e3 += r1v.w;
    }
    a0 += w*e0; a1 += w*e1; a2 += w*e2; a3 += w*e3;
  }
  float as = sm*inv;
  uint2 up = *(const uint2*)(P1 + ob);
  a0 += as*bitsf(up.x << 16);
  a1 += as*bitsf(up.x & 0xffff0000u);
  a2 += as*bitsf(up.y << 16);
  a3 += as*bitsf(up.y & 0xffff0000u);
  X1[ob+0] = __float2bfloat16((a0 > 0.f) ? a0 : __expf(a0)-1.f);
  X1[ob+1] = __float2bfloat16((a1 > 0.f) ? a1 : __expf(a1)-1.f);
  X1[ob+2] = __float2bfloat16((a2 > 0.f) ? a2 : __expf(a2)-1.f);
  X1[ob+3] = __float2bfloat16((a3 > 0.f) ? a3 : __expf(a3)-1.f);
}

// ---------------- layer-2 aggregation (+ optional EP epilogue) ----------------
__global__ __launch_bounds__(256) void agg2(const int* __restrict__ off,
    const int* __restrict__ cperm, const int* __restrict__ r0i, const int* __restrict__ r1i,
    const float* __restrict__ L2, const bf16* __restrict__ Q1, const bf16* __restrict__ Q2,
    const float* __restrict__ QRm, const bf16* __restrict__ EP, float* __restrict__ X2){
  int wid = threadIdx.x >> 6, lane = threadIdx.x & 63;
  int i = blockIdx.x*4 + wid;
  if (i >= N_ENT) return;
  int st = off[i], en = off[i+1];
  int f0 = lane*4;
  size_t ob = (size_t)i*256 + f0;
  float ep0=0.f, ep1=0.f, ep2=0.f, ep3=0.f;
  if (EP){
    uint2 ue = *(const uint2*)(EP + ob);
    ep0 = bitsf(ue.x << 16); ep1 = bitsf(ue.x & 0xffff0000u);
    ep2 = bitsf(ue.y << 16); ep3 = bitsf(ue.y & 0xffff0000u);
  }
  if (st == en){
    X2[ob+0] = ep0; X2[ob+1] = ep1; X2[ob+2] = ep2; X2[ob+3] = ep3;
    return;
  }
  float mx = -1e30f;
  for (int t = st + lane; t < en; t += 64) mx = fmaxf(mx, L2[t]);
  #pragma unroll
  for (int o = 32; o >= 1; o >>= 1) mx = fmaxf(mx, __shfl_xor(mx, o, 64));
  float sm = 0.f;
  for (int t = st + lane; t < en; t += 64) sm += __expf(L2[t] - mx);
  #pragma unroll
  for (int o = 32; o >= 1; o >>= 1) sm += __shfl_xor(sm, o, 64);
  float inv = 1.f/(sm + 1e-16f);
  float a0=0,a1=0,a2=0,a3=0;
  #pragma unroll 2
  for (int t = st; t < en; t++){
    float w = __expf(L2[t] - mx) * inv;
    int c = cperm[t], i0 = r0i[t], i1 = r1i[t];
    uint2 u = *(const uint2*)(Q2 + (size_t)c*256 + f0);
    float4 rv = *(const float4*)(QRm + (size_t)i0*256 + f0);
    float e0 = bitsf(u.x << 16) + rv.x;
    float e1 = bitsf(u.x & 0xffff0000u) + rv.y;
    float e2 = bitsf(u.y << 16) + rv.z;
    float e3 = bitsf(u.y & 0xffff0000u) + rv.w;
    if (i1 >= 0){
      float4 r1v = *(const float4*)(QRm + (size_t)i1*256 + f0);
      e0 += r1v.x; e1 += r1v.y; e2 += r1v.z; e3 += r1v.w;
    }
    a0 += w*e0; a1 += w*e1; a2 += w*e2; a3 += w*e3;
  }
  float as = sm*inv;
  uint2 uq = *(const uint2*)(Q1 + ob);
  a0 += as*bitsf(uq.x << 16);
  a1 += as*bitsf(uq.x & 0xffff0000u);
  a2 += as*bitsf(uq.y << 16);
  a3 += as*bitsf(uq.y & 0xffff0000u);
  X2[ob+0] = ((a0 > 0.f) ? a0 : __expf(a0)-1.f) + ep0;
  X2[ob+1] = ((a1 > 0.f) ? a1 : __expf(a1)-1.f) + ep1;
  X2[ob+2] = ((a2 > 0.f) ? a2 : __expf(a2)-1.f) + ep2;
  X2[ob+3] = ((a3 > 0.f) ? a3 : __expf(a3)-1.f) + ep3;
}

// ---------------- batch norm (in-place over fp32 X in d_out) ----------------
__global__ void bn_reduce(const float* __restrict__ X, float* __restrict__ sums, float* __restrict__ sq){
  int ch = threadIdx.x;
  float s = 0.f, q = 0.f;
  for (int r = blockIdx.x; r < N_ENT; r += gridDim.x){
    float v = X[(size_t)r*256 + ch];
    s += v; q += v*v;
  }
  atomicAdd(&sums[ch], s);
  atomicAdd(&sq[ch], q);
}

__global__ void bn_final(float* __restrict__ X, const float* __restrict__ sums, const float* __restrict__ sq,
                         const float* __restrict__ gamma, const float* __restrict__ beta){
  int idx = blockIdx.x*blockDim.x + threadIdx.x;
  if (idx >= N_ENT*256) return;
  int ch = idx & 255;
  const float invn = 1.f/(float)N_ENT;
  float mean = sums[ch] * invn;
  float var  = fmaxf(sq[ch] * invn - mean*mean, 0.f);
  X[idx] = (X[idx] - mean) * rsqrtf(var + BN_EPS) * gamma[ch] + beta[ch];
}

__global__ void copy_r(const float* __restrict__ RF, float* __restrict__ out){
  int idx = blockIdx.x*blockDim.x + threadIdx.x;
  if (idx < N_REL*256) out[idx] = RF[idx];
}

// ---------------- launch ----------------
extern "C" void kernel_launch(void* const* d_in, const int* in_sizes, int n_in,
                              void* d_out, int out_size, void* d_ws, size_t ws_size,
                              hipStream_t stream){
  const int*   ei  = (const int*)d_in[0];
  const int*   et  = (const int*)d_in[1];
  const int*   i2  = (const int*)d_in[2];
  const float* emb = (const float*)d_in[3];
  const float* rel = (const float*)d_in[4];
  const float* Wh  = (const float*)d_in[5];
  const float* ah  = (const float*)d_in[6];
  const float* gw  = (const float*)d_in[7];
  const float* ow  = (const float*)d_in[8];
  const float* oa  = (const float*)d_in[9];
  const float* we  = (const float*)d_in[10];
  const float* gma = (const float*)d_in[11];
  const float* bta = (const float*)d_in[12];
  float* out = (float*)d_out;

  char* ws = (char*)d_ws;
  size_t o = 0;
  auto alloc = [&](size_t bytes)->char*{
    char* p = ws + o; o = (o + bytes + 255) & ~(size_t)255; return p;
  };
  bf16*  P1  = (bf16*)alloc(20480000);    // P1 -> Q1 (40000x256 bf16)
  bf16*  P2  = (bf16*)alloc(20480000);    // P2 -> Q2
  float* PR  = (float*)alloc(512000);
  float* QR  = (float*)alloc(512000);
  float* RF  = (float*)alloc(512000);
  float* WA  = (float*)alloc(131072);
  float* WB  = (float*)alloc(131072);
  float* WC  = (float*)alloc(131072);
  bf16*  WAp = (bf16*)alloc(65536);
  bf16*  WBp = (bf16*)alloc(65536);
  bf16*  OWp0= (bf16*)alloc(131072);
  bf16*  OWp1= (bf16*)alloc(131072);
  float* S1  = (float*)alloc(640000);
  float* S2  = (float*)alloc(640000);
  float* SRm = (float*)alloc(8192);
  float* S1B = (float*)alloc(160000);
  float* S2B = (float*)alloc(160000);
  float* SRB = (float*)alloc(2048);
  int*   CNT = (int*)alloc(160000);
  int*   CUR = (int*)alloc(160000);
  int*   OFF = (int*)alloc(160016);
  int*   PERM= (int*)alloc(1000000);
  int*   ROWP= (int*)alloc(1000000);
  int*   CPERM=(int*)alloc(1000000);
  int*   R0I = (int*)alloc(1000000);
  int*   R1I = (int*)alloc(1000000);
  float* L1  = (float*)alloc(4000000);    // 4 head planes
  float* L2  = (float*)alloc(1000000);
  float* BNS = (float*)alloc(1024);
  float* BNQ = (float*)alloc(1024);
  // conditional EP (emb @ W_entities via MFMA)
  size_t base_end = o;
  bool useEP = (ws_size >= base_end + 65536 + 20480256 + 512);
  bf16* WEp = nullptr; bf16* EP = nullptr;
  if (useEP){ WEp = (bf16*)alloc(65536); EP = (bf16*)alloc(20480000); }
  // d_out staging: X1 bf16 [0,20.48MB), embb bf16 [20.48,30.72MB); X2 fp32 full region later.
  bf16* X1b  = (bf16*)out;
  bf16* embb = (bf16*)((char*)out + 20480000);
  float* X2 = out;
  (void)in_sizes; (void)n_in; (void)out_size;

  hipMemsetAsync(CNT, 0, 160000, stream);
  hipMemsetAsync(CUR, 0, 160000, stream);
  hipMemsetAsync(BNS, 0, 1024, stream);
  hipMemsetAsync(BNQ, 0, 1024, stream);

  // weight prep
  repack_W_heads<<<(D_IN*D_EMB+255)/256, 256, 0, stream>>>(Wh, WA, WB, WC);
  pack_B<<<16, 256, 0, stream>>>(WA, WAp, 128);
  pack_B<<<16, 256, 0, stream>>>(WB, WBp, 128);
  pack_B<<<32, 256, 0, stream>>>(ow,          OWp0, 256);
  pack_B<<<32, 256, 0, stream>>>(ow + 65536,  OWp1, 256);
  if (useEP) pack_B<<<16, 256, 0, stream>>>(we, WEp, 128);
  cvt_f2b<<<(N_ENT*D_IN+255)/256, 256, 0, stream>>>(emb, embb, N_ENT*D_IN);

  // CSR build + edge precompute
  hist_kernel<<<(E_TOT+255)/256, 256, 0, stream>>>(ei, i2, CNT);
  scan40000<<<1, 1024, 0, stream>>>(CNT, OFF);
  scatter_kernel<<<(E_TOT+255)/256, 256, 0, stream>>>(ei, i2, OFF, CUR, PERM, ROWP);
  edge_prep<<<(E_TOT+255)/256, 256, 0, stream>>>(PERM, ei, et, i2, CPERM, R0I, R1I);

  // layer-1 projections
  dim3 g2((N_REL+63)/64, 4);
  gemm_mfma<<<N_ENT/64, 256, 0, stream>>>((const short*)embb, (const short*)WAp, P1, N_ENT, 128);
  gemm_mfma<<<N_ENT/64, 256, 0, stream>>>((const short*)embb, (const short*)WBp, P2, N_ENT, 128);
  gemm64<float,float,false><<<g2, 256, 0, stream>>>(rel, WC, PR, N_REL, 128);
  gemm64<float,float,false><<<g2, 256, 0, stream>>>(rel, gw, RF, N_REL, 128);
  if (useEP)
    gemm_mfma<<<N_ENT/64, 256, 0, stream>>>((const short*)embb, (const short*)WEp, EP, N_ENT, 128);

  head_dots4<bf16><<<(N_ENT+3)/4, 256, 0, stream>>>(P1, ah, S1, N_ENT);
  head_dots4<bf16><<<(N_ENT+3)/4, 256, 0, stream>>>(P2, ah, S2, N_ENT);
  head_dots4<float><<<(N_REL+3)/4, 256, 0, stream>>>(PR, ah, SRm, N_REL);

  elog1<<<(E_TOT+255)/256, 256, 0, stream>>>(ROWP, CPERM, R0I, R1I, S1, S2, SRm, L1);
  agg1<<<N_ENT/4, 256, 0, stream>>>(OFF, CPERM, R0I, R1I, L1, P1, P2, PR, X1b);

  // layer-2 projections (Q1/Q2 overwrite P1/P2)
  gemm_mfma<<<N_ENT/64, 256, 0, stream>>>((const short*)X1b, (const short*)OWp0, P1, N_ENT, 256);
  gemm_mfma<<<N_ENT/64, 256, 0, stream>>>((const short*)X1b, (const short*)OWp1, P2, N_ENT, 256);
  gemm64<float,float,false><<<g2, 256, 0, stream>>>(RF, ow + 131072, QR, N_REL, 256);

  full_dot<bf16><<<(N_ENT+3)/4, 256, 0, stream>>>(P1, oa, S1B, N_ENT);
  full_dot<bf16><<<(N_ENT+3)/4, 256, 0, stream>>>(P2, oa, S2B, N_ENT);
  full_dot<float><<<(N_REL+3)/4, 256, 0, stream>>>(QR, oa, SRB, N_REL);

  elog2<<<(E_TOT+255)/256, 256, 0, stream>>>(ROWP, CPERM, R0I, R1I, S1B, S2B, SRB, L2);
  agg2<<<N_ENT/4, 256, 0, stream>>>(OFF, CPERM, R0I, R1I, L2, P1, P2, QR, EP, X2);

  if (!useEP){
    dim3 g1((N_ENT+63)/64, 4);
    gemm64<float,float,true><<<g1, 256, 0, stream>>>(emb, we, X2, N_ENT, 128);
  }

  bn_reduce<<<256, 256, 0, stream>>>(X2, BNS, BNQ);
  bn_final<<<(N_ENT*256+255)/256, 256, 0, stream>>>(X2, BNS, BNQ, gma, bta);
  copy_r<<<(N_REL*256+255)/256, 256, 0, stream>>>(RF, out + (size_t)N_ENT*256);
}

// Round 7
// 695.416 us; speedup vs baseline: 1.6043x; 1.0448x over previous
//
#include <hip/hip_runtime.h>
#include <hip/hip_bf16.h>
#include <math.h>

#define N_ENT 40000
#define N_REL 500
#define E_DIR 200000
#define E_2HOP 50000
#define E_TOT 250000
#define D_IN 128
#define D_EMB 256
#define LRELU 0.2f
#define BN_EPS 1e-5f

typedef __hip_bfloat16 bf16;
typedef __attribute__((ext_vector_type(8))) short short8;
typedef __attribute__((ext_vector_type(4))) float float4v;

__device__ __forceinline__ float b2f(bf16 v){ return __bfloat162float(v); }
__device__ __forceinline__ float ldf(const float* p){ return *p; }
__device__ __forceinline__ float ldf(const bf16* p){ return b2f(*p); }
__device__ __forceinline__ void stf(float* p, float v){ *p = v; }
__device__ __forceinline__ void stf(bf16* p, float v){ *p = __float2bfloat16(v); }
__device__ __forceinline__ float bitsf(unsigned int u){ return __builtin_bit_cast(float, u); }
__device__ __forceinline__ unsigned short bbits(float v){ return __builtin_bit_cast(unsigned short, __float2bfloat16(v)); }

// ---------------- fused weight prep ----------------
// seg0 blocks[0,16): WAp  seg1 [16,32): WBp  seg2 [32,48): WEp
// seg3 [48,80): OWp0      seg4 [80,112): OWp1  seg5 [112,240): WC fp32
__global__ void prep_weights(const float* __restrict__ Wh, const float* __restrict__ ow,
                             const float* __restrict__ we,
                             bf16* __restrict__ WAp, bf16* __restrict__ WBp, bf16* __restrict__ WEp,
                             bf16* __restrict__ OWp0, bf16* __restrict__ OWp1, float* __restrict__ WC){
  const int HS = 384*64;
  int b = blockIdx.x, tid = threadIdx.x;
  if (b < 112){
    int seg, base;
    if      (b < 16){ seg = 0; base = 0; }
    else if (b < 32){ seg = 1; base = 16; }
    else if (b < 48){ seg = 2; base = 32; }
    else if (b < 80){ seg = 3; base = 48; }
    else            { seg = 4; base = 80; }
    int idx = (b - base)*256 + tid;
    int lane = idx & 63, nt = (idx >> 6) & 15, kc = idx >> 10;
    int quad = lane >> 4, l16 = lane & 15;
    int col = nt*16 + l16;
    int kbase = kc*32 + quad*8;
    bf16* dst = (seg==0?WAp : seg==1?WBp : seg==2?WEp : seg==3?OWp0 : OWp1) + (size_t)idx*8;
    #pragma unroll
    for (int j = 0; j < 8; j++){
      int k = kbase + j;
      float v;
      if      (seg == 0) v = Wh[(col>>6)*HS + k*64 + (col&63)];
      else if (seg == 1) v = Wh[(col>>6)*HS + (k+128)*64 + (col&63)];
      else if (seg == 2) v = we[(size_t)k*256 + col];
      else if (seg == 3) v = ow[(size_t)k*256 + col];
      else               v = ow[(size_t)(k+256)*256 + col];
      dst[j] = __float2bfloat16(v);
    }
  } else {
    int idx = (b - 112)*256 + tid;   // [0, 32768)
    int k = idx >> 8, col = idx & 255;
    WC[idx] = Wh[(col>>6)*HS + (k+256)*64 + (col&63)];
  }
}

__global__ void cvt_f2b(const float* __restrict__ in, bf16* __restrict__ out, int n){
  int i = blockIdx.x*blockDim.x + threadIdx.x;
  if (i < n) out[i] = __float2bfloat16(in[i]);
}

// ---------------- MFMA GEMM multi (select B/C by blockIdx.y) ----------------
__global__ __launch_bounds__(256) void gemm_mfma_multi(const short* __restrict__ A,
    const short* __restrict__ B0, const short* __restrict__ B1, const short* __restrict__ B2,
    bf16* __restrict__ C0, bf16* __restrict__ C1, bf16* __restrict__ C2, int K){
  const short* Bp = blockIdx.y==0 ? B0 : (blockIdx.y==1 ? B1 : B2);
  bf16* C = blockIdx.y==0 ? C0 : (blockIdx.y==1 ? C1 : C2);
  int w = threadIdx.x >> 6, lane = threadIdx.x & 63;
  int quad = lane >> 4, l16 = lane & 15;
  int rm = blockIdx.x*64 + w*16;
  int arow = rm + l16;
  float4v acc[16];
  #pragma unroll
  for (int nt = 0; nt < 16; nt++) acc[nt] = (float4v){0.f,0.f,0.f,0.f};
  int nkc = K >> 5;
  for (int kc = 0; kc < nkc; kc++){
    short8 a = *(const short8*)(A + (size_t)arow*K + kc*32 + quad*8);
    const short8* bp = (const short8*)(Bp + ((size_t)(kc*16)*64 + lane)*8);
    #pragma unroll
    for (int nt = 0; nt < 16; nt++){
      short8 b = bp[(size_t)nt*64];
      acc[nt] = __builtin_amdgcn_mfma_f32_16x16x32_bf16(a, b, acc[nt], 0, 0, 0);
    }
  }
  #pragma unroll
  for (int nt = 0; nt < 16; nt++){
    #pragma unroll
    for (int r = 0; r < 4; r++){
      int row = quad*4 + r;
      C[(size_t)(rm + row)*256 + nt*16 + l16] = __float2bfloat16(acc[nt][r]);
    }
  }
}

// ---------------- fp32 tiled GEMM (pair-select via blockIdx.z) ----------------
__global__ void gemm64_sel(const float* __restrict__ A,
                           const float* __restrict__ B0, float* __restrict__ C0,
                           const float* __restrict__ B1, float* __restrict__ C1,
                           int M, int K){
  const float* B = blockIdx.z ? B1 : B0;
  float* C = blockIdx.z ? C1 : C0;
  const int N = 256;
  __shared__ float As[16][65];
  __shared__ float Bs[16][65];
  int bm = blockIdx.x * 64, bn = blockIdx.y * 64;
  int tid = threadIdx.x;
  int tx = tid & 15, ty = tid >> 4;
  float acc[4][4] = {};
  for (int k0 = 0; k0 < K; k0 += 16){
    #pragma unroll
    for (int j = 0; j < 4; j++){
      int idx = tid + j*256;
      int m = idx >> 4, kk = idx & 15;
      int gm = bm + m;
      float v = 0.f;
      if (gm < M) v = A[(size_t)gm*K + k0 + kk];
      As[kk][m] = v;
    }
    #pragma unroll
    for (int j = 0; j < 4; j++){
      int idx = tid + j*256;
      int kk = idx >> 6, n = idx & 63;
      Bs[kk][n] = B[(size_t)(k0+kk)*N + bn + n];
    }
    __syncthreads();
    #pragma unroll
    for (int kk = 0; kk < 16; kk++){
      float a[4], b[4];
      #pragma unroll
      for (int i = 0; i < 4; i++) a[i] = As[kk][ty*4+i];
      #pragma unroll
      for (int j = 0; j < 4; j++) b[j] = Bs[kk][tx*4+j];
      #pragma unroll
      for (int i = 0; i < 4; i++)
        #pragma unroll
        for (int j = 0; j < 4; j++) acc[i][j] += a[i]*b[j];
    }
    __syncthreads();
  }
  #pragma unroll
  for (int i = 0; i < 4; i++){
    int gm = bm + ty*4 + i;
    if (gm >= M) continue;
    #pragma unroll
    for (int j = 0; j < 4; j++)
      C[(size_t)gm*N + bn + tx*4 + j] = acc[i][j];
  }
}

// fp32 accumulate GEMM (fallback when EP doesn't fit ws)
template<bool ACCUM>
__global__ void gemm64_acc(const float* __restrict__ A, const float* __restrict__ B,
                           float* __restrict__ C, int M, int K){
  const int N = 256;
  __shared__ float As[16][65];
  __shared__ float Bs[16][65];
  int bm = blockIdx.x * 64, bn = blockIdx.y * 64;
  int tid = threadIdx.x;
  int tx = tid & 15, ty = tid >> 4;
  float acc[4][4] = {};
  for (int k0 = 0; k0 < K; k0 += 16){
    #pragma unroll
    for (int j = 0; j < 4; j++){
      int idx = tid + j*256;
      int m = idx >> 4, kk = idx & 15;
      int gm = bm + m;
      float v = 0.f;
      if (gm < M) v = A[(size_t)gm*K + k0 + kk];
      As[kk][m] = v;
    }
    #pragma unroll
    for (int j = 0; j < 4; j++){
      int idx = tid + j*256;
      int kk = idx >> 6, n = idx & 63;
      Bs[kk][n] = B[(size_t)(k0+kk)*N + bn + n];
    }
    __syncthreads();
    #pragma unroll
    for (int kk = 0; kk < 16; kk++){
      float a[4], b[4];
      #pragma unroll
      for (int i = 0; i < 4; i++) a[i] = As[kk][ty*4+i];
      #pragma unroll
      for (int j = 0; j < 4; j++) b[j] = Bs[kk][tx*4+j];
      #pragma unroll
      for (int i = 0; i < 4; i++)
        #pragma unroll
        for (int j = 0; j < 4; j++) acc[i][j] += a[i]*b[j];
    }
    __syncthreads();
  }
  #pragma unroll
  for (int i = 0; i < 4; i++){
    int gm = bm + ty*4 + i;
    if (gm >= M) continue;
    #pragma unroll
    for (int j = 0; j < 4; j++){
      size_t o = (size_t)gm*N + bn + tx*4 + j;
      if (ACCUM) C[o] += acc[i][j]; else C[o] = acc[i][j];
    }
  }
}

// ---------------- fused dots: per-head (16-lane) over P1,P2,PR ----------------
__global__ void dots3(const bf16* __restrict__ P1, const bf16* __restrict__ P2,
                      const float* __restrict__ PR, const float* __restrict__ a,
                      float* __restrict__ S1, float* __restrict__ S2, float* __restrict__ SR){
  int b = blockIdx.x;
  int wid = threadIdx.x >> 6, lane = threadIdx.x & 63;
  int f0 = lane*4;
  float p = 0.f;
  if (b < 20000){
    const bf16* P = (b < 10000) ? P1 : P2;
    float* S = (b < 10000) ? S1 : S2;
    int i = ((b < 10000) ? b : b - 10000)*4 + wid;
    #pragma unroll
    for (int d = 0; d < 4; d++) p += b2f(P[(size_t)i*256 + f0 + d]) * a[f0+d];
    #pragma unroll
    for (int o = 8; o >= 1; o >>= 1) p += __shfl_xor(p, o, 64);
    if ((lane & 15) == 0) S[i*4 + (lane>>4)] = p;
  } else {
    int i = (b - 20000)*4 + wid;
    if (i >= N_REL) return;
    #pragma unroll
    for (int d = 0; d < 4; d++) p += PR[(size_t)i*256 + f0 + d] * a[f0+d];
    #pragma unroll
    for (int o = 8; o >= 1; o >>= 1) p += __shfl_xor(p, o, 64);
    if ((lane & 15) == 0) SR[i*4 + (lane>>4)] = p;
  }
}

// fused full dots (64-lane) over Q1,Q2,QR
__global__ void fdots3(const bf16* __restrict__ Q1, const bf16* __restrict__ Q2,
                       const float* __restrict__ QR, const float* __restrict__ a,
                       float* __restrict__ S1, float* __restrict__ S2, float* __restrict__ SR){
  int b = blockIdx.x;
  int wid = threadIdx.x >> 6, lane = threadIdx.x & 63;
  int f0 = lane*4;
  float p = 0.f;
  if (b < 20000){
    const bf16* P = (b < 10000) ? Q1 : Q2;
    float* S = (b < 10000) ? S1 : S2;
    int i = ((b < 10000) ? b : b - 10000)*4 + wid;
    #pragma unroll
    for (int d = 0; d < 4; d++) p += b2f(P[(size_t)i*256 + f0 + d]) * a[f0+d];
    #pragma unroll
    for (int o = 32; o >= 1; o >>= 1) p += __shfl_xor(p, o, 64);
    if (lane == 0) S[i] = p;
  } else {
    int i = (b - 20000)*4 + wid;
    if (i >= N_REL) return;
    #pragma unroll
    for (int d = 0; d < 4; d++) p += QR[(size_t)i*256 + f0 + d] * a[f0+d];
    #pragma unroll
    for (int o = 32; o >= 1; o >>= 1) p += __shfl_xor(p, o, 64);
    if (lane == 0) SR[i] = p;
  }
}

// ---------------- CSR build ----------------
__device__ __forceinline__ int e_row(int e, const int* ei, const int* i2){
  return (e < E_DIR) ? ei[E_DIR + e] : i2[(e - E_DIR)*4 + 3];
}

__global__ void hist_kernel(const int* __restrict__ ei, const int* __restrict__ i2, int* __restrict__ cnt){
  int e = blockIdx.x*blockDim.x + threadIdx.x;
  if (e < E_TOT) atomicAdd(&cnt[e_row(e, ei, i2)], 1);
}

__global__ void scan40000(const int* __restrict__ cnt, int* __restrict__ off){
  __shared__ int part[1024];
  int tid = threadIdx.x;
  const int CH = 40;
  int base = tid * CH;
  int s = 0;
  for (int i = 0; i < CH; i++){ int idx = base + i; if (idx < N_ENT) s += cnt[idx]; }
  part[tid] = s;
  __syncthreads();
  for (int o = 1; o < 1024; o <<= 1){
    int v = (tid >= o) ? part[tid-o] : 0;
    __syncthreads();
    part[tid] += v;
    __syncthreads();
  }
  int run = (tid > 0) ? part[tid-1] : 0;
  for (int i = 0; i < CH; i++){
    int idx = base + i;
    if (idx < N_ENT){ off[idx] = run; run += cnt[idx]; }
  }
  if (tid == 0) off[N_ENT] = part[1023];
}

// scatter: writes consolidated per-slot indices (c, r0, r1, row)
__global__ void scatter_kernel(const int* __restrict__ ei, const int* __restrict__ et,
                               const int* __restrict__ i2, const int* __restrict__ off,
                               int* __restrict__ cur, int4* __restrict__ EIDX){
  int e = blockIdx.x*blockDim.x + threadIdx.x;
  if (e >= E_TOT) return;
  int r = e_row(e, ei, i2);
  int p = atomicAdd(&cur[r], 1);
  int d = off[r] + p;
  int4 v;
  if (e < E_DIR){ v.x = ei[e]; v.y = et[e]; v.z = -1; }
  else { int q = (e - E_DIR)*4; v.x = i2[q]; v.y = i2[q+1]; v.z = i2[q+2]; }
  v.w = r;
  EIDX[d] = v;
}

// ---------------- edge logits ----------------
__global__ void elog1(const int4* __restrict__ EIDX,
                      const float* __restrict__ s1, const float* __restrict__ s2,
                      const float* __restrict__ sR, float* __restrict__ L1){
  int t = blockIdx.x*blockDim.x + threadIdx.x;
  if (t >= E_TOT) return;
  int4 e = EIDX[t];
  #pragma unroll
  for (int h = 0; h < 4; h++){
    float v = s1[e.w*4+h] + s2[e.x*4+h] + sR[e.y*4+h];
    if (e.z >= 0) v += sR[e.z*4+h];
    v = (v >= 0.f) ? v : LRELU*v;
    L1[(size_t)h*E_TOT + t] = v;
  }
}

__global__ void elog2(const int4* __restrict__ EIDX,
                      const float* __restrict__ s1, const float* __restrict__ s2,
                      const float* __restrict__ sR, float* __restrict__ L2){
  int t = blockIdx.x*blockDim.x + threadIdx.x;
  if (t >= E_TOT) return;
  int4 e = EIDX[t];
  float v = s1[e.w] + s2[e.x] + sR[e.y];
  if (e.z >= 0) v += sR[e.z];
  v = (v >= 0.f) ? v : LRELU*v;
  L2[t] = v;
}

// ---------------- softmax in place: L -> w, plus AS self-coefficients ----------------
__global__ __launch_bounds__(256) void softmax1(const int* __restrict__ off,
                                                float* __restrict__ L1, float* __restrict__ AS1){
  int wid = threadIdx.x >> 6, lane = threadIdx.x & 63;
  int i = blockIdx.x*4 + wid;
  if (i >= N_ENT) return;
  int st = off[i], en = off[i+1];
  int hf = lane >> 4, l16 = lane & 15;
  float* Lh = L1 + (size_t)hf*E_TOT;
  float mx = -1e30f;
  for (int t = st + l16; t < en; t += 16) mx = fmaxf(mx, Lh[t]);
  #pragma unroll
  for (int o = 8; o >= 1; o >>= 1) mx = fmaxf(mx, __shfl_xor(mx, o, 64));
  float sm = 0.f;
  for (int t = st + l16; t < en; t += 16) sm += __expf(Lh[t] - mx);
  #pragma unroll
  for (int o = 8; o >= 1; o >>= 1) sm += __shfl_xor(sm, o, 64);
  float inv = 1.f/(sm + 1e-16f);
  for (int t = st + l16; t < en; t += 16) Lh[t] = __expf(Lh[t] - mx) * inv;
  if (l16 == 0) AS1[i*4 + hf] = sm * inv;
}

__global__ __launch_bounds__(256) void softmax2(const int* __restrict__ off,
                                                float* __restrict__ L2, float* __restrict__ AS2){
  int wid = threadIdx.x >> 6, lane = threadIdx.x & 63;
  int i = blockIdx.x*4 + wid;
  if (i >= N_ENT) return;
  int st = off[i], en = off[i+1];
  float mx = -1e30f;
  for (int t = st + lane; t < en; t += 64) mx = fmaxf(mx, L2[t]);
  #pragma unroll
  for (int o = 32; o >= 1; o >>= 1) mx = fmaxf(mx, __shfl_xor(mx, o, 64));
  float sm = 0.f;
  for (int t = st + lane; t < en; t += 64) sm += __expf(L2[t] - mx);
  #pragma unroll
  for (int o = 32; o >= 1; o >>= 1) sm += __shfl_xor(sm, o, 64);
  float inv = 1.f/(sm + 1e-16f);
  for (int t = st + lane; t < en; t += 64) L2[t] = __expf(L2[t] - mx) * inv;
  if (lane == 0) AS2[i] = sm * inv;
}

// ---------------- layer-1 aggregation (weights precomputed) ----------------
__global__ __launch_bounds__(256) void agg1(const int* __restrict__ off,
    const int4* __restrict__ EIDX, const float* __restrict__ W1, const float* __restrict__ AS1,
    const bf16* __restrict__ P1, const bf16* __restrict__ P2, const float* __restrict__ PRm,
    bf16* __restrict__ X1){
  int wid = threadIdx.x >> 6, lane = threadIdx.x & 63;
  int i = blockIdx.x*4 + wid;
  if (i >= N_ENT) return;
  int st = off[i], en = off[i+1];
  int hf = lane >> 4, f0 = lane*4;
  size_t ob = (size_t)i*256 + f0;
  if (st == en){
    *(uint2*)(X1 + ob) = (uint2){0u, 0u};
    return;
  }
  const float* Wh_ = W1 + (size_t)hf*E_TOT;
  float a0=0,a1=0,a2=0,a3=0;
  #pragma unroll 2
  for (int t = st; t < en; t++){
    float w = Wh_[t];
    int4 e = EIDX[t];
    uint2 u = *(const uint2*)(P2 + (size_t)e.x*256 + f0);
    float4 rv = *(const float4*)(PRm + (size_t)e.y*256 + f0);
    float e0 = bitsf(u.x << 16) + rv.x;
    float e1 = bitsf(u.x & 0xffff0000u) + rv.y;
    float e2 = bitsf(u.y << 16) + rv.z;
    float e3 = bitsf(u.y & 0xffff0000u) + rv.w;
    if (e.z >= 0){
      float4 r1v = *(const float4*)(PRm + (size_t)e.z*256 + f0);
      e0 += r1v.x; e1 += r1v.y; e2 += r1v.z; e3 += r1v.w;
    }
    a0 += w*e0; a1 += w*e1; a2 += w*e2; a3 += w*e3;
  }
  float as = AS1[i*4 + hf];
  uint2 up = *(const uint2*)(P1 + ob);
  a0 += as*bitsf(up.x << 16);
  a1 += as*bitsf(up.x & 0xffff0000u);
  a2 += as*bitsf(up.y << 16);
  a3 += as*bitsf(up.y & 0xffff0000u);
  a0 = (a0 > 0.f) ? a0 : __expf(a0)-1.f;
  a1 = (a1 > 0.f) ? a1 : __expf(a1)-1.f;
  a2 = (a2 > 0.f) ? a2 : __expf(a2)-1.f;
  a3 = (a3 > 0.f) ? a3 : __expf(a3)-1.f;
  unsigned int lo = (unsigned int)bbits(a0) | ((unsigned int)bbits(a1) << 16);
  unsigned int hi = (unsigned int)bbits(a2) | ((unsigned int)bbits(a3) << 16);
  *(uint2*)(X1 + ob) = (uint2){lo, hi};
}

// ---------------- layer-2 aggregation (+ EP epilogue) ----------------
__global__ __launch_bounds__(256) void agg2(const int* __restrict__ off,
    const int4* __restrict__ EIDX, const float* __restrict__ W2, const float* __restrict__ AS2,
    const bf16* __restrict__ Q1, const bf16* __restrict__ Q2, const float* __restrict__ QRm,
    const bf16* __restrict__ EP, float* __restrict__ X2){
  int wid = threadIdx.x >> 6, lane = threadIdx.x & 63;
  int i = blockIdx.x*4 + wid;
  if (i >= N_ENT) return;
  int st = off[i], en = off[i+1];
  int f0 = lane*4;
  size_t ob = (size_t)i*256 + f0;
  float ep0=0.f, ep1=0.f, ep2=0.f, ep3=0.f;
  if (EP){
    uint2 ue = *(const uint2*)(EP + ob);
    ep0 = bitsf(ue.x << 16); ep1 = bitsf(ue.x & 0xffff0000u);
    ep2 = bitsf(ue.y << 16); ep3 = bitsf(ue.y & 0xffff0000u);
  }
  if (st == en){
    *(float4*)(X2 + ob) = (float4){ep0, ep1, ep2, ep3};
    return;
  }
  float a0=0,a1=0,a2=0,a3=0;
  #pragma unroll 2
  for (int t = st; t < en; t++){
    float w = W2[t];
    int4 e = EIDX[t];
    uint2 u = *(const uint2*)(Q2 + (size_t)e.x*256 + f0);
    float4 rv = *(const float4*)(QRm + (size_t)e.y*256 + f0);
    float e0 = bitsf(u.x << 16) + rv.x;
    float e1 = bitsf(u.x & 0xffff0000u) + rv.y;
    float e2 = bitsf(u.y << 16) + rv.z;
    float e3 = bitsf(u.y & 0xffff0000u) + rv.w;
    if (e.z >= 0){
      float4 r1v = *(const float4*)(QRm + (size_t)e.z*256 + f0);
      e0 += r1v.x; e1 += r1v.y; e2 += r1v.z; e3 += r1v.w;
    }
    a0 += w*e0; a1 += w*e1; a2 += w*e2; a3 += w*e3;
  }
  float as = AS2[i];
  uint2 uq = *(const uint2*)(Q1 + ob);
  a0 += as*bitsf(uq.x << 16);
  a1 += as*bitsf(uq.x & 0xffff0000u);
  a2 += as*bitsf(uq.y << 16);
  a3 += as*bitsf(uq.y & 0xffff0000u);
  a0 = ((a0 > 0.f) ? a0 : __expf(a0)-1.f) + ep0;
  a1 = ((a1 > 0.f) ? a1 : __expf(a1)-1.f) + ep1;
  a2 = ((a2 > 0.f) ? a2 : __expf(a2)-1.f) + ep2;
  a3 = ((a3 > 0.f) ? a3 : __expf(a3)-1.f) + ep3;
  *(float4*)(X2 + ob) = (float4){a0, a1, a2, a3};
}

// ---------------- batch norm + r output ----------------
__global__ void bn_reduce(const float* __restrict__ X, float* __restrict__ sums, float* __restrict__ sq){
  int ch = threadIdx.x;
  float s = 0.f, q = 0.f;
  for (int r = blockIdx.x; r < N_ENT; r += gridDim.x){
    float v = X[(size_t)r*256 + ch];
    s += v; q += v*v;
  }
  atomicAdd(&sums[ch], s);
  atomicAdd(&sq[ch], q);
}

__global__ void bn_final_r(float* __restrict__ X, const float* __restrict__ sums, const float* __restrict__ sq,
                           const float* __restrict__ gamma, const float* __restrict__ beta,
                           const float* __restrict__ RF, float* __restrict__ out_r){
  int b = blockIdx.x;
  if (b < 40000){
    int idx = b*256 + threadIdx.x;
    int ch = idx & 255;
    const float invn = 1.f/(float)N_ENT;
    float mean = sums[ch] * invn;
    float var  = fmaxf(sq[ch] * invn - mean*mean, 0.f);
    X[idx] = (X[idx] - mean) * rsqrtf(var + BN_EPS) * gamma[ch] + beta[ch];
  } else {
    int idx = (b - 40000)*256 + threadIdx.x;
    out_r[idx] = RF[idx];
  }
}

// ---------------- launch ----------------
extern "C" void kernel_launch(void* const* d_in, const int* in_sizes, int n_in,
                              void* d_out, int out_size, void* d_ws, size_t ws_size,
                              hipStream_t stream){
  const int*   ei  = (const int*)d_in[0];
  const int*   et  = (const int*)d_in[1];
  const int*   i2  = (const int*)d_in[2];
  const float* emb = (const float*)d_in[3];
  const float* Wh  = (const float*)d_in[5];
  const float* ah  = (const float*)d_in[6];
  const float* gw  = (const float*)d_in[7];
  const float* ow  = (const float*)d_in[8];
  const float* oa  = (const float*)d_in[9];
  const float* we  = (const float*)d_in[10];
  const float* gma = (const float*)d_in[11];
  const float* bta = (const float*)d_in[12];
  const float* rel = (const float*)d_in[4];
  float* out = (float*)d_out;

  char* ws = (char*)d_ws;
  size_t o = 0;
  auto alloc = [&](size_t bytes)->char*{
    char* p = ws + o; o = (o + bytes + 255) & ~(size_t)255; return p;
  };
  bf16*  P1  = (bf16*)alloc(20480000);    // P1 -> Q1
  bf16*  P2  = (bf16*)alloc(20480000);    // P2 -> Q2
  float* PR  = (float*)alloc(512000);
  float* QR  = (float*)alloc(512000);
  float* RF  = (float*)alloc(512000);
  float* WC  = (float*)alloc(131072);
  bf16*  WAp = (bf16*)alloc(65536);
  bf16*  WBp = (bf16*)alloc(65536);
  bf16*  WEp = (bf16*)alloc(65536);
  bf16*  OWp0= (bf16*)alloc(131072);
  bf16*  OWp1= (bf16*)alloc(131072);
  float* S1  = (float*)alloc(640000);
  float* S2  = (float*)alloc(640000);
  float* SRm = (float*)alloc(8192);
  float* S1B = (float*)alloc(160000);
  float* S2B = (float*)alloc(160000);
  float* SRB = (float*)alloc(2048);
  int*   CNT = (int*)alloc(160000);       // CNT and CUR adjacent: one memset
  int*   CUR = (int*)alloc(160000);
  int*   OFF = (int*)alloc(160016);
  int4*  EIDX= (int4*)alloc(4000000);
  float* L1  = (float*)alloc(4000000);    // logits -> weights in place
  float* L2  = (float*)alloc(1000000);
  float* AS1 = (float*)alloc(640000);
  float* AS2 = (float*)alloc(160000);
  float* BNS = (float*)alloc(1024);       // BNS/BNQ adjacent: one memset
  float* BNQ = (float*)alloc(1024);
  size_t base_end = o;
  bool useEP = (ws_size >= base_end + 20480256 + 512);
  bf16* EP = nullptr;
  if (useEP) EP = (bf16*)alloc(20480000);
  // d_out staging: X1 bf16 [0,20.48MB), embb bf16 [20.48,30.72MB); X2 fp32 later.
  bf16* X1b  = (bf16*)out;
  bf16* embb = (bf16*)((char*)out + 20480000);
  float* X2 = out;
  (void)in_sizes; (void)n_in; (void)out_size;

  hipMemsetAsync(CNT, 0, 320000, stream);
  hipMemsetAsync(BNS, 0, 2048, stream);

  prep_weights<<<240, 256, 0, stream>>>(Wh, ow, we, WAp, WBp, WEp, OWp0, OWp1, WC);
  cvt_f2b<<<20000, 256, 0, stream>>>(emb, embb, N_ENT*D_IN);

  hist_kernel<<<(E_TOT+255)/256, 256, 0, stream>>>(ei, i2, CNT);
  scan40000<<<1, 1024, 0, stream>>>(CNT, OFF);
  scatter_kernel<<<(E_TOT+255)/256, 256, 0, stream>>>(ei, et, i2, OFF, CUR, EIDX);

  // layer-1 projections: P1, P2 (+EP) in one launch; rel pair in one launch
  gemm_mfma_multi<<<dim3(N_ENT/64, useEP ? 3 : 2), 256, 0, stream>>>(
      (const short*)embb, (const short*)WAp, (const short*)WBp, (const short*)WEp,
      P1, P2, EP, 128);
  gemm64_sel<<<dim3((N_REL+63)/64, 4, 2), 256, 0, stream>>>(rel, WC, PR, gw, RF, N_REL, 128);

  dots3<<<20125, 256, 0, stream>>>(P1, P2, PR, ah, S1, S2, SRm);
  elog1<<<(E_TOT+255)/256, 256, 0, stream>>>(EIDX, S1, S2, SRm, L1);
  softmax1<<<N_ENT/4, 256, 0, stream>>>(OFF, L1, AS1);
  agg1<<<N_ENT/4, 256, 0, stream>>>(OFF, EIDX, L1, AS1, P1, P2, PR, X1b);

  // layer-2 projections
  gemm_mfma_multi<<<dim3(N_ENT/64, 2), 256, 0, stream>>>(
      (const short*)X1b, (const short*)OWp0, (const short*)OWp1, (const short*)OWp1,
      P1, P2, P2, 256);
  gemm64_sel<<<dim3((N_REL+63)/64, 4, 1), 256, 0, stream>>>(RF, ow + 131072, QR, nullptr, nullptr, N_REL, 256);

  fdots3<<<20125, 256, 0, stream>>>(P1, P2, QR, oa, S1B, S2B, SRB);
  elog2<<<(E_TOT+255)/256, 256, 0, stream>>>(EIDX, S1B, S2B, SRB, L2);
  softmax2<<<N_ENT/4, 256, 0, stream>>>(OFF, L2, AS2);
  agg2<<<N_ENT/4, 256, 0, stream>>>(OFF, EIDX, L2, AS2, P1, P2, QR, EP, X2);

  if (!useEP)
    gemm64_acc<true><<<dim3((N_ENT+63)/64, 4), 256, 0, stream>>>(emb, we, X2, N_ENT, 128);

  bn_reduce<<<256, 256, 0, stream>>>(X2, BNS, BNQ);
  bn_final_r<<<40500, 256, 0, stream>>>(X2, BNS, BNQ, gma, bta, RF, out + (size_t)N_ENT*256);
}

// Round 8
// 653.387 us; speedup vs baseline: 1.7075x; 1.0643x over previous
//
#include <hip/hip_runtime.h>
#include <hip/hip_bf16.h>
#include <math.h>

#define N_ENT 40000
#define N_REL 500
#define E_DIR 200000
#define E_2HOP 50000
#define E_TOT 250000
#define D_IN 128
#define D_EMB 256
#define LRELU 0.2f
#define BN_EPS 1e-5f

typedef __hip_bfloat16 bf16;
typedef __attribute__((ext_vector_type(8))) short short8;
typedef __attribute__((ext_vector_type(4))) float float4v;

__device__ __forceinline__ float b2f(bf16 v){ return __bfloat162float(v); }
__device__ __forceinline__ float bitsf(unsigned int u){ return __builtin_bit_cast(float, u); }
__device__ __forceinline__ unsigned short bbits(float v){ return __builtin_bit_cast(unsigned short, __float2bfloat16(v)); }

// ---------------- fused weight prep + emb bf16 convert ----------------
// b<112: pack weights (seg0 WAp,16 | seg1 WBp,16 | seg2 WEp,16 | seg3 OWp0,32 | seg4 OWp1,32)
// b in [112,240): WC fp32 repack ; b >= 240: emb -> bf16
__global__ void prep_all(const float* __restrict__ Wh, const float* __restrict__ ow,
                         const float* __restrict__ we, const float* __restrict__ emb,
                         bf16* __restrict__ WAp, bf16* __restrict__ WBp, bf16* __restrict__ WEp,
                         bf16* __restrict__ OWp0, bf16* __restrict__ OWp1, float* __restrict__ WC,
                         bf16* __restrict__ embb){
  const int HS = 384*64;
  int b = blockIdx.x, tid = threadIdx.x;
  if (b >= 240){
    int i = (b - 240)*256 + tid;
    embb[i] = __float2bfloat16(emb[i]);
    return;
  }
  if (b < 112){
    int seg, base;
    if      (b < 16){ seg = 0; base = 0; }
    else if (b < 32){ seg = 1; base = 16; }
    else if (b < 48){ seg = 2; base = 32; }
    else if (b < 80){ seg = 3; base = 48; }
    else            { seg = 4; base = 80; }
    int idx = (b - base)*256 + tid;
    int lane = idx & 63, nt = (idx >> 6) & 15, kc = idx >> 10;
    int quad = lane >> 4, l16 = lane & 15;
    int col = nt*16 + l16;
    int kbase = kc*32 + quad*8;
    bf16* dst = (seg==0?WAp : seg==1?WBp : seg==2?WEp : seg==3?OWp0 : OWp1) + (size_t)idx*8;
    #pragma unroll
    for (int j = 0; j < 8; j++){
      int k = kbase + j;
      float v;
      if      (seg == 0) v = Wh[(col>>6)*HS + k*64 + (col&63)];
      else if (seg == 1) v = Wh[(col>>6)*HS + (k+128)*64 + (col&63)];
      else if (seg == 2) v = we[(size_t)k*256 + col];
      else if (seg == 3) v = ow[(size_t)k*256 + col];
      else               v = ow[(size_t)(k+256)*256 + col];
      dst[j] = __float2bfloat16(v);
    }
  } else {
    int idx = (b - 112)*256 + tid;
    int k = idx >> 8, col = idx & 255;
    WC[idx] = Wh[(col>>6)*HS + (k+256)*64 + (col&63)];
  }
}

// ---------------- MFMA GEMM multi + fused dot epilogue ----------------
// dmode: 0 = per-head dots (S[row*4+h]), 1 = full dot (S[row]); Sout==nullptr -> skip
__global__ __launch_bounds__(256) void gemm_mfma_multi(const short* __restrict__ A,
    const short* __restrict__ B0, const short* __restrict__ B1, const short* __restrict__ B2,
    bf16* __restrict__ C0, bf16* __restrict__ C1, bf16* __restrict__ C2, int K,
    const float* __restrict__ avec, float* __restrict__ S0, float* __restrict__ S1o,
    int dmode){
  const short* Bp = blockIdx.y==0 ? B0 : (blockIdx.y==1 ? B1 : B2);
  bf16* C = blockIdx.y==0 ? C0 : (blockIdx.y==1 ? C1 : C2);
  float* Sout = blockIdx.y==0 ? S0 : (blockIdx.y==1 ? S1o : nullptr);
  int w = threadIdx.x >> 6, lane = threadIdx.x & 63;
  int quad = lane >> 4, l16 = lane & 15;
  int rm = blockIdx.x*64 + w*16;
  int arow = rm + l16;
  float4v acc[16];
  #pragma unroll
  for (int nt = 0; nt < 16; nt++) acc[nt] = (float4v){0.f,0.f,0.f,0.f};
  int nkc = K >> 5;
  for (int kc = 0; kc < nkc; kc++){
    short8 a = *(const short8*)(A + (size_t)arow*K + kc*32 + quad*8);
    const short8* bp = (const short8*)(Bp + ((size_t)(kc*16)*64 + lane)*8);
    #pragma unroll
    for (int nt = 0; nt < 16; nt++){
      short8 b = bp[(size_t)nt*64];
      acc[nt] = __builtin_amdgcn_mfma_f32_16x16x32_bf16(a, b, acc[nt], 0, 0, 0);
    }
  }
  #pragma unroll
  for (int nt = 0; nt < 16; nt++){
    #pragma unroll
    for (int r = 0; r < 4; r++){
      int row = quad*4 + r;
      C[(size_t)(rm + row)*256 + nt*16 + l16] = __float2bfloat16(acc[nt][r]);
    }
  }
  if (Sout){
    if (dmode == 0){
      #pragma unroll
      for (int h = 0; h < 4; h++){
        float pr[4] = {0.f,0.f,0.f,0.f};
        #pragma unroll
        for (int ntl = 0; ntl < 4; ntl++){
          int nt = h*4 + ntl;
          float av = avec[nt*16 + l16];
          #pragma unroll
          for (int r = 0; r < 4; r++) pr[r] += acc[nt][r]*av;
        }
        #pragma unroll
        for (int m = 8; m >= 1; m >>= 1)
          #pragma unroll
          for (int r = 0; r < 4; r++) pr[r] += __shfl_xor(pr[r], m, 64);
        if (l16 == 0){
          #pragma unroll
          for (int r = 0; r < 4; r++) Sout[(rm + quad*4 + r)*4 + h] = pr[r];
        }
      }
    } else {
      float pr[4] = {0.f,0.f,0.f,0.f};
      #pragma unroll
      for (int nt = 0; nt < 16; nt++){
        float av = avec[nt*16 + l16];
        #pragma unroll
        for (int r = 0; r < 4; r++) pr[r] += acc[nt][r]*av;
      }
      #pragma unroll
      for (int m = 8; m >= 1; m >>= 1)
        #pragma unroll
        for (int r = 0; r < 4; r++) pr[r] += __shfl_xor(pr[r], m, 64);
      if (l16 == 0){
        #pragma unroll
        for (int r = 0; r < 4; r++) Sout[rm + quad*4 + r] = pr[r];
      }
    }
  }
}

// ---------------- fp32 tiled GEMM (pair-select by z) + fused dot epilogue ----------------
// mode: 0 = head dots (S[row*4 + bn/64]), 1 = full dot via atomicAdd(S[row]), 2 = none
__global__ void gemm64_sel(const float* __restrict__ A,
                           const float* __restrict__ B0, float* __restrict__ C0,
                           const float* __restrict__ B1, float* __restrict__ C1,
                           int M, int K,
                           const float* __restrict__ av0, float* __restrict__ S0, int mode0,
                           const float* __restrict__ av1, float* __restrict__ S1o, int mode1){
  const float* B = blockIdx.z ? B1 : B0;
  float* C = blockIdx.z ? C1 : C0;
  const float* av = blockIdx.z ? av1 : av0;
  float* So = blockIdx.z ? S1o : S0;
  int mode = blockIdx.z ? mode1 : mode0;
  const int N = 256;
  __shared__ float As[16][65];
  __shared__ float Bs[16][65];
  int bm = blockIdx.x * 64, bn = blockIdx.y * 64;
  int tid = threadIdx.x;
  int tx = tid & 15, ty = tid >> 4;
  float acc[4][4] = {};
  for (int k0 = 0; k0 < K; k0 += 16){
    #pragma unroll
    for (int j = 0; j < 4; j++){
      int idx = tid + j*256;
      int m = idx >> 4, kk = idx & 15;
      int gm = bm + m;
      float v = 0.f;
      if (gm < M) v = A[(size_t)gm*K + k0 + kk];
      As[kk][m] = v;
    }
    #pragma unroll
    for (int j = 0; j < 4; j++){
      int idx = tid + j*256;
      int kk = idx >> 6, n = idx & 63;
      Bs[kk][n] = B[(size_t)(k0+kk)*N + bn + n];
    }
    __syncthreads();
    #pragma unroll
    for (int kk = 0; kk < 16; kk++){
      float a[4], b[4];
      #pragma unroll
      for (int i = 0; i < 4; i++) a[i] = As[kk][ty*4+i];
      #pragma unroll
      for (int j = 0; j < 4; j++) b[j] = Bs[kk][tx*4+j];
      #pragma unroll
      for (int i = 0; i < 4; i++)
        #pragma unroll
        for (int j = 0; j < 4; j++) acc[i][j] += a[i]*b[j];
    }
    __syncthreads();
  }
  #pragma unroll
  for (int i = 0; i < 4; i++){
    int gm = bm + ty*4 + i;
    if (gm >= M) continue;
    #pragma unroll
    for (int j = 0; j < 4; j++)
      C[(size_t)gm*N + bn + tx*4 + j] = acc[i][j];
  }
  if (mode != 2){
    float pr[4];
    #pragma unroll
    for (int i = 0; i < 4; i++){
      float p = 0.f;
      #pragma unroll
      for (int j = 0; j < 4; j++) p += acc[i][j]*av[bn + tx*4 + j];
      pr[i] = p;
    }
    #pragma unroll
    for (int m = 8; m >= 1; m >>= 1)
      #pragma unroll
      for (int i = 0; i < 4; i++) pr[i] += __shfl_xor(pr[i], m, 64);
    if (tx == 0){
      int head = bn >> 6;
      #pragma unroll
      for (int i = 0; i < 4; i++){
        int gm = bm + ty*4 + i;
        if (gm < M){
          if (mode == 0) So[gm*4 + head] = pr[i];
          else atomicAdd(&So[gm], pr[i]);
        }
      }
    }
  }
}

// fp32 accumulate GEMM (fallback when EP doesn't fit ws)
__global__ void gemm64_acc(const float* __restrict__ A, const float* __restrict__ B,
                           float* __restrict__ C, int M, int K){
  const int N = 256;
  __shared__ float As[16][65];
  __shared__ float Bs[16][65];
  int bm = blockIdx.x * 64, bn = blockIdx.y * 64;
  int tid = threadIdx.x;
  int tx = tid & 15, ty = tid >> 4;
  float acc[4][4] = {};
  for (int k0 = 0; k0 < K; k0 += 16){
    #pragma unroll
    for (int j = 0; j < 4; j++){
      int idx = tid + j*256;
      int m = idx >> 4, kk = idx & 15;
      int gm = bm + m;
      float v = 0.f;
      if (gm < M) v = A[(size_t)gm*K + k0 + kk];
      As[kk][m] = v;
    }
    #pragma unroll
    for (int j = 0; j < 4; j++){
      int idx = tid + j*256;
      int kk = idx >> 6, n = idx & 63;
      Bs[kk][n] = B[(size_t)(k0+kk)*N + bn + n];
    }
    __syncthreads();
    #pragma unroll
    for (int kk = 0; kk < 16; kk++){
      float a[4], b[4];
      #pragma unroll
      for (int i = 0; i < 4; i++) a[i] = As[kk][ty*4+i];
      #pragma unroll
      for (int j = 0; j < 4; j++) b[j] = Bs[kk][tx*4+j];
      #pragma unroll
      for (int i = 0; i < 4; i++)
        #pragma unroll
        for (int j = 0; j < 4; j++) acc[i][j] += a[i]*b[j];
    }
    __syncthreads();
  }
  #pragma unroll
  for (int i = 0; i < 4; i++){
    int gm = bm + ty*4 + i;
    if (gm >= M) continue;
    #pragma unroll
    for (int j = 0; j < 4; j++){
      size_t o = (size_t)gm*N + bn + tx*4 + j;
      C[o] += acc[i][j];
    }
  }
}

// ---------------- CSR build ----------------
__device__ __forceinline__ int e_row(int e, const int* ei, const int* i2){
  return (e < E_DIR) ? ei[E_DIR + e] : i2[(e - E_DIR)*4 + 3];
}

__global__ void hist_kernel(const int* __restrict__ ei, const int* __restrict__ i2, int* __restrict__ cnt){
  int e = blockIdx.x*blockDim.x + threadIdx.x;
  if (e < E_TOT) atomicAdd(&cnt[e_row(e, ei, i2)], 1);
}

__global__ void scan40000(const int* __restrict__ cnt, int* __restrict__ off){
  __shared__ int part[1024];
  int tid = threadIdx.x;
  const int CH = 40;
  int base = tid * CH;
  int s = 0;
  for (int i = 0; i < CH; i++){ int idx = base + i; if (idx < N_ENT) s += cnt[idx]; }
  part[tid] = s;
  __syncthreads();
  for (int o = 1; o < 1024; o <<= 1){
    int v = (tid >= o) ? part[tid-o] : 0;
    __syncthreads();
    part[tid] += v;
    __syncthreads();
  }
  int run = (tid > 0) ? part[tid-1] : 0;
  for (int i = 0; i < CH; i++){
    int idx = base + i;
    if (idx < N_ENT){ off[idx] = run; run += cnt[idx]; }
  }
  if (tid == 0) off[N_ENT] = part[1023];
}

__global__ void scatter_kernel(const int* __restrict__ ei, const int* __restrict__ et,
                               const int* __restrict__ i2, const int* __restrict__ off,
                               int* __restrict__ cur, int4* __restrict__ EIDX){
  int e = blockIdx.x*blockDim.x + threadIdx.x;
  if (e >= E_TOT) return;
  int r = e_row(e, ei, i2);
  int p = atomicAdd(&cur[r], 1);
  int d = off[r] + p;
  int4 v;
  if (e < E_DIR){ v.x = ei[e]; v.y = et[e]; v.z = -1; }
  else { int q = (e - E_DIR)*4; v.x = i2[q]; v.y = i2[q+1]; v.z = i2[q+2]; }
  v.w = r;
  EIDX[d] = v;
}

// ---------------- edge logits ----------------
__global__ void elog1(const int4* __restrict__ EIDX,
                      const float* __restrict__ s1, const float* __restrict__ s2,
                      const float* __restrict__ sR, float* __restrict__ L1){
  int t = blockIdx.x*blockDim.x + threadIdx.x;
  if (t >= E_TOT) return;
  int4 e = EIDX[t];
  #pragma unroll
  for (int h = 0; h < 4; h++){
    float v = s1[e.w*4+h] + s2[e.x*4+h] + sR[e.y*4+h];
    if (e.z >= 0) v += sR[e.z*4+h];
    v = (v >= 0.f) ? v : LRELU*v;
    L1[(size_t)h*E_TOT + t] = v;
  }
}

__global__ void elog2(const int4* __restrict__ EIDX,
                      const float* __restrict__ s1, const float* __restrict__ s2,
                      const float* __restrict__ sR, float* __restrict__ L2){
  int t = blockIdx.x*blockDim.x + threadIdx.x;
  if (t >= E_TOT) return;
  int4 e = EIDX[t];
  float v = s1[e.w] + s2[e.x] + sR[e.y];
  if (e.z >= 0) v += sR[e.z];
  v = (v >= 0.f) ? v : LRELU*v;
  L2[t] = v;
}

// ---------------- softmax in place ----------------
__global__ __launch_bounds__(256) void softmax1(const int* __restrict__ off,
                                                float* __restrict__ L1, float* __restrict__ AS1){
  int wid = threadIdx.x >> 6, lane = threadIdx.x & 63;
  int i = blockIdx.x*4 + wid;
  if (i >= N_ENT) return;
  int st = off[i], en = off[i+1];
  int hf = lane >> 4, l16 = lane & 15;
  float* Lh = L1 + (size_t)hf*E_TOT;
  float mx = -1e30f;
  for (int t = st + l16; t < en; t += 16) mx = fmaxf(mx, Lh[t]);
  #pragma unroll
  for (int o = 8; o >= 1; o >>= 1) mx = fmaxf(mx, __shfl_xor(mx, o, 64));
  float sm = 0.f;
  for (int t = st + l16; t < en; t += 16) sm += __expf(Lh[t] - mx);
  #pragma unroll
  for (int o = 8; o >= 1; o >>= 1) sm += __shfl_xor(sm, o, 64);
  float inv = 1.f/(sm + 1e-16f);
  for (int t = st + l16; t < en; t += 16) Lh[t] = __expf(Lh[t] - mx) * inv;
  if (l16 == 0) AS1[i*4 + hf] = sm * inv;
}

__global__ __launch_bounds__(256) void softmax2(const int* __restrict__ off,
                                                float* __restrict__ L2, float* __restrict__ AS2){
  int wid = threadIdx.x >> 6, lane = threadIdx.x & 63;
  int i = blockIdx.x*4 + wid;
  if (i >= N_ENT) return;
  int st = off[i], en = off[i+1];
  float mx = -1e30f;
  for (int t = st + lane; t < en; t += 64) mx = fmaxf(mx, L2[t]);
  #pragma unroll
  for (int o = 32; o >= 1; o >>= 1) mx = fmaxf(mx, __shfl_xor(mx, o, 64));
  float sm = 0.f;
  for (int t = st + lane; t < en; t += 64) sm += __expf(L2[t] - mx);
  #pragma unroll
  for (int o = 32; o >= 1; o >>= 1) sm += __shfl_xor(sm, o, 64);
  float inv = 1.f/(sm + 1e-16f);
  for (int t = st + lane; t < en; t += 64) L2[t] = __expf(L2[t] - mx) * inv;
  if (lane == 0) AS2[i] = sm * inv;
}

// ---------------- layer-1 aggregation (4-wide pipelined) ----------------
__global__ __launch_bounds__(256) void agg1(const int* __restrict__ off,
    const int4* __restrict__ EIDX, const float* __restrict__ W1, const float* __restrict__ AS1,
    const bf16* __restrict__ P1, const bf16* __restrict__ P2, const float* __restrict__ PRm,
    bf16* __restrict__ X1){
  int wid = threadIdx.x >> 6, lane = threadIdx.x & 63;
  int i = blockIdx.x*4 + wid;
  if (i >= N_ENT) return;
  int st = off[i], en = off[i+1];
  int hf = lane >> 4, f0 = lane*4;
  size_t ob = (size_t)i*256 + f0;
  if (st == en){
    *(uint2*)(X1 + ob) = (uint2){0u, 0u};
    return;
  }
  const float* Wp = W1 + (size_t)hf*E_TOT;
  float a0=0,a1=0,a2=0,a3=0;
  int t = st;
  int n4 = st + ((en - st) & ~3);
  for (; t < n4; t += 4){
    int4 e[4]; float wv[4]; uint2 u[4]; float4 rv[4];
    #pragma unroll
    for (int k = 0; k < 4; k++){ e[k] = EIDX[t+k]; wv[k] = Wp[t+k]; }
    #pragma unroll
    for (int k = 0; k < 4; k++){
      u[k] = *(const uint2*)(P2 + (size_t)e[k].x*256 + f0);
      rv[k] = *(const float4*)(PRm + (size_t)e[k].y*256 + f0);
    }
    #pragma unroll
    for (int k = 0; k < 4; k++){
      if (e[k].z >= 0){
        float4 s = *(const float4*)(PRm + (size_t)e[k].z*256 + f0);
        rv[k].x += s.x; rv[k].y += s.y; rv[k].z += s.z; rv[k].w += s.w;
      }
    }
    #pragma unroll
    for (int k = 0; k < 4; k++){
      a0 += wv[k]*(bitsf(u[k].x << 16) + rv[k].x);
      a1 += wv[k]*(bitsf(u[k].x & 0xffff0000u) + rv[k].y);
      a2 += wv[k]*(bitsf(u[k].y << 16) + rv[k].z);
      a3 += wv[k]*(bitsf(u[k].y & 0xffff0000u) + rv[k].w);
    }
  }
  for (; t < en; t++){
    float w = Wp[t];
    int4 e = EIDX[t];
    uint2 u = *(const uint2*)(P2 + (size_t)e.x*256 + f0);
    float4 rv = *(const float4*)(PRm + (size_t)e.y*256 + f0);
    if (e.z >= 0){
      float4 s = *(const float4*)(PRm + (size_t)e.z*256 + f0);
      rv.x += s.x; rv.y += s.y; rv.z += s.z; rv.w += s.w;
    }
    a0 += w*(bitsf(u.x << 16) + rv.x);
    a1 += w*(bitsf(u.x & 0xffff0000u) + rv.y);
    a2 += w*(bitsf(u.y << 16) + rv.z);
    a3 += w*(bitsf(u.y & 0xffff0000u) + rv.w);
  }
  float as = AS1[i*4 + hf];
  uint2 up = *(const uint2*)(P1 + ob);
  a0 += as*bitsf(up.x << 16);
  a1 += as*bitsf(up.x & 0xffff0000u);
  a2 += as*bitsf(up.y << 16);
  a3 += as*bitsf(up.y & 0xffff0000u);
  a0 = (a0 > 0.f) ? a0 : __expf(a0)-1.f;
  a1 = (a1 > 0.f) ? a1 : __expf(a1)-1.f;
  a2 = (a2 > 0.f) ? a2 : __expf(a2)-1.f;
  a3 = (a3 > 0.f) ? a3 : __expf(a3)-1.f;
  unsigned int lo = (unsigned int)bbits(a0) | ((unsigned int)bbits(a1) << 16);
  unsigned int hi = (unsigned int)bbits(a2) | ((unsigned int)bbits(a3) << 16);
  *(uint2*)(X1 + ob) = (uint2){lo, hi};
}

// ---------------- layer-2 aggregation (4-wide pipelined, + EP epilogue) ----------------
__global__ __launch_bounds__(256) void agg2(const int* __restrict__ off,
    const int4* __restrict__ EIDX, const float* __restrict__ W2, const float* __restrict__ AS2,
    const bf16* __restrict__ Q1, const bf16* __restrict__ Q2, const float* __restrict__ QRm,
    const bf16* __restrict__ EP, float* __restrict__ X2){
  int wid = threadIdx.x >> 6, lane = threadIdx.x & 63;
  int i = blockIdx.x*4 + wid;
  if (i >= N_ENT) return;
  int st = off[i], en = off[i+1];
  int f0 = lane*4;
  size_t ob = (size_t)i*256 + f0;
  float ep0=0.f, ep1=0.f, ep2=0.f, ep3=0.f;
  if (EP){
    uint2 ue = *(const uint2*)(EP + ob);
    ep0 = bitsf(ue.x << 16); ep1 = bitsf(ue.x & 0xffff0000u);
    ep2 = bitsf(ue.y << 16); ep3 = bitsf(ue.y & 0xffff0000u);
  }
  if (st == en){
    *(float4*)(X2 + ob) = (float4){ep0, ep1, ep2, ep3};
    return;
  }
  float a0=0,a1=0,a2=0,a3=0;
  int t = st;
  int n4 = st + ((en - st) & ~3);
  for (; t < n4; t += 4){
    int4 e[4]; float wv[4]; uint2 u[4]; float4 rv[4];
    #pragma unroll
    for (int k = 0; k < 4; k++){ e[k] = EIDX[t+k]; wv[k] = W2[t+k]; }
    #pragma unroll
    for (int k = 0; k < 4; k++){
      u[k] = *(const uint2*)(Q2 + (size_t)e[k].x*256 + f0);
      rv[k] = *(const float4*)(QRm + (size_t)e[k].y*256 + f0);
    }
    #pragma unroll
    for (int k = 0; k < 4; k++){
      if (e[k].z >= 0){
        float4 s = *(const float4*)(QRm + (size_t)e[k].z*256 + f0);
        rv[k].x += s.x; rv[k].y += s.y; rv[k].z += s.z; rv[k].w += s.w;
      }
    }
    #pragma unroll
    for (int k = 0; k < 4; k++){
      a0 += wv[k]*(bitsf(u[k].x << 16) + rv[k].x);
      a1 += wv[k]*(bitsf(u[k].x & 0xffff0000u) + rv[k].y);
      a2 += wv[k]*(bitsf(u[k].y << 16) + rv[k].z);
      a3 += wv[k]*(bitsf(u[k].y & 0xffff0000u) + rv[k].w);
    }
  }
  for (; t < en; t++){
    float w = W2[t];
    int4 e = EIDX[t];
    uint2 u = *(const uint2*)(Q2 + (size_t)e.x*256 + f0);
    float4 rv = *(const float4*)(QRm + (size_t)e.y*256 + f0);
    if (e.z >= 0){
      float4 s = *(const float4*)(QRm + (size_t)e.z*256 + f0);
      rv.x += s.x; rv.y += s.y; rv.z += s.z; rv.w += s.w;
    }
    a0 += w*(bitsf(u.x << 16) + rv.x);
    a1 += w*(bitsf(u.x & 0xffff0000u) + rv.y);
    a2 += w*(bitsf(u.y << 16) + rv.z);
    a3 += w*(bitsf(u.y & 0xffff0000u) + rv.w);
  }
  float as = AS2[i];
  uint2 uq = *(const uint2*)(Q1 + ob);
  a0 += as*bitsf(uq.x << 16);
  a1 += as*bitsf(uq.x & 0xffff0000u);
  a2 += as*bitsf(uq.y << 16);
  a3 += as*bitsf(uq.y & 0xffff0000u);
  a0 = ((a0 > 0.f) ? a0 : __expf(a0)-1.f) + ep0;
  a1 = ((a1 > 0.f) ? a1 : __expf(a1)-1.f) + ep1;
  a2 = ((a2 > 0.f) ? a2 : __expf(a2)-1.f) + ep2;
  a3 = ((a3 > 0.f) ? a3 : __expf(a3)-1.f) + ep3;
  *(float4*)(X2 + ob) = (float4){a0, a1, a2, a3};
}

// ---------------- batch norm + r output ----------------
__global__ void bn_reduce(const float* __restrict__ X, float* __restrict__ sums, float* __restrict__ sq){
  int ch = threadIdx.x;
  float s = 0.f, q = 0.f;
  for (int r = blockIdx.x; r < N_ENT; r += gridDim.x){
    float v = X[(size_t)r*256 + ch];
    s += v; q += v*v;
  }
  atomicAdd(&sums[ch], s);
  atomicAdd(&sq[ch], q);
}

__global__ void bn_final_r(float* __restrict__ X, const float* __restrict__ sums, const float* __restrict__ sq,
                           const float* __restrict__ gamma, const float* __restrict__ beta,
                           const float* __restrict__ RF, float* __restrict__ out_r){
  int b = blockIdx.x;
  if (b < 40000){
    int idx = b*256 + threadIdx.x;
    int ch = idx & 255;
    const float invn = 1.f/(float)N_ENT;
    float mean = sums[ch] * invn;
    float var  = fmaxf(sq[ch] * invn - mean*mean, 0.f);
    X[idx] = (X[idx] - mean) * rsqrtf(var + BN_EPS) * gamma[ch] + beta[ch];
  } else {
    int idx = (b - 40000)*256 + threadIdx.x;
    out_r[idx] = RF[idx];
  }
}

// ---------------- launch ----------------
extern "C" void kernel_launch(void* const* d_in, const int* in_sizes, int n_in,
                              void* d_out, int out_size, void* d_ws, size_t ws_size,
                              hipStream_t stream){
  const int*   ei  = (const int*)d_in[0];
  const int*   et  = (const int*)d_in[1];
  const int*   i2  = (const int*)d_in[2];
  const float* emb = (const float*)d_in[3];
  const float* rel = (const float*)d_in[4];
  const float* Wh  = (const float*)d_in[5];
  const float* ah  = (const float*)d_in[6];
  const float* gw  = (const float*)d_in[7];
  const float* ow  = (const float*)d_in[8];
  const float* oa  = (const float*)d_in[9];
  const float* we  = (const float*)d_in[10];
  const float* gma = (const float*)d_in[11];
  const float* bta = (const float*)d_in[12];
  float* out = (float*)d_out;

  char* ws = (char*)d_ws;
  size_t o = 0;
  auto alloc = [&](size_t bytes)->char*{
    char* p = ws + o; o = (o + bytes + 255) & ~(size_t)255; return p;
  };
  bf16*  P1  = (bf16*)alloc(20480000);    // P1 -> Q1
  bf16*  P2  = (bf16*)alloc(20480000);    // P2 -> Q2
  float* PR  = (float*)alloc(512000);
  float* QR  = (float*)alloc(512000);
  float* RF  = (float*)alloc(512000);
  float* WC  = (float*)alloc(131072);
  bf16*  WAp = (bf16*)alloc(65536);
  bf16*  WBp = (bf16*)alloc(65536);
  bf16*  WEp = (bf16*)alloc(65536);
  bf16*  OWp0= (bf16*)alloc(131072);
  bf16*  OWp1= (bf16*)alloc(131072);
  float* S1  = (float*)alloc(640000);
  float* S2  = (float*)alloc(640000);
  float* SRm = (float*)alloc(8192);
  float* S1B = (float*)alloc(160000);
  float* S2B = (float*)alloc(160000);
  int*   CNT = (int*)alloc(160000);       // CNT+CUR adjacent: one memset
  int*   CUR = (int*)alloc(160000);
  int*   OFF = (int*)alloc(160016);
  int4*  EIDX= (int4*)alloc(4000000);
  float* L1  = (float*)alloc(4000000);
  float* L2  = (float*)alloc(1000000);
  float* AS1 = (float*)alloc(640000);
  float* AS2 = (float*)alloc(160000);
  float* SRB = (float*)alloc(2048);       // SRB+BNS+BNQ adjacent: one memset
  float* BNS = (float*)alloc(1024);
  float* BNQ = (float*)alloc(1024);
  size_t base_end = o;
  bool useEP = (ws_size >= base_end + 20480256 + 512);
  bf16* EP = nullptr;
  if (useEP) EP = (bf16*)alloc(20480000);
  bf16* X1b  = (bf16*)out;
  bf16* embb = (bf16*)((char*)out + 20480000);
  float* X2 = out;
  (void)in_sizes; (void)n_in; (void)out_size;

  hipMemsetAsync(CNT, 0, 320000, stream);
  hipMemsetAsync(SRB, 0, 4096, stream);

  prep_all<<<20240, 256, 0, stream>>>(Wh, ow, we, emb, WAp, WBp, WEp, OWp0, OWp1, WC, embb);

  hist_kernel<<<(E_TOT+255)/256, 256, 0, stream>>>(ei, i2, CNT);
  scan40000<<<1, 1024, 0, stream>>>(CNT, OFF);
  scatter_kernel<<<(E_TOT+255)/256, 256, 0, stream>>>(ei, et, i2, OFF, CUR, EIDX);

  // layer-1: entity projections (+EP) with fused per-head dots; rel pair with fused dots
  gemm_mfma_multi<<<dim3(N_ENT/64, useEP ? 3 : 2), 256, 0, stream>>>(
      (const short*)embb, (const short*)WAp, (const short*)WBp, (const short*)WEp,
      P1, P2, EP, 128, ah, S1, S2, 0);
  gemm64_sel<<<dim3((N_REL+63)/64, 4, 2), 256, 0, stream>>>(rel, WC, PR, gw, RF, N_REL, 128,
      ah, SRm, 0, nullptr, nullptr, 2);

  elog1<<<(E_TOT+255)/256, 256, 0, stream>>>(EIDX, S1, S2, SRm, L1);
  softmax1<<<N_ENT/4, 256, 0, stream>>>(OFF, L1, AS1);
  agg1<<<N_ENT/4, 256, 0, stream>>>(OFF, EIDX, L1, AS1, P1, P2, PR, X1b);

  // layer-2: entity projections with fused full dots; rel gemm with atomic full dot
  gemm_mfma_multi<<<dim3(N_ENT/64, 2), 256, 0, stream>>>(
      (const short*)X1b, (const short*)OWp0, (const short*)OWp1, (const short*)OWp1,
      P1, P2, P2, 256, oa, S1B, S2B, 1);
  gemm64_sel<<<dim3((N_REL+63)/64, 4, 1), 256, 0, stream>>>(RF, ow + 131072, QR, nullptr, nullptr,
      N_REL, 256, oa, SRB, 1, nullptr, nullptr, 2);

  elog2<<<(E_TOT+255)/256, 256, 0, stream>>>(EIDX, S1B, S2B, SRB, L2);
  softmax2<<<N_ENT/4, 256, 0, stream>>>(OFF, L2, AS2);
  agg2<<<N_ENT/4, 256, 0, stream>>>(OFF, EIDX, L2, AS2, P1, P2, QR, EP, X2);

  if (!useEP)
    gemm64_acc<<<dim3((N_ENT+63)/64, 4), 256, 0, stream>>>(emb, we, X2, N_ENT, 128);

  bn_reduce<<<256, 256, 0, stream>>>(X2, BNS, BNQ);
  bn_final_r<<<40500, 256, 0, stream>>>(X2, BNS, BNQ, gma, bta, RF, out + (size_t)N_ENT*256);
}

// Round 9
// 548.373 us; speedup vs baseline: 2.0344x; 1.1915x over previous
//
#include <hip/hip_runtime.h>
#include <hip/hip_bf16.h>
#include <math.h>

#define N_ENT 40000
#define N_REL 500
#define E_DIR 200000
#define E_2HOP 50000
#define E_TOT 250000
#define D_IN 128
#define D_EMB 256
#define LRELU 0.2f
#define BN_EPS 1e-5f

typedef __hip_bfloat16 bf16;
typedef __attribute__((ext_vector_type(8))) short short8;
typedef __attribute__((ext_vector_type(4))) float float4v;

__device__ __forceinline__ float b2f(bf16 v){ return __bfloat162float(v); }
__device__ __forceinline__ float bitsf(unsigned int u){ return __builtin_bit_cast(float, u); }
__device__ __forceinline__ unsigned short bbits(float v){ return __builtin_bit_cast(unsigned short, __float2bfloat16(v)); }

// ---------------- fused weight prep + emb bf16 convert ----------------
__global__ void prep_all(const float* __restrict__ Wh, const float* __restrict__ ow,
                         const float* __restrict__ we, const float* __restrict__ emb,
                         bf16* __restrict__ WAp, bf16* __restrict__ WBp, bf16* __restrict__ WEp,
                         bf16* __restrict__ OWp0, bf16* __restrict__ OWp1, float* __restrict__ WC,
                         bf16* __restrict__ embb){
  const int HS = 384*64;
  int b = blockIdx.x, tid = threadIdx.x;
  if (b >= 240){
    int i = (b - 240)*256 + tid;
    embb[i] = __float2bfloat16(emb[i]);
    return;
  }
  if (b < 112){
    int seg, base;
    if      (b < 16){ seg = 0; base = 0; }
    else if (b < 32){ seg = 1; base = 16; }
    else if (b < 48){ seg = 2; base = 32; }
    else if (b < 80){ seg = 3; base = 48; }
    else            { seg = 4; base = 80; }
    int idx = (b - base)*256 + tid;
    int lane = idx & 63, nt = (idx >> 6) & 15, kc = idx >> 10;
    int quad = lane >> 4, l16 = lane & 15;
    int col = nt*16 + l16;
    int kbase = kc*32 + quad*8;
    bf16* dst = (seg==0?WAp : seg==1?WBp : seg==2?WEp : seg==3?OWp0 : OWp1) + (size_t)idx*8;
    #pragma unroll
    for (int j = 0; j < 8; j++){
      int k = kbase + j;
      float v;
      if      (seg == 0) v = Wh[(col>>6)*HS + k*64 + (col&63)];
      else if (seg == 1) v = Wh[(col>>6)*HS + (k+128)*64 + (col&63)];
      else if (seg == 2) v = we[(size_t)k*256 + col];
      else if (seg == 3) v = ow[(size_t)k*256 + col];
      else               v = ow[(size_t)(k+256)*256 + col];
      dst[j] = __float2bfloat16(v);
    }
  } else {
    int idx = (b - 112)*256 + tid;
    int k = idx >> 8, col = idx & 255;
    WC[idx] = Wh[(col>>6)*HS + (k+256)*64 + (col&63)];
  }
}

// ---------------- MFMA GEMM multi: register-pipelined B, prefetched A ----------------
// dmode: 0 = per-head dots (S[row*4+h]), 1 = full dot (S[row]); Sout==nullptr -> skip
__global__ __launch_bounds__(256) void gemm_mfma_multi(const short* __restrict__ A,
    const short* __restrict__ B0, const short* __restrict__ B1, const short* __restrict__ B2,
    bf16* __restrict__ C0, bf16* __restrict__ C1, bf16* __restrict__ C2, int K,
    const float* __restrict__ avec, float* __restrict__ S0, float* __restrict__ S1o,
    int dmode){
  const short* Bp = blockIdx.y==0 ? B0 : (blockIdx.y==1 ? B1 : B2);
  bf16* C = blockIdx.y==0 ? C0 : (blockIdx.y==1 ? C1 : C2);
  float* Sout = blockIdx.y==0 ? S0 : (blockIdx.y==1 ? S1o : nullptr);
  int w = threadIdx.x >> 6, lane = threadIdx.x & 63;
  int quad = lane >> 4, l16 = lane & 15;
  int rm = blockIdx.x*64 + w*16;
  int arow = rm + l16;
  float4v acc[16];
  #pragma unroll
  for (int nt = 0; nt < 16; nt++) acc[nt] = (float4v){0.f,0.f,0.f,0.f};
  int nkc = K >> 5;
  const short8* Ap = (const short8*)(A + (size_t)arow*K);
  const short8* Bv = (const short8*)Bp;
  short8 a_cur = Ap[quad];
  for (int kc = 0; kc < nkc; kc++){
    int kn = (kc + 1 < nkc) ? kc + 1 : kc;
    short8 a_nxt = Ap[kn*4 + quad];          // deep prefetch (HBM)
    const short8* bp = Bv + (size_t)kc*16*64 + lane;
    short8 b[8];
    #pragma unroll
    for (int nt = 0; nt < 8; nt++) b[nt] = bp[(size_t)nt*64];       // 8 loads in flight
    #pragma unroll
    for (int nt = 0; nt < 8; nt++)
      acc[nt] = __builtin_amdgcn_mfma_f32_16x16x32_bf16(a_cur, b[nt], acc[nt], 0, 0, 0);
    #pragma unroll
    for (int nt = 0; nt < 8; nt++) b[nt] = bp[(size_t)(nt+8)*64];   // next 8 in flight
    #pragma unroll
    for (int nt = 0; nt < 8; nt++)
      acc[nt+8] = __builtin_amdgcn_mfma_f32_16x16x32_bf16(a_cur, b[nt], acc[nt+8], 0, 0, 0);
    a_cur = a_nxt;
  }
  #pragma unroll
  for (int nt = 0; nt < 16; nt++){
    #pragma unroll
    for (int r = 0; r < 4; r++){
      int row = quad*4 + r;
      C[(size_t)(rm + row)*256 + nt*16 + l16] = __float2bfloat16(acc[nt][r]);
    }
  }
  if (Sout){
    if (dmode == 0){
      #pragma unroll
      for (int h = 0; h < 4; h++){
        float pr[4] = {0.f,0.f,0.f,0.f};
        #pragma unroll
        for (int ntl = 0; ntl < 4; ntl++){
          int nt = h*4 + ntl;
          float av = avec[nt*16 + l16];
          #pragma unroll
          for (int r = 0; r < 4; r++) pr[r] += acc[nt][r]*av;
        }
        #pragma unroll
        for (int m = 8; m >= 1; m >>= 1)
          #pragma unroll
          for (int r = 0; r < 4; r++) pr[r] += __shfl_xor(pr[r], m, 64);
        if (l16 == 0){
          #pragma unroll
          for (int r = 0; r < 4; r++) Sout[(rm + quad*4 + r)*4 + h] = pr[r];
        }
      }
    } else {
      float pr[4] = {0.f,0.f,0.f,0.f};
      #pragma unroll
      for (int nt = 0; nt < 16; nt++){
        float av = avec[nt*16 + l16];
        #pragma unroll
        for (int r = 0; r < 4; r++) pr[r] += acc[nt][r]*av;
      }
      #pragma unroll
      for (int m = 8; m >= 1; m >>= 1)
        #pragma unroll
        for (int r = 0; r < 4; r++) pr[r] += __shfl_xor(pr[r], m, 64);
      if (l16 == 0){
        #pragma unroll
        for (int r = 0; r < 4; r++) Sout[rm + quad*4 + r] = pr[r];
      }
    }
  }
}

// ---------------- fp32 tiled GEMM (pair-select by z) + fused dot epilogue ----------------
__global__ void gemm64_sel(const float* __restrict__ A,
                           const float* __restrict__ B0, float* __restrict__ C0,
                           const float* __restrict__ B1, float* __restrict__ C1,
                           int M, int K,
                           const float* __restrict__ av0, float* __restrict__ S0, int mode0,
                           const float* __restrict__ av1, float* __restrict__ S1o, int mode1){
  const float* B = blockIdx.z ? B1 : B0;
  float* C = blockIdx.z ? C1 : C0;
  const float* av = blockIdx.z ? av1 : av0;
  float* So = blockIdx.z ? S1o : S0;
  int mode = blockIdx.z ? mode1 : mode0;
  const int N = 256;
  __shared__ float As[16][65];
  __shared__ float Bs[16][65];
  int bm = blockIdx.x * 64, bn = blockIdx.y * 64;
  int tid = threadIdx.x;
  int tx = tid & 15, ty = tid >> 4;
  float acc[4][4] = {};
  for (int k0 = 0; k0 < K; k0 += 16){
    #pragma unroll
    for (int j = 0; j < 4; j++){
      int idx = tid + j*256;
      int m = idx >> 4, kk = idx & 15;
      int gm = bm + m;
      float v = 0.f;
      if (gm < M) v = A[(size_t)gm*K + k0 + kk];
      As[kk][m] = v;
    }
    #pragma unroll
    for (int j = 0; j < 4; j++){
      int idx = tid + j*256;
      int kk = idx >> 6, n = idx & 63;
      Bs[kk][n] = B[(size_t)(k0+kk)*N + bn + n];
    }
    __syncthreads();
    #pragma unroll
    for (int kk = 0; kk < 16; kk++){
      float a[4], b[4];
      #pragma unroll
      for (int i = 0; i < 4; i++) a[i] = As[kk][ty*4+i];
      #pragma unroll
      for (int j = 0; j < 4; j++) b[j] = Bs[kk][tx*4+j];
      #pragma unroll
      for (int i = 0; i < 4; i++)
        #pragma unroll
        for (int j = 0; j < 4; j++) acc[i][j] += a[i]*b[j];
    }
    __syncthreads();
  }
  #pragma unroll
  for (int i = 0; i < 4; i++){
    int gm = bm + ty*4 + i;
    if (gm >= M) continue;
    #pragma unroll
    for (int j = 0; j < 4; j++)
      C[(size_t)gm*N + bn + tx*4 + j] = acc[i][j];
  }
  if (mode != 2){
    float pr[4];
    #pragma unroll
    for (int i = 0; i < 4; i++){
      float p = 0.f;
      #pragma unroll
      for (int j = 0; j < 4; j++) p += acc[i][j]*av[bn + tx*4 + j];
      pr[i] = p;
    }
    #pragma unroll
    for (int m = 8; m >= 1; m >>= 1)
      #pragma unroll
      for (int i = 0; i < 4; i++) pr[i] += __shfl_xor(pr[i], m, 64);
    if (tx == 0){
      int head = bn >> 6;
      #pragma unroll
      for (int i = 0; i < 4; i++){
        int gm = bm + ty*4 + i;
        if (gm < M){
          if (mode == 0) So[gm*4 + head] = pr[i];
          else atomicAdd(&So[gm], pr[i]);
        }
      }
    }
  }
}

// fp32 accumulate GEMM (fallback when EP doesn't fit ws)
__global__ void gemm64_acc(const float* __restrict__ A, const float* __restrict__ B,
                           float* __restrict__ C, int M, int K){
  const int N = 256;
  __shared__ float As[16][65];
  __shared__ float Bs[16][65];
  int bm = blockIdx.x * 64, bn = blockIdx.y * 64;
  int tid = threadIdx.x;
  int tx = tid & 15, ty = tid >> 4;
  float acc[4][4] = {};
  for (int k0 = 0; k0 < K; k0 += 16){
    #pragma unroll
    for (int j = 0; j < 4; j++){
      int idx = tid + j*256;
      int m = idx >> 4, kk = idx & 15;
      int gm = bm + m;
      float v = 0.f;
      if (gm < M) v = A[(size_t)gm*K + k0 + kk];
      As[kk][m] = v;
    }
    #pragma unroll
    for (int j = 0; j < 4; j++){
      int idx = tid + j*256;
      int kk = idx >> 6, n = idx & 63;
      Bs[kk][n] = B[(size_t)(k0+kk)*N + bn + n];
    }
    __syncthreads();
    #pragma unroll
    for (int kk = 0; kk < 16; kk++){
      float a[4], b[4];
      #pragma unroll
      for (int i = 0; i < 4; i++) a[i] = As[kk][ty*4+i];
      #pragma unroll
      for (int j = 0; j < 4; j++) b[j] = Bs[kk][tx*4+j];
      #pragma unroll
      for (int i = 0; i < 4; i++)
        #pragma unroll
        for (int j = 0; j < 4; j++) acc[i][j] += a[i]*b[j];
    }
    __syncthreads();
  }
  #pragma unroll
  for (int i = 0; i < 4; i++){
    int gm = bm + ty*4 + i;
    if (gm >= M) continue;
    #pragma unroll
    for (int j = 0; j < 4; j++){
      size_t o = (size_t)gm*N + bn + tx*4 + j;
      C[o] += acc[i][j];
    }
  }
}

// ---------------- CSR build ----------------
__device__ __forceinline__ int e_row(int e, const int* ei, const int* i2){
  return (e < E_DIR) ? ei[E_DIR + e] : i2[(e - E_DIR)*4 + 3];
}

__global__ void hist_kernel(const int* __restrict__ ei, const int* __restrict__ i2, int* __restrict__ cnt){
  int e = blockIdx.x*blockDim.x + threadIdx.x;
  if (e < E_TOT) atomicAdd(&cnt[e_row(e, ei, i2)], 1);
}

__global__ void scan40000(const int* __restrict__ cnt, int* __restrict__ off){
  __shared__ int part[1024];
  int tid = threadIdx.x;
  const int CH = 40;
  int base = tid * CH;
  int s = 0;
  for (int i = 0; i < CH; i++){ int idx = base + i; if (idx < N_ENT) s += cnt[idx]; }
  part[tid] = s;
  __syncthreads();
  for (int o = 1; o < 1024; o <<= 1){
    int v = (tid >= o) ? part[tid-o] : 0;
    __syncthreads();
    part[tid] += v;
    __syncthreads();
  }
  int run = (tid > 0) ? part[tid-1] : 0;
  for (int i = 0; i < CH; i++){
    int idx = base + i;
    if (idx < N_ENT){ off[idx] = run; run += cnt[idx]; }
  }
  if (tid == 0) off[N_ENT] = part[1023];
}

__global__ void scatter_kernel(const int* __restrict__ ei, const int* __restrict__ et,
                               const int* __restrict__ i2, const int* __restrict__ off,
                               int* __restrict__ cur, int4* __restrict__ EIDX){
  int e = blockIdx.x*blockDim.x + threadIdx.x;
  if (e >= E_TOT) return;
  int r = e_row(e, ei, i2);
  int p = atomicAdd(&cur[r], 1);
  int d = off[r] + p;
  int4 v;
  if (e < E_DIR){ v.x = ei[e]; v.y = et[e]; v.z = -1; }
  else { int q = (e - E_DIR)*4; v.x = i2[q]; v.y = i2[q+1]; v.z = i2[q+2]; }
  v.w = r;
  EIDX[d] = v;
}

// ---------------- edge logits ----------------
__global__ void elog1(const int4* __restrict__ EIDX,
                      const float* __restrict__ s1, const float* __restrict__ s2,
                      const float* __restrict__ sR, float* __restrict__ L1){
  int t = blockIdx.x*blockDim.x + threadIdx.x;
  if (t >= E_TOT) return;
  int4 e = EIDX[t];
  #pragma unroll
  for (int h = 0; h < 4; h++){
    float v = s1[e.w*4+h] + s2[e.x*4+h] + sR[e.y*4+h];
    if (e.z >= 0) v += sR[e.z*4+h];
    v = (v >= 0.f) ? v : LRELU*v;
    L1[(size_t)h*E_TOT + t] = v;
  }
}

__global__ void elog2(const int4* __restrict__ EIDX,
                      const float* __restrict__ s1, const float* __restrict__ s2,
                      const float* __restrict__ sR, float* __restrict__ L2){
  int t = blockIdx.x*blockDim.x + threadIdx.x;
  if (t >= E_TOT) return;
  int4 e = EIDX[t];
  float v = s1[e.w] + s2[e.x] + sR[e.y];
  if (e.z >= 0) v += sR[e.z];
  v = (v >= 0.f) ? v : LRELU*v;
  L2[t] = v;
}

// ---------------- softmax in place ----------------
__global__ __launch_bounds__(256) void softmax1(const int* __restrict__ off,
                                                float* __restrict__ L1, float* __restrict__ AS1){
  int wid = threadIdx.x >> 6, lane = threadIdx.x & 63;
  int i = blockIdx.x*4 + wid;
  if (i >= N_ENT) return;
  int st = off[i], en = off[i+1];
  int hf = lane >> 4, l16 = lane & 15;
  float* Lh = L1 + (size_t)hf*E_TOT;
  float mx = -1e30f;
  for (int t = st + l16; t < en; t += 16) mx = fmaxf(mx, Lh[t]);
  #pragma unroll
  for (int o = 8; o >= 1; o >>= 1) mx = fmaxf(mx, __shfl_xor(mx, o, 64));
  float sm = 0.f;
  for (int t = st + l16; t < en; t += 16) sm += __expf(Lh[t] - mx);
  #pragma unroll
  for (int o = 8; o >= 1; o >>= 1) sm += __shfl_xor(sm, o, 64);
  float inv = 1.f/(sm + 1e-16f);
  for (int t = st + l16; t < en; t += 16) Lh[t] = __expf(Lh[t] - mx) * inv;
  if (l16 == 0) AS1[i*4 + hf] = sm * inv;
}

__global__ __launch_bounds__(256) void softmax2(const int* __restrict__ off,
                                                float* __restrict__ L2, float* __restrict__ AS2){
  int wid = threadIdx.x >> 6, lane = threadIdx.x & 63;
  int i = blockIdx.x*4 + wid;
  if (i >= N_ENT) return;
  int st = off[i], en = off[i+1];
  float mx = -1e30f;
  for (int t = st + lane; t < en; t += 64) mx = fmaxf(mx, L2[t]);
  #pragma unroll
  for (int o = 32; o >= 1; o >>= 1) mx = fmaxf(mx, __shfl_xor(mx, o, 64));
  float sm = 0.f;
  for (int t = st + lane; t < en; t += 64) sm += __expf(L2[t] - mx);
  #pragma unroll
  for (int o = 32; o >= 1; o >>= 1) sm += __shfl_xor(sm, o, 64);
  float inv = 1.f/(sm + 1e-16f);
  for (int t = st + lane; t < en; t += 64) L2[t] = __expf(L2[t] - mx) * inv;
  if (lane == 0) AS2[i] = sm * inv;
}

// ---------------- layer-1 aggregation (4-wide pipelined) ----------------
__global__ __launch_bounds__(256) void agg1(const int* __restrict__ off,
    const int4* __restrict__ EIDX, const float* __restrict__ W1, const float* __restrict__ AS1,
    const bf16* __restrict__ P1, const bf16* __restrict__ P2, const float* __restrict__ PRm,
    bf16* __restrict__ X1){
  int wid = threadIdx.x >> 6, lane = threadIdx.x & 63;
  int i = blockIdx.x*4 + wid;
  if (i >= N_ENT) return;
  int st = off[i], en = off[i+1];
  int hf = lane >> 4, f0 = lane*4;
  size_t ob = (size_t)i*256 + f0;
  if (st == en){
    *(uint2*)(X1 + ob) = (uint2){0u, 0u};
    return;
  }
  const float* Wp = W1 + (size_t)hf*E_TOT;
  float a0=0,a1=0,a2=0,a3=0;
  int t = st;
  int n4 = st + ((en - st) & ~3);
  for (; t < n4; t += 4){
    int4 e[4]; float wv[4]; uint2 u[4]; float4 rv[4];
    #pragma unroll
    for (int k = 0; k < 4; k++){ e[k] = EIDX[t+k]; wv[k] = Wp[t+k]; }
    #pragma unroll
    for (int k = 0; k < 4; k++){
      u[k] = *(const uint2*)(P2 + (size_t)e[k].x*256 + f0);
      rv[k] = *(const float4*)(PRm + (size_t)e[k].y*256 + f0);
    }
    #pragma unroll
    for (int k = 0; k < 4; k++){
      if (e[k].z >= 0){
        float4 s = *(const float4*)(PRm + (size_t)e[k].z*256 + f0);
        rv[k].x += s.x; rv[k].y += s.y; rv[k].z += s.z; rv[k].w += s.w;
      }
    }
    #pragma unroll
    for (int k = 0; k < 4; k++){
      a0 += wv[k]*(bitsf(u[k].x << 16) + rv[k].x);
      a1 += wv[k]*(bitsf(u[k].x & 0xffff0000u) + rv[k].y);
      a2 += wv[k]*(bitsf(u[k].y << 16) + rv[k].z);
      a3 += wv[k]*(bitsf(u[k].y & 0xffff0000u) + rv[k].w);
    }
  }
  for (; t < en; t++){
    float w = Wp[t];
    int4 e = EIDX[t];
    uint2 u = *(const uint2*)(P2 + (size_t)e.x*256 + f0);
    float4 rv = *(const float4*)(PRm + (size_t)e.y*256 + f0);
    if (e.z >= 0){
      float4 s = *(const float4*)(PRm + (size_t)e.z*256 + f0);
      rv.x += s.x; rv.y += s.y; rv.z += s.z; rv.w += s.w;
    }
    a0 += w*(bitsf(u.x << 16) + rv.x);
    a1 += w*(bitsf(u.x & 0xffff0000u) + rv.y);
    a2 += w*(bitsf(u.y << 16) + rv.z);
    a3 += w*(bitsf(u.y & 0xffff0000u) + rv.w);
  }
  float as = AS1[i*4 + hf];
  uint2 up = *(const uint2*)(P1 + ob);
  a0 += as*bitsf(up.x << 16);
  a1 += as*bitsf(up.x & 0xffff0000u);
  a2 += as*bitsf(up.y << 16);
  a3 += as*bitsf(up.y & 0xffff0000u);
  a0 = (a0 > 0.f) ? a0 : __expf(a0)-1.f;
  a1 = (a1 > 0.f) ? a1 : __expf(a1)-1.f;
  a2 = (a2 > 0.f) ? a2 : __expf(a2)-1.f;
  a3 = (a3 > 0.f) ? a3 : __expf(a3)-1.f;
  unsigned int lo = (unsigned int)bbits(a0) | ((unsigned int)bbits(a1) << 16);
  unsigned int hi = (unsigned int)bbits(a2) | ((unsigned int)bbits(a3) << 16);
  *(uint2*)(X1 + ob) = (uint2){lo, hi};
}

// ---------------- layer-2 aggregation (4-wide pipelined, + EP epilogue) ----------------
__global__ __launch_bounds__(256) void agg2(const int* __restrict__ off,
    const int4* __restrict__ EIDX, const float* __restrict__ W2, const float* __restrict__ AS2,
    const bf16* __restrict__ Q1, const bf16* __restrict__ Q2, const float* __restrict__ QRm,
    const bf16* __restrict__ EP, float* __restrict__ X2){
  int wid = threadIdx.x >> 6, lane = threadIdx.x & 63;
  int i = blockIdx.x*4 + wid;
  if (i >= N_ENT) return;
  int st = off[i], en = off[i+1];
  int f0 = lane*4;
  size_t ob = (size_t)i*256 + f0;
  float ep0=0.f, ep1=0.f, ep2=0.f, ep3=0.f;
  if (EP){
    uint2 ue = *(const uint2*)(EP + ob);
    ep0 = bitsf(ue.x << 16); ep1 = bitsf(ue.x & 0xffff0000u);
    ep2 = bitsf(ue.y << 16); ep3 = bitsf(ue.y & 0xffff0000u);
  }
  if (st == en){
    *(float4*)(X2 + ob) = (float4){ep0, ep1, ep2, ep3};
    return;
  }
  float a0=0,a1=0,a2=0,a3=0;
  int t = st;
  int n4 = st + ((en - st) & ~3);
  for (; t < n4; t += 4){
    int4 e[4]; float wv[4]; uint2 u[4]; float4 rv[4];
    #pragma unroll
    for (int k = 0; k < 4; k++){ e[k] = EIDX[t+k]; wv[k] = W2[t+k]; }
    #pragma unroll
    for (int k = 0; k < 4; k++){
      u[k] = *(const uint2*)(Q2 + (size_t)e[k].x*256 + f0);
      rv[k] = *(const float4*)(QRm + (size_t)e[k].y*256 + f0);
    }
    #pragma unroll
    for (int k = 0; k < 4; k++){
      if (e[k].z >= 0){
        float4 s = *(const float4*)(QRm + (size_t)e[k].z*256 + f0);
        rv[k].x += s.x; rv[k].y += s.y; rv[k].z += s.z; rv[k].w += s.w;
      }
    }
    #pragma unroll
    for (int k = 0; k < 4; k++){
      a0 += wv[k]*(bitsf(u[k].x << 16) + rv[k].x);
      a1 += wv[k]*(bitsf(u[k].x & 0xffff0000u) + rv[k].y);
      a2 += wv[k]*(bitsf(u[k].y << 16) + rv[k].z);
      a3 += wv[k]*(bitsf(u[k].y & 0xffff0000u) + rv[k].w);
    }
  }
  for (; t < en; t++){
    float w = W2[t];
    int4 e = EIDX[t];
    uint2 u = *(const uint2*)(Q2 + (size_t)e.x*256 + f0);
    float4 rv = *(const float4*)(QRm + (size_t)e.y*256 + f0);
    if (e.z >= 0){
      float4 s = *(const float4*)(QRm + (size_t)e.z*256 + f0);
      rv.x += s.x; rv.y += s.y; rv.z += s.z; rv.w += s.w;
    }
    a0 += w*(bitsf(u.x << 16) + rv.x);
    a1 += w*(bitsf(u.x & 0xffff0000u) + rv.y);
    a2 += w*(bitsf(u.y << 16) + rv.z);
    a3 += w*(bitsf(u.y & 0xffff0000u) + rv.w);
  }
  float as = AS2[i];
  uint2 uq = *(const uint2*)(Q1 + ob);
  a0 += as*bitsf(uq.x << 16);
  a1 += as*bitsf(uq.x & 0xffff0000u);
  a2 += as*bitsf(uq.y << 16);
  a3 += as*bitsf(uq.y & 0xffff0000u);
  a0 = ((a0 > 0.f) ? a0 : __expf(a0)-1.f) + ep0;
  a1 = ((a1 > 0.f) ? a1 : __expf(a1)-1.f) + ep1;
  a2 = ((a2 > 0.f) ? a2 : __expf(a2)-1.f) + ep2;
  a3 = ((a3 > 0.f) ? a3 : __expf(a3)-1.f) + ep3;
  *(float4*)(X2 + ob) = (float4){a0, a1, a2, a3};
}

// ---------------- batch norm + r output ----------------
__global__ void bn_reduce(const float* __restrict__ X, float* __restrict__ sums, float* __restrict__ sq){
  int ch = threadIdx.x;
  float s = 0.f, q = 0.f;
  for (int r = blockIdx.x; r < N_ENT; r += gridDim.x){
    float v = X[(size_t)r*256 + ch];
    s += v; q += v*v;
  }
  atomicAdd(&sums[ch], s);
  atomicAdd(&sq[ch], q);
}

__global__ void bn_final_r(float* __restrict__ X, const float* __restrict__ sums, const float* __restrict__ sq,
                           const float* __restrict__ gamma, const float* __restrict__ beta,
                           const float* __restrict__ RF, float* __restrict__ out_r){
  int b = blockIdx.x;
  if (b < 40000){
    int idx = b*256 + threadIdx.x;
    int ch = idx & 255;
    const float invn = 1.f/(float)N_ENT;
    float mean = sums[ch] * invn;
    float var  = fmaxf(sq[ch] * invn - mean*mean, 0.f);
    X[idx] = (X[idx] - mean) * rsqrtf(var + BN_EPS) * gamma[ch] + beta[ch];
  } else {
    int idx = (b - 40000)*256 + threadIdx.x;
    out_r[idx] = RF[idx];
  }
}

// ---------------- launch ----------------
extern "C" void kernel_launch(void* const* d_in, const int* in_sizes, int n_in,
                              void* d_out, int out_size, void* d_ws, size_t ws_size,
                              hipStream_t stream){
  const int*   ei  = (const int*)d_in[0];
  const int*   et  = (const int*)d_in[1];
  const int*   i2  = (const int*)d_in[2];
  const float* emb = (const float*)d_in[3];
  const float* rel = (const float*)d_in[4];
  const float* Wh  = (const float*)d_in[5];
  const float* ah  = (const float*)d_in[6];
  const float* gw  = (const float*)d_in[7];
  const float* ow  = (const float*)d_in[8];
  const float* oa  = (const float*)d_in[9];
  const float* we  = (const float*)d_in[10];
  const float* gma = (const float*)d_in[11];
  const float* bta = (const float*)d_in[12];
  float* out = (float*)d_out;

  char* ws = (char*)d_ws;
  size_t o = 0;
  auto alloc = [&](size_t bytes)->char*{
    char* p = ws + o; o = (o + bytes + 255) & ~(size_t)255; return p;
  };
  bf16*  P1  = (bf16*)alloc(20480000);    // P1 -> Q1
  bf16*  P2  = (bf16*)alloc(20480000);    // P2 -> Q2
  float* PR  = (float*)alloc(512000);
  float* QR  = (float*)alloc(512000);
  float* RF  = (float*)alloc(512000);
  float* WC  = (float*)alloc(131072);
  bf16*  WAp = (bf16*)alloc(65536);
  bf16*  WBp = (bf16*)alloc(65536);
  bf16*  WEp = (bf16*)alloc(65536);
  bf16*  OWp0= (bf16*)alloc(131072);
  bf16*  OWp1= (bf16*)alloc(131072);
  float* S1  = (float*)alloc(640000);
  float* S2  = (float*)alloc(640000);
  float* SRm = (float*)alloc(8192);
  float* S1B = (float*)alloc(160000);
  float* S2B = (float*)alloc(160000);
  int*   CNT = (int*)alloc(160000);       // CNT+CUR adjacent: one memset
  int*   CUR = (int*)alloc(160000);
  int*   OFF = (int*)alloc(160016);
  int4*  EIDX= (int4*)alloc(4000000);
  float* L1  = (float*)alloc(4000000);
  float* L2  = (float*)alloc(1000000);
  float* AS1 = (float*)alloc(640000);
  float* AS2 = (float*)alloc(160000);
  float* SRB = (float*)alloc(2048);       // SRB+BNS+BNQ adjacent: one memset
  float* BNS = (float*)alloc(1024);
  float* BNQ = (float*)alloc(1024);
  size_t base_end = o;
  bool useEP = (ws_size >= base_end + 20480256 + 512);
  bf16* EP = nullptr;
  if (useEP) EP = (bf16*)alloc(20480000);
  bf16* X1b  = (bf16*)out;
  bf16* embb = (bf16*)((char*)out + 20480000);
  float* X2 = out;
  (void)in_sizes; (void)n_in; (void)out_size;

  hipMemsetAsync(CNT, 0, 320000, stream);
  hipMemsetAsync(SRB, 0, 4096, stream);

  prep_all<<<20240, 256, 0, stream>>>(Wh, ow, we, emb, WAp, WBp, WEp, OWp0, OWp1, WC, embb);

  hist_kernel<<<(E_TOT+255)/256, 256, 0, stream>>>(ei, i2, CNT);
  scan40000<<<1, 1024, 0, stream>>>(CNT, OFF);
  scatter_kernel<<<(E_TOT+255)/256, 256, 0, stream>>>(ei, et, i2, OFF, CUR, EIDX);

  // layer-1: entity projections (+EP) with fused per-head dots; rel pair with fused dots
  gemm_mfma_multi<<<dim3(N_ENT/64, useEP ? 3 : 2), 256, 0, stream>>>(
      (const short*)embb, (const short*)WAp, (const short*)WBp, (const short*)WEp,
      P1, P2, EP, 128, ah, S1, S2, 0);
  gemm64_sel<<<dim3((N_REL+63)/64, 4, 2), 256, 0, stream>>>(rel, WC, PR, gw, RF, N_REL, 128,
      ah, SRm, 0, nullptr, nullptr, 2);

  elog1<<<(E_TOT+255)/256, 256, 0, stream>>>(EIDX, S1, S2, SRm, L1);
  softmax1<<<N_ENT/4, 256, 0, stream>>>(OFF, L1, AS1);
  agg1<<<N_ENT/4, 256, 0, stream>>>(OFF, EIDX, L1, AS1, P1, P2, PR, X1b);

  // layer-2: entity projections with fused full dots; rel gemm with atomic full dot
  gemm_mfma_multi<<<dim3(N_ENT/64, 2), 256, 0, stream>>>(
      (const short*)X1b, (const short*)OWp0, (const short*)OWp1, (const short*)OWp1,
      P1, P2, P2, 256, oa, S1B, S2B, 1);
  gemm64_sel<<<dim3((N_REL+63)/64, 4, 1), 256, 0, stream>>>(RF, ow + 131072, QR, nullptr, nullptr,
      N_REL, 256, oa, SRB, 1, nullptr, nullptr, 2);

  elog2<<<(E_TOT+255)/256, 256, 0, stream>>>(EIDX, S1B, S2B, SRB, L2);
  softmax2<<<N_ENT/4, 256, 0, stream>>>(OFF, L2, AS2);
  agg2<<<N_ENT/4, 256, 0, stream>>>(OFF, EIDX, L2, AS2, P1, P2, QR, EP, X2);

  if (!useEP)
    gemm64_acc<<<dim3((N_ENT+63)/64, 4), 256, 0, stream>>>(emb, we, X2, N_ENT, 128);

  bn_reduce<<<1024, 256, 0, stream>>>(X2, BNS, BNQ);
  bn_final_r<<<40500, 256, 0, stream>>>(X2, BNS, BNQ, gma, bta, RF, out + (size_t)N_ENT*256);
}

// Round 10
// 479.480 us; speedup vs baseline: 2.3268x; 1.1437x over previous
//
#include <hip/hip_runtime.h>
#include <hip/hip_bf16.h>
#include <math.h>

#define N_ENT 40000
#define N_REL 500
#define E_DIR 200000
#define E_2HOP 50000
#define E_TOT 250000
#define D_IN 128
#define D_EMB 256
#define LRELU 0.2f
#define BN_EPS 1e-5f
#define NB_SCAN 157   // ceil(40000/256)

typedef __hip_bfloat16 bf16;
typedef __attribute__((ext_vector_type(8))) short short8;
typedef __attribute__((ext_vector_type(4))) float float4v;

__device__ __forceinline__ float b2f(bf16 v){ return __bfloat162float(v); }
__device__ __forceinline__ float bitsf(unsigned int u){ return __builtin_bit_cast(float, u); }
__device__ __forceinline__ unsigned short bbits(float v){ return __builtin_bit_cast(unsigned short, __float2bfloat16(v)); }

// ---------------- fused weight prep + emb bf16 convert ----------------
__global__ void prep_all(const float* __restrict__ Wh, const float* __restrict__ ow,
                         const float* __restrict__ we, const float* __restrict__ emb,
                         bf16* __restrict__ WAp, bf16* __restrict__ WBp, bf16* __restrict__ WEp,
                         bf16* __restrict__ OWp0, bf16* __restrict__ OWp1, float* __restrict__ WC,
                         bf16* __restrict__ embb){
  const int HS = 384*64;
  int b = blockIdx.x, tid = threadIdx.x;
  if (b >= 240){
    int i = (b - 240)*256 + tid;
    embb[i] = __float2bfloat16(emb[i]);
    return;
  }
  if (b < 112){
    int seg, base;
    if      (b < 16){ seg = 0; base = 0; }
    else if (b < 32){ seg = 1; base = 16; }
    else if (b < 48){ seg = 2; base = 32; }
    else if (b < 80){ seg = 3; base = 48; }
    else            { seg = 4; base = 80; }
    int idx = (b - base)*256 + tid;
    int lane = idx & 63, nt = (idx >> 6) & 15, kc = idx >> 10;
    int quad = lane >> 4, l16 = lane & 15;
    int col = nt*16 + l16;
    int kbase = kc*32 + quad*8;
    bf16* dst = (seg==0?WAp : seg==1?WBp : seg==2?WEp : seg==3?OWp0 : OWp1) + (size_t)idx*8;
    #pragma unroll
    for (int j = 0; j < 8; j++){
      int k = kbase + j;
      float v;
      if      (seg == 0) v = Wh[(col>>6)*HS + k*64 + (col&63)];
      else if (seg == 1) v = Wh[(col>>6)*HS + (k+128)*64 + (col&63)];
      else if (seg == 2) v = we[(size_t)k*256 + col];
      else if (seg == 3) v = ow[(size_t)k*256 + col];
      else               v = ow[(size_t)(k+256)*256 + col];
      dst[j] = __float2bfloat16(v);
    }
  } else {
    int idx = (b - 112)*256 + tid;
    int k = idx >> 8, col = idx & 255;
    WC[idx] = Wh[(col>>6)*HS + (k+256)*64 + (col&63)];
  }
}

// ---------------- MFMA GEMM multi: register-pipelined B, prefetched A ----------------
__global__ __launch_bounds__(256) void gemm_mfma_multi(const short* __restrict__ A,
    const short* __restrict__ B0, const short* __restrict__ B1, const short* __restrict__ B2,
    bf16* __restrict__ C0, bf16* __restrict__ C1, bf16* __restrict__ C2, int K,
    const float* __restrict__ avec, float* __restrict__ S0, float* __restrict__ S1o,
    int dmode){
  const short* Bp = blockIdx.y==0 ? B0 : (blockIdx.y==1 ? B1 : B2);
  bf16* C = blockIdx.y==0 ? C0 : (blockIdx.y==1 ? C1 : C2);
  float* Sout = blockIdx.y==0 ? S0 : (blockIdx.y==1 ? S1o : nullptr);
  int w = threadIdx.x >> 6, lane = threadIdx.x & 63;
  int quad = lane >> 4, l16 = lane & 15;
  int rm = blockIdx.x*64 + w*16;
  int arow = rm + l16;
  float4v acc[16];
  #pragma unroll
  for (int nt = 0; nt < 16; nt++) acc[nt] = (float4v){0.f,0.f,0.f,0.f};
  int nkc = K >> 5;
  const short8* Ap = (const short8*)(A + (size_t)arow*K);
  const short8* Bv = (const short8*)Bp;
  short8 a_cur = Ap[quad];
  for (int kc = 0; kc < nkc; kc++){
    int kn = (kc + 1 < nkc) ? kc + 1 : kc;
    short8 a_nxt = Ap[kn*4 + quad];
    const short8* bp = Bv + (size_t)kc*16*64 + lane;
    short8 b[8];
    #pragma unroll
    for (int nt = 0; nt < 8; nt++) b[nt] = bp[(size_t)nt*64];
    #pragma unroll
    for (int nt = 0; nt < 8; nt++)
      acc[nt] = __builtin_amdgcn_mfma_f32_16x16x32_bf16(a_cur, b[nt], acc[nt], 0, 0, 0);
    #pragma unroll
    for (int nt = 0; nt < 8; nt++) b[nt] = bp[(size_t)(nt+8)*64];
    #pragma unroll
    for (int nt = 0; nt < 8; nt++)
      acc[nt+8] = __builtin_amdgcn_mfma_f32_16x16x32_bf16(a_cur, b[nt], acc[nt+8], 0, 0, 0);
    a_cur = a_nxt;
  }
  #pragma unroll
  for (int nt = 0; nt < 16; nt++){
    #pragma unroll
    for (int r = 0; r < 4; r++){
      int row = quad*4 + r;
      C[(size_t)(rm + row)*256 + nt*16 + l16] = __float2bfloat16(acc[nt][r]);
    }
  }
  if (Sout){
    if (dmode == 0){
      #pragma unroll
      for (int h = 0; h < 4; h++){
        float pr[4] = {0.f,0.f,0.f,0.f};
        #pragma unroll
        for (int ntl = 0; ntl < 4; ntl++){
          int nt = h*4 + ntl;
          float av = avec[nt*16 + l16];
          #pragma unroll
          for (int r = 0; r < 4; r++) pr[r] += acc[nt][r]*av;
        }
        #pragma unroll
        for (int m = 8; m >= 1; m >>= 1)
          #pragma unroll
          for (int r = 0; r < 4; r++) pr[r] += __shfl_xor(pr[r], m, 64);
        if (l16 == 0){
          #pragma unroll
          for (int r = 0; r < 4; r++) Sout[(rm + quad*4 + r)*4 + h] = pr[r];
        }
      }
    } else {
      float pr[4] = {0.f,0.f,0.f,0.f};
      #pragma unroll
      for (int nt = 0; nt < 16; nt++){
        float av = avec[nt*16 + l16];
        #pragma unroll
        for (int r = 0; r < 4; r++) pr[r] += acc[nt][r]*av;
      }
      #pragma unroll
      for (int m = 8; m >= 1; m >>= 1)
        #pragma unroll
        for (int r = 0; r < 4; r++) pr[r] += __shfl_xor(pr[r], m, 64);
      if (l16 == 0){
        #pragma unroll
        for (int r = 0; r < 4; r++) Sout[rm + quad*4 + r] = pr[r];
      }
    }
  }
}

// ---------------- fp32 tiled GEMM (pair-select by z) + fused dot epilogue ----------------
__global__ void gemm64_sel(const float* __restrict__ A,
                           const float* __restrict__ B0, float* __restrict__ C0,
                           const float* __restrict__ B1, float* __restrict__ C1,
                           int M, int K,
                           const float* __restrict__ av0, float* __restrict__ S0, int mode0,
                           const float* __restrict__ av1, float* __restrict__ S1o, int mode1){
  const float* B = blockIdx.z ? B1 : B0;
  float* C = blockIdx.z ? C1 : C0;
  const float* av = blockIdx.z ? av1 : av0;
  float* So = blockIdx.z ? S1o : S0;
  int mode = blockIdx.z ? mode1 : mode0;
  const int N = 256;
  __shared__ float As[16][65];
  __shared__ float Bs[16][65];
  int bm = blockIdx.x * 64, bn = blockIdx.y * 64;
  int tid = threadIdx.x;
  int tx = tid & 15, ty = tid >> 4;
  float acc[4][4] = {};
  for (int k0 = 0; k0 < K; k0 += 16){
    #pragma unroll
    for (int j = 0; j < 4; j++){
      int idx = tid + j*256;
      int m = idx >> 4, kk = idx & 15;
      int gm = bm + m;
      float v = 0.f;
      if (gm < M) v = A[(size_t)gm*K + k0 + kk];
      As[kk][m] = v;
    }
    #pragma unroll
    for (int j = 0; j < 4; j++){
      int idx = tid + j*256;
      int kk = idx >> 6, n = idx & 63;
      Bs[kk][n] = B[(size_t)(k0+kk)*N + bn + n];
    }
    __syncthreads();
    #pragma unroll
    for (int kk = 0; kk < 16; kk++){
      float a[4], b[4];
      #pragma unroll
      for (int i = 0; i < 4; i++) a[i] = As[kk][ty*4+i];
      #pragma unroll
      for (int j = 0; j < 4; j++) b[j] = Bs[kk][tx*4+j];
      #pragma unroll
      for (int i = 0; i < 4; i++)
        #pragma unroll
        for (int j = 0; j < 4; j++) acc[i][j] += a[i]*b[j];
    }
    __syncthreads();
  }
  #pragma unroll
  for (int i = 0; i < 4; i++){
    int gm = bm + ty*4 + i;
    if (gm >= M) continue;
    #pragma unroll
    for (int j = 0; j < 4; j++)
      C[(size_t)gm*N + bn + tx*4 + j] = acc[i][j];
  }
  if (mode != 2){
    float pr[4];
    #pragma unroll
    for (int i = 0; i < 4; i++){
      float p = 0.f;
      #pragma unroll
      for (int j = 0; j < 4; j++) p += acc[i][j]*av[bn + tx*4 + j];
      pr[i] = p;
    }
    #pragma unroll
    for (int m = 8; m >= 1; m >>= 1)
      #pragma unroll
      for (int i = 0; i < 4; i++) pr[i] += __shfl_xor(pr[i], m, 64);
    if (tx == 0){
      int head = bn >> 6;
      #pragma unroll
      for (int i = 0; i < 4; i++){
        int gm = bm + ty*4 + i;
        if (gm < M){
          if (mode == 0) So[gm*4 + head] = pr[i];
          else atomicAdd(&So[gm], pr[i]);
        }
      }
    }
  }
}

// fp32 accumulate GEMM (fallback when EP doesn't fit ws)
__global__ void gemm64_acc(const float* __restrict__ A, const float* __restrict__ B,
                           float* __restrict__ C, int M, int K){
  const int N = 256;
  __shared__ float As[16][65];
  __shared__ float Bs[16][65];
  int bm = blockIdx.x * 64, bn = blockIdx.y * 64;
  int tid = threadIdx.x;
  int tx = tid & 15, ty = tid >> 4;
  float acc[4][4] = {};
  for (int k0 = 0; k0 < K; k0 += 16){
    #pragma unroll
    for (int j = 0; j < 4; j++){
      int idx = tid + j*256;
      int m = idx >> 4, kk = idx & 15;
      int gm = bm + m;
      float v = 0.f;
      if (gm < M) v = A[(size_t)gm*K + k0 + kk];
      As[kk][m] = v;
    }
    #pragma unroll
    for (int j = 0; j < 4; j++){
      int idx = tid + j*256;
      int kk = idx >> 6, n = idx & 63;
      Bs[kk][n] = B[(size_t)(k0+kk)*N + bn + n];
    }
    __syncthreads();
    #pragma unroll
    for (int kk = 0; kk < 16; kk++){
      float a[4], b[4];
      #pragma unroll
      for (int i = 0; i < 4; i++) a[i] = As[kk][ty*4+i];
      #pragma unroll
      for (int j = 0; j < 4; j++) b[j] = Bs[kk][tx*4+j];
      #pragma unroll
      for (int i = 0; i < 4; i++)
        #pragma unroll
        for (int j = 0; j < 4; j++) acc[i][j] += a[i]*b[j];
    }
    __syncthreads();
  }
  #pragma unroll
  for (int i = 0; i < 4; i++){
    int gm = bm + ty*4 + i;
    if (gm >= M) continue;
    #pragma unroll
    for (int j = 0; j < 4; j++){
      size_t o = (size_t)gm*N + bn + tx*4 + j;
      C[o] += acc[i][j];
    }
  }
}

// ---------------- CSR build ----------------
__device__ __forceinline__ int e_row(int e, const int* ei, const int* i2){
  return (e < E_DIR) ? ei[E_DIR + e] : i2[(e - E_DIR)*4 + 3];
}

__global__ void hist_kernel(const int* __restrict__ ei, const int* __restrict__ i2, int* __restrict__ cnt){
  int e = blockIdx.x*blockDim.x + threadIdx.x;
  if (e < E_TOT) atomicAdd(&cnt[e_row(e, ei, i2)], 1);
}

// hierarchical scan: block sums -> scan of block sums -> per-block exclusive scan
__global__ void scan_bsum(const int* __restrict__ cnt, int* __restrict__ bsum){
  int i = blockIdx.x*256 + threadIdx.x;
  int v = (i < N_ENT) ? cnt[i] : 0;
  int lane = threadIdx.x & 63, w = threadIdx.x >> 6;
  int s = v;
  #pragma unroll
  for (int o = 32; o >= 1; o >>= 1) s += __shfl_xor(s, o, 64);
  __shared__ int ws[4];
  if (lane == 0) ws[w] = s;
  __syncthreads();
  if (threadIdx.x == 0) bsum[blockIdx.x] = ws[0]+ws[1]+ws[2]+ws[3];
}

__global__ void scan_boff(const int* __restrict__ bsum, int* __restrict__ boff, int* __restrict__ offN){
  int t = threadIdx.x;
  int v = (t < NB_SCAN) ? bsum[t] : 0;
  int lane = t & 63, w = t >> 6;
  int s = v;
  #pragma unroll
  for (int o = 1; o < 64; o <<= 1){ int n = __shfl_up(s, o, 64); if (lane >= o) s += n; }
  __shared__ int ws[4];
  if (lane == 63) ws[w] = s;
  __syncthreads();
  int add = 0;
  for (int k = 0; k < w; k++) add += ws[k];
  int incl = s + add;
  if (t < NB_SCAN) boff[t] = incl - v;
  if (t == NB_SCAN-1) offN[0] = incl;   // total edges = OFF[N_ENT]
}

__global__ void scan_final(const int* __restrict__ cnt, const int* __restrict__ boff, int* __restrict__ off){
  int i = blockIdx.x*256 + threadIdx.x;
  int v = (i < N_ENT) ? cnt[i] : 0;
  int lane = threadIdx.x & 63, w = threadIdx.x >> 6;
  int s = v;
  #pragma unroll
  for (int o = 1; o < 64; o <<= 1){ int n = __shfl_up(s, o, 64); if (lane >= o) s += n; }
  __shared__ int ws[4];
  if (lane == 63) ws[w] = s;
  __syncthreads();
  int add = boff[blockIdx.x];
  for (int k = 0; k < w; k++) add += ws[k];
  if (i < N_ENT) off[i] = add + s - v;
}

__global__ void scatter_kernel(const int* __restrict__ ei, const int* __restrict__ et,
                               const int* __restrict__ i2, const int* __restrict__ off,
                               int* __restrict__ cur, int4* __restrict__ EIDX){
  int e = blockIdx.x*blockDim.x + threadIdx.x;
  if (e >= E_TOT) return;
  int r = e_row(e, ei, i2);
  int p = atomicAdd(&cur[r], 1);
  int d = off[r] + p;
  int4 v;
  if (e < E_DIR){ v.x = ei[e]; v.y = et[e]; v.z = -1; }
  else { int q = (e - E_DIR)*4; v.x = i2[q]; v.y = i2[q+1]; v.z = i2[q+2]; }
  v.w = r;
  EIDX[d] = v;
}

// ---------------- edge logits ----------------
__global__ void elog1(const int4* __restrict__ EIDX,
                      const float* __restrict__ s1, const float* __restrict__ s2,
                      const float* __restrict__ sR, float* __restrict__ L1){
  int t = blockIdx.x*blockDim.x + threadIdx.x;
  if (t >= E_TOT) return;
  int4 e = EIDX[t];
  #pragma unroll
  for (int h = 0; h < 4; h++){
    float v = s1[e.w*4+h] + s2[e.x*4+h] + sR[e.y*4+h];
    if (e.z >= 0) v += sR[e.z*4+h];
    v = (v >= 0.f) ? v : LRELU*v;
    L1[(size_t)h*E_TOT + t] = v;
  }
}

__global__ void elog2(const int4* __restrict__ EIDX,
                      const float* __restrict__ s1, const float* __restrict__ s2,
                      const float* __restrict__ sR, float* __restrict__ L2){
  int t = blockIdx.x*blockDim.x + threadIdx.x;
  if (t >= E_TOT) return;
  int4 e = EIDX[t];
  float v = s1[e.w] + s2[e.x] + sR[e.y];
  if (e.z >= 0) v += sR[e.z];
  v = (v >= 0.f) ? v : LRELU*v;
  L2[t] = v;
}

// ---------------- softmax in place ----------------
__global__ __launch_bounds__(256) void softmax1(const int* __restrict__ off,
                                                float* __restrict__ L1, float* __restrict__ AS1){
  int wid = threadIdx.x >> 6, lane = threadIdx.x & 63;
  int i = blockIdx.x*4 + wid;
  if (i >= N_ENT) return;
  int st = off[i], en = off[i+1];
  int hf = lane >> 4, l16 = lane & 15;
  float* Lh = L1 + (size_t)hf*E_TOT;
  float mx = -1e30f;
  for (int t = st + l16; t < en; t += 16) mx = fmaxf(mx, Lh[t]);
  #pragma unroll
  for (int o = 8; o >= 1; o >>= 1) mx = fmaxf(mx, __shfl_xor(mx, o, 64));
  float sm = 0.f;
  for (int t = st + l16; t < en; t += 16) sm += __expf(Lh[t] - mx);
  #pragma unroll
  for (int o = 8; o >= 1; o >>= 1) sm += __shfl_xor(sm, o, 64);
  float inv = 1.f/(sm + 1e-16f);
  for (int t = st + l16; t < en; t += 16) Lh[t] = __expf(Lh[t] - mx) * inv;
  if (l16 == 0) AS1[i*4 + hf] = sm * inv;
}

__global__ __launch_bounds__(256) void softmax2(const int* __restrict__ off,
                                                float* __restrict__ L2, float* __restrict__ AS2){
  int wid = threadIdx.x >> 6, lane = threadIdx.x & 63;
  int i = blockIdx.x*4 + wid;
  if (i >= N_ENT) return;
  int st = off[i], en = off[i+1];
  float mx = -1e30f;
  for (int t = st + lane; t < en; t += 64) mx = fmaxf(mx, L2[t]);
  #pragma unroll
  for (int o = 32; o >= 1; o >>= 1) mx = fmaxf(mx, __shfl_xor(mx, o, 64));
  float sm = 0.f;
  for (int t = st + lane; t < en; t += 64) sm += __expf(L2[t] - mx);
  #pragma unroll
  for (int o = 32; o >= 1; o >>= 1) sm += __shfl_xor(sm, o, 64);
  float inv = 1.f/(sm + 1e-16f);
  for (int t = st + lane; t < en; t += 64) L2[t] = __expf(L2[t] - mx) * inv;
  if (lane == 0) AS2[i] = sm * inv;
}

// ---------------- layer-1 aggregation (4-wide pipelined) ----------------
__global__ __launch_bounds__(256) void agg1(const int* __restrict__ off,
    const int4* __restrict__ EIDX, const float* __restrict__ W1, const float* __restrict__ AS1,
    const bf16* __restrict__ P1, const bf16* __restrict__ P2, const float* __restrict__ PRm,
    bf16* __restrict__ X1){
  int wid = threadIdx.x >> 6, lane = threadIdx.x & 63;
  int i = blockIdx.x*4 + wid;
  if (i >= N_ENT) return;
  int st = off[i], en = off[i+1];
  int hf = lane >> 4, f0 = lane*4;
  size_t ob = (size_t)i*256 + f0;
  if (st == en){
    *(uint2*)(X1 + ob) = (uint2){0u, 0u};
    return;
  }
  const float* Wp = W1 + (size_t)hf*E_TOT;
  float a0=0,a1=0,a2=0,a3=0;
  int t = st;
  int n4 = st + ((en - st) & ~3);
  for (; t < n4; t += 4){
    int4 e[4]; float wv[4]; uint2 u[4]; float4 rv[4];
    #pragma unroll
    for (int k = 0; k < 4; k++){ e[k] = EIDX[t+k]; wv[k] = Wp[t+k]; }
    #pragma unroll
    for (int k = 0; k < 4; k++){
      u[k] = *(const uint2*)(P2 + (size_t)e[k].x*256 + f0);
      rv[k] = *(const float4*)(PRm + (size_t)e[k].y*256 + f0);
    }
    #pragma unroll
    for (int k = 0; k < 4; k++){
      if (e[k].z >= 0){
        float4 s = *(const float4*)(PRm + (size_t)e[k].z*256 + f0);
        rv[k].x += s.x; rv[k].y += s.y; rv[k].z += s.z; rv[k].w += s.w;
      }
    }
    #pragma unroll
    for (int k = 0; k < 4; k++){
      a0 += wv[k]*(bitsf(u[k].x << 16) + rv[k].x);
      a1 += wv[k]*(bitsf(u[k].x & 0xffff0000u) + rv[k].y);
      a2 += wv[k]*(bitsf(u[k].y << 16) + rv[k].z);
      a3 += wv[k]*(bitsf(u[k].y & 0xffff0000u) + rv[k].w);
    }
  }
  for (; t < en; t++){
    float w = Wp[t];
    int4 e = EIDX[t];
    uint2 u = *(const uint2*)(P2 + (size_t)e.x*256 + f0);
    float4 rv = *(const float4*)(PRm + (size_t)e.y*256 + f0);
    if (e.z >= 0){
      float4 s = *(const float4*)(PRm + (size_t)e.z*256 + f0);
      rv.x += s.x; rv.y += s.y; rv.z += s.z; rv.w += s.w;
    }
    a0 += w*(bitsf(u.x << 16) + rv.x);
    a1 += w*(bitsf(u.x & 0xffff0000u) + rv.y);
    a2 += w*(bitsf(u.y << 16) + rv.z);
    a3 += w*(bitsf(u.y & 0xffff0000u) + rv.w);
  }
  float as = AS1[i*4 + hf];
  uint2 up = *(const uint2*)(P1 + ob);
  a0 += as*bitsf(up.x << 16);
  a1 += as*bitsf(up.x & 0xffff0000u);
  a2 += as*bitsf(up.y << 16);
  a3 += as*bitsf(up.y & 0xffff0000u);
  a0 = (a0 > 0.f) ? a0 : __expf(a0)-1.f;
  a1 = (a1 > 0.f) ? a1 : __expf(a1)-1.f;
  a2 = (a2 > 0.f) ? a2 : __expf(a2)-1.f;
  a3 = (a3 > 0.f) ? a3 : __expf(a3)-1.f;
  unsigned int lo = (unsigned int)bbits(a0) | ((unsigned int)bbits(a1) << 16);
  unsigned int hi = (unsigned int)bbits(a2) | ((unsigned int)bbits(a3) << 16);
  *(uint2*)(X1 + ob) = (uint2){lo, hi};
}

// ---------------- layer-2 aggregation (4-wide pipelined, + EP epilogue) ----------------
__global__ __launch_bounds__(256) void agg2(const int* __restrict__ off,
    const int4* __restrict__ EIDX, const float* __restrict__ W2, const float* __restrict__ AS2,
    const bf16* __restrict__ Q1, const bf16* __restrict__ Q2, const float* __restrict__ QRm,
    const bf16* __restrict__ EP, float* __restrict__ X2){
  int wid = threadIdx.x >> 6, lane = threadIdx.x & 63;
  int i = blockIdx.x*4 + wid;
  if (i >= N_ENT) return;
  int st = off[i], en = off[i+1];
  int f0 = lane*4;
  size_t ob = (size_t)i*256 + f0;
  float ep0=0.f, ep1=0.f, ep2=0.f, ep3=0.f;
  if (EP){
    uint2 ue = *(const uint2*)(EP + ob);
    ep0 = bitsf(ue.x << 16); ep1 = bitsf(ue.x & 0xffff0000u);
    ep2 = bitsf(ue.y << 16); ep3 = bitsf(ue.y & 0xffff0000u);
  }
  if (st == en){
    *(float4*)(X2 + ob) = (float4){ep0, ep1, ep2, ep3};
    return;
  }
  float a0=0,a1=0,a2=0,a3=0;
  int t = st;
  int n4 = st + ((en - st) & ~3);
  for (; t < n4; t += 4){
    int4 e[4]; float wv[4]; uint2 u[4]; float4 rv[4];
    #pragma unroll
    for (int k = 0; k < 4; k++){ e[k] = EIDX[t+k]; wv[k] = W2[t+k]; }
    #pragma unroll
    for (int k = 0; k < 4; k++){
      u[k] = *(const uint2*)(Q2 + (size_t)e[k].x*256 + f0);
      rv[k] = *(const float4*)(QRm + (size_t)e[k].y*256 + f0);
    }
    #pragma unroll
    for (int k = 0; k < 4; k++){
      if (e[k].z >= 0){
        float4 s = *(const float4*)(QRm + (size_t)e[k].z*256 + f0);
        rv[k].x += s.x; rv[k].y += s.y; rv[k].z += s.z; rv[k].w += s.w;
      }
    }
    #pragma unroll
    for (int k = 0; k < 4; k++){
      a0 += wv[k]*(bitsf(u[k].x << 16) + rv[k].x);
      a1 += wv[k]*(bitsf(u[k].x & 0xffff0000u) + rv[k].y);
      a2 += wv[k]*(bitsf(u[k].y << 16) + rv[k].z);
      a3 += wv[k]*(bitsf(u[k].y & 0xffff0000u) + rv[k].w);
    }
  }
  for (; t < en; t++){
    float w = W2[t];
    int4 e = EIDX[t];
    uint2 u = *(const uint2*)(Q2 + (size_t)e.x*256 + f0);
    float4 rv = *(const float4*)(QRm + (size_t)e.y*256 + f0);
    if (e.z >= 0){
      float4 s = *(const float4*)(QRm + (size_t)e.z*256 + f0);
      rv.x += s.x; rv.y += s.y; rv.z += s.z; rv.w += s.w;
    }
    a0 += w*(bitsf(u.x << 16) + rv.x);
    a1 += w*(bitsf(u.x & 0xffff0000u) + rv.y);
    a2 += w*(bitsf(u.y << 16) + rv.z);
    a3 += w*(bitsf(u.y & 0xffff0000u) + rv.w);
  }
  float as = AS2[i];
  uint2 uq = *(const uint2*)(Q1 + ob);
  a0 += as*bitsf(uq.x << 16);
  a1 += as*bitsf(uq.x & 0xffff0000u);
  a2 += as*bitsf(uq.y << 16);
  a3 += as*bitsf(uq.y & 0xffff0000u);
  a0 = ((a0 > 0.f) ? a0 : __expf(a0)-1.f) + ep0;
  a1 = ((a1 > 0.f) ? a1 : __expf(a1)-1.f) + ep1;
  a2 = ((a2 > 0.f) ? a2 : __expf(a2)-1.f) + ep2;
  a3 = ((a3 > 0.f) ? a3 : __expf(a3)-1.f) + ep3;
  *(float4*)(X2 + ob) = (float4){a0, a1, a2, a3};
}

// ---------------- batch norm + r output ----------------
__global__ void bn_reduce(const float* __restrict__ X, float* __restrict__ sums, float* __restrict__ sq){
  int ch = threadIdx.x;
  float s = 0.f, q = 0.f;
  for (int r = blockIdx.x; r < N_ENT; r += gridDim.x){
    float v = X[(size_t)r*256 + ch];
    s += v; q += v*v;
  }
  atomicAdd(&sums[ch], s);
  atomicAdd(&sq[ch], q);
}

__global__ void bn_final_r(float* __restrict__ X, const float* __restrict__ sums, const float* __restrict__ sq,
                           const float* __restrict__ gamma, const float* __restrict__ beta,
                           const float* __restrict__ RF, float* __restrict__ out_r){
  int b = blockIdx.x;
  if (b < 40000){
    int idx = b*256 + threadIdx.x;
    int ch = idx & 255;
    const float invn = 1.f/(float)N_ENT;
    float mean = sums[ch] * invn;
    float var  = fmaxf(sq[ch] * invn - mean*mean, 0.f);
    X[idx] = (X[idx] - mean) * rsqrtf(var + BN_EPS) * gamma[ch] + beta[ch];
  } else {
    int idx = (b - 40000)*256 + threadIdx.x;
    out_r[idx] = RF[idx];
  }
}

// ---------------- launch ----------------
extern "C" void kernel_launch(void* const* d_in, const int* in_sizes, int n_in,
                              void* d_out, int out_size, void* d_ws, size_t ws_size,
                              hipStream_t stream){
  const int*   ei  = (const int*)d_in[0];
  const int*   et  = (const int*)d_in[1];
  const int*   i2  = (const int*)d_in[2];
  const float* emb = (const float*)d_in[3];
  const float* rel = (const float*)d_in[4];
  const float* Wh  = (const float*)d_in[5];
  const float* ah  = (const float*)d_in[6];
  const float* gw  = (const float*)d_in[7];
  const float* ow  = (const float*)d_in[8];
  const float* oa  = (const float*)d_in[9];
  const float* we  = (const float*)d_in[10];
  const float* gma = (const float*)d_in[11];
  const float* bta = (const float*)d_in[12];
  float* out = (float*)d_out;

  char* ws = (char*)d_ws;
  size_t o = 0;
  auto alloc = [&](size_t bytes)->char*{
    char* p = ws + o; o = (o + bytes + 255) & ~(size_t)255; return p;
  };
  bf16*  P1  = (bf16*)alloc(20480000);    // P1 -> Q1
  bf16*  P2  = (bf16*)alloc(20480000);    // P2 -> Q2
  float* PR  = (float*)alloc(512000);
  float* QR  = (float*)alloc(512000);
  float* RF  = (float*)alloc(512000);
  float* WC  = (float*)alloc(131072);
  bf16*  WAp = (bf16*)alloc(65536);
  bf16*  WBp = (bf16*)alloc(65536);
  bf16*  WEp = (bf16*)alloc(65536);
  bf16*  OWp0= (bf16*)alloc(131072);
  bf16*  OWp1= (bf16*)alloc(131072);
  float* S1  = (float*)alloc(640000);
  float* S2  = (float*)alloc(640000);
  float* SRm = (float*)alloc(8192);
  float* S1B = (float*)alloc(160000);
  float* S2B = (float*)alloc(160000);
  int*   CNT = (int*)alloc(160000);       // CNT+CUR adjacent: one memset
  int*   CUR = (int*)alloc(160000);
  int*   OFF = (int*)alloc(160016);
  int*   BSUM= (int*)alloc(1024);
  int*   BOFF= (int*)alloc(1024);
  int4*  EIDX= (int4*)alloc(4000000);
  float* L1  = (float*)alloc(4000000);
  float* L2  = (float*)alloc(1000000);
  float* AS1 = (float*)alloc(640000);
  float* AS2 = (float*)alloc(160000);
  float* SRB = (float*)alloc(2048);       // SRB+BNS+BNQ adjacent: one memset
  float* BNS = (float*)alloc(1024);
  float* BNQ = (float*)alloc(1024);
  size_t base_end = o;
  bool useEP = (ws_size >= base_end + 20480256 + 512);
  bf16* EP = nullptr;
  if (useEP) EP = (bf16*)alloc(20480000);
  bf16* X1b  = (bf16*)out;
  bf16* embb = (bf16*)((char*)out + 20480000);
  float* X2 = out;
  (void)in_sizes; (void)n_in; (void)out_size;

  hipMemsetAsync(CNT, 0, 320000, stream);
  hipMemsetAsync(SRB, 0, 4096, stream);

  prep_all<<<20240, 256, 0, stream>>>(Wh, ow, we, emb, WAp, WBp, WEp, OWp0, OWp1, WC, embb);

  hist_kernel<<<(E_TOT+255)/256, 256, 0, stream>>>(ei, i2, CNT);
  scan_bsum<<<NB_SCAN, 256, 0, stream>>>(CNT, BSUM);
  scan_boff<<<1, 256, 0, stream>>>(BSUM, BOFF, OFF + N_ENT);
  scan_final<<<NB_SCAN, 256, 0, stream>>>(CNT, BOFF, OFF);
  scatter_kernel<<<(E_TOT+255)/256, 256, 0, stream>>>(ei, et, i2, OFF, CUR, EIDX);

  // layer-1: entity projections (+EP) with fused per-head dots; rel pair with fused dots
  gemm_mfma_multi<<<dim3(N_ENT/64, useEP ? 3 : 2), 256, 0, stream>>>(
      (const short*)embb, (const short*)WAp, (const short*)WBp, (const short*)WEp,
      P1, P2, EP, 128, ah, S1, S2, 0);
  gemm64_sel<<<dim3((N_REL+63)/64, 4, 2), 256, 0, stream>>>(rel, WC, PR, gw, RF, N_REL, 128,
      ah, SRm, 0, nullptr, nullptr, 2);

  elog1<<<(E_TOT+255)/256, 256, 0, stream>>>(EIDX, S1, S2, SRm, L1);
  softmax1<<<N_ENT/4, 256, 0, stream>>>(OFF, L1, AS1);
  agg1<<<N_ENT/4, 256, 0, stream>>>(OFF, EIDX, L1, AS1, P1, P2, PR, X1b);

  // layer-2: entity projections with fused full dots; rel gemm with atomic full dot
  gemm_mfma_multi<<<dim3(N_ENT/64, 2), 256, 0, stream>>>(
      (const short*)X1b, (const short*)OWp0, (const short*)OWp1, (const short*)OWp1,
      P1, P2, P2, 256, oa, S1B, S2B, 1);
  gemm64_sel<<<dim3((N_REL+63)/64, 4, 1), 256, 0, stream>>>(RF, ow + 131072, QR, nullptr, nullptr,
      N_REL, 256, oa, SRB, 1, nullptr, nullptr, 2);

  elog2<<<(E_TOT+255)/256, 256, 0, stream>>>(EIDX, S1B, S2B, SRB, L2);
  softmax2<<<N_ENT/4, 256, 0, stream>>>(OFF, L2, AS2);
  agg2<<<N_ENT/4, 256, 0, stream>>>(OFF, EIDX, L2, AS2, P1, P2, QR, EP, X2);

  if (!useEP)
    gemm64_acc<<<dim3((N_ENT+63)/64, 4), 256, 0, stream>>>(emb, we, X2, N_ENT, 128);

  bn_reduce<<<1024, 256, 0, stream>>>(X2, BNS, BNQ);
  bn_final_r<<<40500, 256, 0, stream>>>(X2, BNS, BNQ, gma, bta, RF, out + (size_t)N_ENT*256);
}